// Round 26
// baseline (623.179 us; speedup 1.0000x reference)
//
#include <hip/hip_runtime.h>
#include <hip/hip_bf16.h>
#include <math.h>

constexpr int CC = 64, KK = 256, LL = 128;
constexpr int NN = KK * LL;          // 32768
constexpr int PR = 64;               // Linformer projection
constexpr int CPG = 16;              // channels per group (C / 4)
constexpr float EPSV = 1e-5f;
constexpr float SCL = 0.35355339059327373f;  // 1/sqrt(8)

typedef __attribute__((ext_vector_type(8))) short short8;      // 8 bf16 (4 VGPR)
typedef __attribute__((ext_vector_type(4))) float f32x4;       // MFMA 16x16 acc

__device__ __forceinline__ unsigned short f2bf(float x) {
  __hip_bfloat16 h = __float2bfloat16(x);
  union { __hip_bfloat16 b; unsigned short u; } v; v.b = h;
  return v.u;
}
__device__ __forceinline__ float bf2f(unsigned short x) {
  union { unsigned int u; float f; } v; v.u = ((unsigned int)x) << 16;
  return v.f;
}

// ---------------- adaptive adjacency: softmax(relu(nv1@nv2), axis=1) -> bf16 ----------------
__global__ __launch_bounds__(256) void k_adp(const float* __restrict__ nv1,
                                             const float* __restrict__ nv2,
                                             unsigned short* __restrict__ adp_bf) {
  int w = blockIdx.x, v = threadIdx.x;
  float s = 0.f;
  for (int d = 0; d < 10; ++d) s += nv1[w * 10 + d] * nv2[d * KK + v];
  s = fmaxf(s, 0.f);
  __shared__ float red[256];
  red[v] = s; __syncthreads();
  for (int off = 128; off; off >>= 1) { if (v < off) red[v] = fmaxf(red[v], red[v + off]); __syncthreads(); }
  float m = red[0]; __syncthreads();
  float e = expf(s - m);
  red[v] = e; __syncthreads();
  for (int off = 128; off; off >>= 1) { if (v < off) red[v] += red[v + off]; __syncthreads(); }
  adp_bf[w * KK + v] = f2bf(e / red[0]);
}

// ---------------- fused cast + GN-accumulator zeroing; grid 960 ----------------
__global__ __launch_bounds__(256) void k_castW(const float* __restrict__ s0, const float* __restrict__ s1,
                                               const float* __restrict__ s2,
                                               const float* __restrict__ swo, const float* __restrict__ two,
                                               const float* __restrict__ f1, const float* __restrict__ f2,
                                               const float* __restrict__ swq, const float* __restrict__ swk,
                                               const float* __restrict__ swv,
                                               const float* __restrict__ twq, const float* __restrict__ twk,
                                               const float* __restrict__ twv,
                                               const float* __restrict__ pk, const float* __restrict__ pv,
                                               unsigned short* __restrict__ d0, unsigned short* __restrict__ d1,
                                               unsigned short* __restrict__ d2,
                                               unsigned short* __restrict__ swoT, unsigned short* __restrict__ twoT,
                                               unsigned short* __restrict__ ff1T, unsigned short* __restrict__ ff2T,
                                               unsigned short* __restrict__ swqT, unsigned short* __restrict__ swkT,
                                               unsigned short* __restrict__ swvT,
                                               unsigned short* __restrict__ twqT, unsigned short* __restrict__ twkT,
                                               unsigned short* __restrict__ twvT,
                                               unsigned short* __restrict__ PkT, unsigned short* __restrict__ PvT,
                                               float* __restrict__ partZ) {
  int i = blockIdx.x * 256 + threadIdx.x;
  if (i < 65536) d0[i] = f2bf(s0[i]);
  else if (i < 131072) d1[i - 65536] = f2bf(s1[i - 65536]);
  else if (i < 159744) d2[i - 131072] = f2bf(s2[i - 131072]);
  else if (i < 163840) {
    int z = i - 159744;
    if (z < 48) {
      int off = (z < 16) ? 2048 + z : (z < 32) ? 4096 + (z - 16) : 6144 + (z - 32);
      partZ[off] = 0.f;
    }
  } else {
    int j = i - 163840;
    if (j < 4096) { int r = j >> 6, c = j & 63; swoT[c * 64 + r] = f2bf(swo[j]); }
    else if (j < 8192) { int q = j - 4096; int r = q >> 6, c = q & 63; twoT[c * 64 + r] = f2bf(two[q]); }
    else if (j < 16384) { int q = j - 8192; int r = q >> 7, c = q & 127; ff1T[c * 64 + r] = f2bf(f1[q]); }
    else if (j < 24576) { int q = j - 16384; int r = q >> 6, c = q & 63; ff2T[c * 128 + r] = f2bf(f2[q]); }
    else if (j < 28672) { int q = j - 24576; int r = q >> 6, c = q & 63; swqT[c * 64 + r] = f2bf(swq[q]); }
    else if (j < 32768) { int q = j - 28672; int r = q >> 6, c = q & 63; swkT[c * 64 + r] = f2bf(swk[q]); }
    else if (j < 36864) { int q = j - 32768; int r = q >> 6, c = q & 63; swvT[c * 64 + r] = f2bf(swv[q]); }
    else if (j < 40960) { int q = j - 36864; int r = q >> 6, c = q & 63; twqT[c * 64 + r] = f2bf(twq[q]); }
    else if (j < 45056) { int q = j - 40960; int r = q >> 6, c = q & 63; twkT[c * 64 + r] = f2bf(twk[q]); }
    else if (j < 49152) { int q = j - 45056; int r = q >> 6, c = q & 63; twvT[c * 64 + r] = f2bf(twv[q]); }
    else if (j < 65536) { int q = j - 49152; int n = q >> 6, c = q & 63; PkT[c * 256 + n] = f2bf(pk[q]); }
    else if (j < 81920) { int q = j - 65536; int n = q >> 6, c = q & 63; PvT[c * 256 + n] = f2bf(pv[q]); }
  }
}

// ---------------- s0 term (bf16 out) ----------------
__global__ __launch_bounds__(64) void k_mix0(const unsigned short* __restrict__ Xbf,
                                             const unsigned short* __restrict__ Wbf,
                                             const float* __restrict__ bias,
                                             unsigned short* __restrict__ s0) {
  int pb = blockIdx.x;
  int lh = pb & 1;
  int k = (pb >> 1) & 255;
  int b = pb >> 9;
  int lane = threadIdx.x;
  int lr = lane & 15, g = lane >> 4;
  short8 af[4][2], bfv[4][2];
#pragma unroll
  for (int ot = 0; ot < 4; ++ot)
#pragma unroll
    for (int kc = 0; kc < 2; ++kc)
      af[ot][kc] = *(const short8*)(Wbf + (size_t)(ot * 16 + lr) * 448 + kc * 32 + g * 8);
#pragma unroll
  for (int ct = 0; ct < 4; ++ct)
#pragma unroll
    for (int kc = 0; kc < 2; ++kc)
      bfv[ct][kc] = *(const short8*)(Xbf + ((size_t)(b * 128 + lh * 64 + ct * 16 + lr) * 256 + k) * 64 + kc * 32 + g * 8);
  f32x4 acc[4][4];
#pragma unroll
  for (int ot = 0; ot < 4; ++ot)
#pragma unroll
    for (int ct = 0; ct < 4; ++ct) acc[ot][ct] = f32x4{0.f, 0.f, 0.f, 0.f};
#pragma unroll
  for (int kc = 0; kc < 2; ++kc)
#pragma unroll
    for (int ot = 0; ot < 4; ++ot)
#pragma unroll
      for (int ct = 0; ct < 4; ++ct)
        acc[ot][ct] = __builtin_amdgcn_mfma_f32_16x16x32_bf16(af[ot][kc], bfv[ct][kc], acc[ot][ct], 0, 0, 0);
#pragma unroll
  for (int ot = 0; ot < 4; ++ot)
#pragma unroll
    for (int ct = 0; ct < 4; ++ct) {
#pragma unroll
      for (int reg = 0; reg < 4; ++reg) {
        int o = ot * 16 + g * 4 + reg;
        s0[(size_t)(b * 64 + o) * NN + (size_t)k * 128 + lh * 64 + ct * 16 + lr] = f2bf(acc[ot][ct][reg] + bias[o]);
      }
    }
}

// ---------------- U terms ----------------
__global__ __launch_bounds__(64) void k_mix6(const unsigned short* __restrict__ Xbf,
                                             const unsigned short* __restrict__ Wbf,
                                             unsigned short* __restrict__ U1, unsigned short* __restrict__ U2,
                                             unsigned short* __restrict__ U3, unsigned short* __restrict__ U4,
                                             unsigned short* __restrict__ U5, unsigned short* __restrict__ U6) {
  int pb = blockIdx.x;
  int sy = blockIdx.y;
  int b = pb >> 9;
  int rem = pb & 511;
  int l = rem >> 2;
  int kq = (rem & 3) * 64;
  size_t posbase = ((size_t)(b * 128 + l)) * 256 + kq;
  int lane = threadIdx.x;
  int lr = lane & 15, g = lane >> 4;

  short8 af[4][2];
#pragma unroll
  for (int rt = 0; rt < 4; ++rt)
#pragma unroll
    for (int kc = 0; kc < 2; ++kc)
      af[rt][kc] = *(const short8*)(Xbf + (posbase + rt * 16 + lr) * 64 + kc * 32 + g * 8);

  for (int si = 0; si < 2; ++si) {
    int s = sy * 2 + 1 + si;
    short8 bfv[4][2];
#pragma unroll
    for (int ct = 0; ct < 4; ++ct)
#pragma unroll
      for (int kc = 0; kc < 2; ++kc)
        bfv[ct][kc] = *(const short8*)(Wbf + (size_t)(ct * 16 + lr) * 448 + s * 64 + kc * 32 + g * 8);
    f32x4 acc[4][4];
#pragma unroll
    for (int rt = 0; rt < 4; ++rt)
#pragma unroll
      for (int ct = 0; ct < 4; ++ct) acc[rt][ct] = f32x4{0.f, 0.f, 0.f, 0.f};
#pragma unroll
    for (int kc = 0; kc < 2; ++kc)
#pragma unroll
      for (int rt = 0; rt < 4; ++rt)
#pragma unroll
        for (int ct = 0; ct < 4; ++ct)
          acc[rt][ct] = __builtin_amdgcn_mfma_f32_16x16x32_bf16(af[rt][kc], bfv[ct][kc], acc[rt][ct], 0, 0, 0);
    unsigned short* dst = (s == 1) ? U1 : (s == 2) ? U2 : (s == 3) ? U3
                        : (s == 4) ? U4 : (s == 5) ? U5 : U6;
#pragma unroll
    for (int rt = 0; rt < 4; ++rt)
#pragma unroll
      for (int ct = 0; ct < 4; ++ct) {
        int o = ct * 16 + lr;
        int k = kq + rt * 16 + g * 4;
        ushort4 pk;
        pk.x = f2bf(acc[rt][ct][0]); pk.y = f2bf(acc[rt][ct][1]);
        pk.z = f2bf(acc[rt][ct][2]); pk.w = f2bf(acc[rt][ct][3]);
        *(ushort4*)&dst[((size_t)(b * 64 + o) * 128 + l) * 256 + k] = pk;
      }
  }
}

// ---------------- fused 2-hop (bf16 out) ----------------
__global__ __launch_bounds__(256) void k_adj2M(const unsigned short* __restrict__ Abf,
                                               const unsigned short* __restrict__ Ueven,
                                               const unsigned short* __restrict__ Uodd,
                                               unsigned short* __restrict__ out) {
  __shared__ unsigned short sH[32 * 256];
  int lq = blockIdx.x & 3, bc = blockIdx.x >> 2;
  int tid = threadIdx.x, wid = tid >> 6, lane = tid & 63;
  int lr = lane & 15, g = lane >> 4;
  int wbase = wid * 64;
  const unsigned short* aP = Abf + (size_t)(wbase + lr) * 256 + g * 8;
  const unsigned short* bP = Ueven + ((size_t)bc * 128 + lq * 32 + lr) * 256 + g * 8;

  f32x4 acc[4][2];
#pragma unroll
  for (int i = 0; i < 4; ++i)
#pragma unroll
    for (int j = 0; j < 2; ++j) acc[i][j] = f32x4{0.f, 0.f, 0.f, 0.f};
  for (int k0 = 0; k0 < 256; k0 += 32) {
    short8 af[4], bfv[2];
#pragma unroll
    for (int i = 0; i < 4; ++i) af[i] = *(const short8*)(aP + (size_t)i * 16 * 256 + k0);
#pragma unroll
    for (int i = 0; i < 2; ++i) bfv[i] = *(const short8*)(bP + (size_t)i * 16 * 256 + k0);
#pragma unroll
    for (int rm = 0; rm < 4; ++rm)
#pragma unroll
      for (int cn = 0; cn < 2; ++cn)
        acc[rm][cn] = __builtin_amdgcn_mfma_f32_16x16x32_bf16(af[rm], bfv[cn], acc[rm][cn], 0, 0, 0);
  }
  {
    const unsigned short* aT = Uodd + (size_t)bc * NN + (size_t)(lq * 32) * 256;
#pragma unroll
    for (int rm = 0; rm < 4; ++rm)
#pragma unroll
      for (int cn = 0; cn < 2; ++cn) {
        int l = cn * 16 + lr;
        int v = wbase + rm * 16 + g * 4;
        ushort4 av = *(const ushort4*)&aT[(size_t)l * 256 + v];
        ushort4 pk;
        pk.x = f2bf(acc[rm][cn][0] + bf2f(av.x));
        pk.y = f2bf(acc[rm][cn][1] + bf2f(av.y));
        pk.z = f2bf(acc[rm][cn][2] + bf2f(av.z));
        pk.w = f2bf(acc[rm][cn][3] + bf2f(av.w));
        int bo = ((l * 256 + v) * 2) ^ ((l & 7) << 4);
        *(ushort4*)((char*)sH + bo) = pk;
      }
  }
  __syncthreads();

  f32x4 c2[4][2];
#pragma unroll
  for (int i = 0; i < 4; ++i)
#pragma unroll
    for (int j = 0; j < 2; ++j) c2[i][j] = f32x4{0.f, 0.f, 0.f, 0.f};
  for (int k0 = 0; k0 < 256; k0 += 32) {
    short8 af[4], bfv[2];
#pragma unroll
    for (int i = 0; i < 4; ++i) af[i] = *(const short8*)(aP + (size_t)i * 16 * 256 + k0);
#pragma unroll
    for (int cn = 0; cn < 2; ++cn) {
      int l = cn * 16 + lr;
      int bo = ((l * 256 + k0 + g * 8) * 2) ^ ((l & 7) << 4);
      bfv[cn] = *(const short8*)((char*)sH + bo);
    }
#pragma unroll
    for (int rm = 0; rm < 4; ++rm)
#pragma unroll
      for (int cn = 0; cn < 2; ++cn)
        c2[rm][cn] = __builtin_amdgcn_mfma_f32_16x16x32_bf16(af[rm], bfv[cn], c2[rm][cn], 0, 0, 0);
  }
  unsigned short* dst = out + (size_t)bc * NN + lq * 32;
#pragma unroll
  for (int rm = 0; rm < 4; ++rm)
#pragma unroll
    for (int cn = 0; cn < 2; ++cn) {
      int col = cn * 16 + lr;
      int row = wbase + rm * 16 + g * 4;
#pragma unroll
      for (int j = 0; j < 4; ++j)
        dst[(size_t)(row + j) * 128 + col] = f2bf(c2[rm][cn][j]);
    }
}

// ---------------- generic (c,l)-plane transpose; optional dst/add/bf16 + fused GN partials ----------------
// partA != nullptr is only used for the (nC=128, nL=64) calls, where the 'll' dim is channels.
__global__ __launch_bounds__(256) void k_tr(const float* __restrict__ src, float* __restrict__ dst,
                                            const float* __restrict__ add,
                                            unsigned short* __restrict__ dstBf,
                                            float* __restrict__ partA,
                                            long sb, long sk, long sc, long sl,
                                            long db, long dk, long dc, long dl, int nC, int nL) {
  int outer = blockIdx.x;
  int b = outer >> 8, k = outer & 255;
  int tilesL = nL >> 5;
  int tC = blockIdx.y / tilesL, tL = blockIdx.y % tilesL;
  int c0 = tC << 5, l0 = tL << 5;
  __shared__ float s[32][33];
  int tx = threadIdx.x & 31, ty = threadIdx.x >> 5;
  const float* sp = src + (long)b * sb + (long)k * sk;
#pragma unroll
  for (int j = 0; j < 4; ++j) {
    int cc = c0 + ty + j * 8;
    s[ty + j * 8][tx] = sp[(long)cc * sc + (long)(l0 + tx) * sl];
  }
  __syncthreads();
  long dbase = (long)b * db + (long)k * dk;
  float vals[4];
#pragma unroll
  for (int j = 0; j < 4; ++j) {
    int ll = l0 + ty + j * 8;
    long off = dbase + (long)(c0 + tx) * dc + (long)ll * dl;
    float val = s[tx][ty + j * 8];
    if (add) val += add[off];
    if (dst) dst[off] = val;
    if (dstBf) dstBf[off] = f2bf(val);
    vals[j] = val;
  }
  if (partA) {
    // channels = ll dim; group0 = j in {0,1} (ch 0..15 of tile), group1 = j in {2,3}
    float g0s = vals[0] + vals[1], g1s = vals[2] + vals[3];
    float g0q = vals[0] * vals[0] + vals[1] * vals[1];
    float g1q = vals[2] * vals[2] + vals[3] * vals[3];
#pragma unroll
    for (int off = 32; off; off >>= 1) {
      g0s += __shfl_xor(g0s, off); g0q += __shfl_xor(g0q, off);
      g1s += __shfl_xor(g1s, off); g1q += __shfl_xor(g1q, off);
    }
    __syncthreads();
    float* red = (float*)s;
    int wv = threadIdx.x >> 6;
    if ((threadIdx.x & 63) == 0) {
      red[wv] = g0s; red[wv + 4] = g0q; red[wv + 8] = g1s; red[wv + 12] = g1q;
    }
    __syncthreads();
    if (threadIdx.x < 2) {
      float S, Q;
      if (threadIdx.x == 0) { S = red[0] + red[1] + red[2] + red[3]; Q = red[4] + red[5] + red[6] + red[7]; }
      else                  { S = red[8] + red[9] + red[10] + red[11]; Q = red[12] + red[13] + red[14] + red[15]; }
      int bg = b * 4 + (l0 >> 4) + (int)threadIdx.x;
      atomicAdd(&partA[bg * 2], S);
      atomicAdd(&partA[bg * 2 + 1], Q);
    }
  }
}

// ---------------- spatial QKV (MFMA, bf16 in/out): Q RM; K^T,V^T [bl][c][n] ----------------
__global__ __launch_bounds__(256) void k_qkvs_M(const unsigned short* __restrict__ Xbf,
                                                const unsigned short* __restrict__ wqT,
                                                const unsigned short* __restrict__ wkT,
                                                const unsigned short* __restrict__ wvT,
                                                unsigned short* __restrict__ qb,
                                                unsigned short* __restrict__ xkT,
                                                unsigned short* __restrict__ xvT) {
  int r0 = blockIdx.x * 64;
  int t = threadIdx.x, w = t >> 6, lane = t & 63;
  int lr = lane & 15, g = lane >> 4;
  const unsigned short* aP = Xbf + (size_t)(r0 + w * 16 + lr) * 64 + g * 8;
  short8 ax0 = *(const short8*)aP;
  short8 ax1 = *(const short8*)(aP + 32);
  {
    f32x4 acc[4];
#pragma unroll
    for (int ct = 0; ct < 4; ++ct) acc[ct] = f32x4{0.f, 0.f, 0.f, 0.f};
#pragma unroll
    for (int ct = 0; ct < 4; ++ct) {
      short8 b0 = *(const short8*)(wqT + (size_t)(ct * 16 + lr) * 64 + g * 8);
      short8 b1 = *(const short8*)(wqT + (size_t)(ct * 16 + lr) * 64 + 32 + g * 8);
      acc[ct] = __builtin_amdgcn_mfma_f32_16x16x32_bf16(ax0, b0, acc[ct], 0, 0, 0);
      acc[ct] = __builtin_amdgcn_mfma_f32_16x16x32_bf16(ax1, b1, acc[ct], 0, 0, 0);
    }
#pragma unroll
    for (int ct = 0; ct < 4; ++ct)
#pragma unroll
      for (int reg = 0; reg < 4; ++reg)
        qb[(size_t)(r0 + w * 16 + g * 4 + reg) * 64 + ct * 16 + lr] = f2bf(acc[ct][reg]);
  }
  short8 bx0[4], bx1[4];
#pragma unroll
  for (int ct = 0; ct < 4; ++ct) {
    const unsigned short* bP = Xbf + (size_t)(r0 + ct * 16 + lr) * 64 + g * 8;
    bx0[ct] = *(const short8*)bP;
    bx1[ct] = *(const short8*)(bP + 32);
  }
  int bl = r0 >> 8, nb = r0 & 255;
#pragma unroll
  for (int which = 0; which < 2; ++which) {
    const unsigned short* WT = which ? wvT : wkT;
    unsigned short* dstb = which ? xvT : xkT;
    short8 aw0 = *(const short8*)(WT + (size_t)(w * 16 + lr) * 64 + g * 8);
    short8 aw1 = *(const short8*)(WT + (size_t)(w * 16 + lr) * 64 + 32 + g * 8);
    f32x4 acc[4];
#pragma unroll
    for (int ct = 0; ct < 4; ++ct) {
      acc[ct] = f32x4{0.f, 0.f, 0.f, 0.f};
      acc[ct] = __builtin_amdgcn_mfma_f32_16x16x32_bf16(aw0, bx0[ct], acc[ct], 0, 0, 0);
      acc[ct] = __builtin_amdgcn_mfma_f32_16x16x32_bf16(aw1, bx1[ct], acc[ct], 0, 0, 0);
    }
#pragma unroll
    for (int ct = 0; ct < 4; ++ct)
#pragma unroll
      for (int reg = 0; reg < 4; ++reg) {
        int o = w * 16 + g * 4 + reg;
        dstb[(size_t)bl * 16384 + (size_t)o * 256 + nb + ct * 16 + lr] = f2bf(acc[ct][reg]);
      }
  }
}

// ---------------- temporal QKV (MFMA, bf16 in/out); V^T stored with sigma-permuted l-columns ----------------
__global__ __launch_bounds__(256) void k_qkvt_M(const unsigned short* __restrict__ Xbf,
                                                const unsigned short* __restrict__ wqT,
                                                const unsigned short* __restrict__ wkT,
                                                const unsigned short* __restrict__ wvT,
                                                const float* __restrict__ bq, const float* __restrict__ bk_,
                                                const float* __restrict__ bv,
                                                unsigned short* __restrict__ qb,
                                                unsigned short* __restrict__ kb,
                                                unsigned short* __restrict__ vt) {
  int r0 = blockIdx.x * 64;
  int t = threadIdx.x, w = t >> 6, lane = t & 63;
  int lr = lane & 15, g = lane >> 4;
  const unsigned short* aP = Xbf + (size_t)(r0 + w * 16 + lr) * 64 + g * 8;
  short8 ax0 = *(const short8*)aP;
  short8 ax1 = *(const short8*)(aP + 32);
#pragma unroll
  for (int which = 0; which < 2; ++which) {
    const unsigned short* WT = which ? wkT : wqT;
    const float* bias = which ? bk_ : bq;
    unsigned short* dstb = which ? kb : qb;
    f32x4 acc[4];
#pragma unroll
    for (int ct = 0; ct < 4; ++ct) {
      acc[ct] = f32x4{0.f, 0.f, 0.f, 0.f};
      short8 b0 = *(const short8*)(WT + (size_t)(ct * 16 + lr) * 64 + g * 8);
      short8 b1 = *(const short8*)(WT + (size_t)(ct * 16 + lr) * 64 + 32 + g * 8);
      acc[ct] = __builtin_amdgcn_mfma_f32_16x16x32_bf16(ax0, b0, acc[ct], 0, 0, 0);
      acc[ct] = __builtin_amdgcn_mfma_f32_16x16x32_bf16(ax1, b1, acc[ct], 0, 0, 0);
    }
#pragma unroll
    for (int ct = 0; ct < 4; ++ct) {
      float bvv = bias[ct * 16 + lr];
#pragma unroll
      for (int reg = 0; reg < 4; ++reg)
        dstb[(size_t)(r0 + w * 16 + g * 4 + reg) * 64 + ct * 16 + lr] = f2bf(acc[ct][reg] + bvv);
    }
  }
  short8 bx0[4], bx1[4];
#pragma unroll
  for (int ct = 0; ct < 4; ++ct) {
    const unsigned short* bP = Xbf + (size_t)(r0 + ct * 16 + lr) * 64 + g * 8;
    bx0[ct] = *(const short8*)bP;
    bx1[ct] = *(const short8*)(bP + 32);
  }
  int bkk = r0 >> 7, lbase = r0 & 127;
  short8 aw0 = *(const short8*)(wvT + (size_t)(w * 16 + lr) * 64 + g * 8);
  short8 aw1 = *(const short8*)(wvT + (size_t)(w * 16 + lr) * 64 + 32 + g * 8);
  f32x4 acc[4];
#pragma unroll
  for (int ct = 0; ct < 4; ++ct) {
    acc[ct] = f32x4{0.f, 0.f, 0.f, 0.f};
    acc[ct] = __builtin_amdgcn_mfma_f32_16x16x32_bf16(aw0, bx0[ct], acc[ct], 0, 0, 0);
    acc[ct] = __builtin_amdgcn_mfma_f32_16x16x32_bf16(aw1, bx1[ct], acc[ct], 0, 0, 0);
  }
  int lb4 = lbase >> 4;   // 0 or 4
#pragma unroll
  for (int ct = 0; ct < 4; ++ct)
#pragma unroll
    for (int reg = 0; reg < 4; ++reg) {
      int o = w * 16 + g * 4 + reg;
      vt[(size_t)bkk * 8192 + (size_t)o * 128 + lr * 8 + lb4 + ct] = f2bf(acc[ct][reg] + bv[o]);
    }
}

// ---------------- MFMA sproj; V^T output stored with sigma-permuted p-columns ----------------
__global__ __launch_bounds__(256) void k_sprojM(const unsigned short* __restrict__ XkT,
                                                const unsigned short* __restrict__ XvT,
                                                const unsigned short* __restrict__ PkT,
                                                const unsigned short* __restrict__ PvT,
                                                unsigned short* __restrict__ kpb,
                                                unsigned short* __restrict__ vptb) {
  int bl = blockIdx.x;
  int which = blockIdx.y;
  int t = threadIdx.x, w = t >> 6, lane = t & 63;
  int lr = lane & 15, g = lane >> 4;
  const unsigned short* Abase = which ? PvT : XkT + (size_t)bl * 16384;
  const unsigned short* Bbase = which ? XvT + (size_t)bl * 16384 : PkT;
  const unsigned short* aP = Abase + (size_t)(w * 16 + lr) * 256 + g * 8;
  f32x4 acc[4];
#pragma unroll
  for (int ct = 0; ct < 4; ++ct) acc[ct] = f32x4{0.f, 0.f, 0.f, 0.f};
  for (int k0 = 0; k0 < 256; k0 += 32) {
    short8 af = *(const short8*)(aP + k0);
#pragma unroll
    for (int ct = 0; ct < 4; ++ct) {
      short8 bf = *(const short8*)(Bbase + (size_t)(ct * 16 + lr) * 256 + k0 + g * 8);
      acc[ct] = __builtin_amdgcn_mfma_f32_16x16x32_bf16(af, bf, acc[ct], 0, 0, 0);
    }
  }
  if (!which) {
    unsigned short* dst = kpb + (size_t)bl * 4096;
#pragma unroll
    for (int ct = 0; ct < 4; ++ct) {
      int p = ct * 16 + lr;
      int c0 = w * 16 + g * 4;
      ushort4 pk;
      pk.x = f2bf(acc[ct][0]); pk.y = f2bf(acc[ct][1]);
      pk.z = f2bf(acc[ct][2]); pk.w = f2bf(acc[ct][3]);
      *(ushort4*)&dst[(size_t)p * 64 + c0] = pk;
    }
  } else {
    unsigned short* dst = vptb + (size_t)bl * 4096;
#pragma unroll
    for (int ct = 0; ct < 4; ++ct) {
      int c = ct * 16 + lr;
#pragma unroll
      for (int reg = 0; reg < 4; ++reg)
        dst[(size_t)c * 64 + (g * 4 + reg) * 4 + w] = f2bf(acc[ct][reg]);
    }
  }
}

// ---------------- fused channel FFN (MFMA) ----------------
__global__ __launch_bounds__(256) void k_cffn(const unsigned short* __restrict__ in,
                                              const unsigned short* __restrict__ ff1T,
                                              const unsigned short* __restrict__ ff2T,
                                              const float* __restrict__ b1,
                                              const float* __restrict__ b2,
                                              float* __restrict__ out) {
  __shared__ unsigned short sH[4][16 * 128];
  int r0 = blockIdx.x * 64;
  int t = threadIdx.x, w = t >> 6, lane = t & 63;
  int lr = lane & 15, g = lane >> 4;
  unsigned short* myH = sH[w];
  const unsigned short* aP = in + (size_t)(r0 + w * 16 + lr) * 64 + g * 8;
  short8 af0 = *(const short8*)aP;
  short8 af1 = *(const short8*)(aP + 32);
  f32x4 acc1[8];
#pragma unroll
  for (int ct = 0; ct < 8; ++ct) acc1[ct] = f32x4{0.f, 0.f, 0.f, 0.f};
#pragma unroll
  for (int ct = 0; ct < 8; ++ct) {
    short8 b0 = *(const short8*)(ff1T + (size_t)(ct * 16 + lr) * 64 + g * 8);
    short8 bx = *(const short8*)(ff1T + (size_t)(ct * 16 + lr) * 64 + 32 + g * 8);
    acc1[ct] = __builtin_amdgcn_mfma_f32_16x16x32_bf16(af0, b0, acc1[ct], 0, 0, 0);
    acc1[ct] = __builtin_amdgcn_mfma_f32_16x16x32_bf16(af1, bx, acc1[ct], 0, 0, 0);
  }
#pragma unroll
  for (int ct = 0; ct < 8; ++ct) {
    int o = ct * 16 + lr;
    float bv = b1[o];
#pragma unroll
    for (int reg = 0; reg < 4; ++reg) {
      int m = g * 4 + reg;
      float h = fmaxf(acc1[ct][reg] + bv, 0.f);
      int bo = ((m * 128 + o) * 2) ^ ((m & 7) << 4);
      *(unsigned short*)((char*)myH + bo) = f2bf(h);
    }
  }
  __syncthreads();
  short8 ha[4];
#pragma unroll
  for (int ks = 0; ks < 4; ++ks) {
    int bo = ((lr * 128 + ks * 32 + g * 8) * 2) ^ ((lr & 7) << 4);
    ha[ks] = *(const short8*)((char*)myH + bo);
  }
  f32x4 acc2[4];
#pragma unroll
  for (int ct = 0; ct < 4; ++ct) acc2[ct] = f32x4{0.f, 0.f, 0.f, 0.f};
#pragma unroll
  for (int ct = 0; ct < 4; ++ct)
#pragma unroll
    for (int ks = 0; ks < 4; ++ks) {
      short8 b0 = *(const short8*)(ff2T + (size_t)(ct * 16 + lr) * 128 + ks * 32 + g * 8);
      acc2[ct] = __builtin_amdgcn_mfma_f32_16x16x32_bf16(ha[ks], b0, acc2[ct], 0, 0, 0);
    }
#pragma unroll
  for (int ct = 0; ct < 4; ++ct) {
    int o = ct * 16 + lr;
    float bv = b2[o];
#pragma unroll
    for (int reg = 0; reg < 4; ++reg)
      out[(size_t)(r0 + w * 16 + g * 4 + reg) * 64 + o] = acc2[ct][reg] + bv;
  }
}

// ---------------- fused LN1 -> FFN(64->8 gelu ->64) -> LN2 ----------------
__global__ __launch_bounds__(256) void k_tffn(const float* __restrict__ A, const float* __restrict__ Bz,
                                              const float* __restrict__ l1w, const float* __restrict__ l1b,
                                              const float* __restrict__ l2w, const float* __restrict__ l2b,
                                              const float* __restrict__ ln1g, const float* __restrict__ ln1b,
                                              const float* __restrict__ ln2g, const float* __restrict__ ln2b,
                                              float* __restrict__ outp) {
  int r0 = blockIdx.x * 64;
  __shared__ float sSrc[64][65];
  __shared__ float sH[64][8];
  __shared__ float sW1[64][8];
  __shared__ float sW2[8][64];
  int t = threadIdx.x;
  for (int i = t; i < 512; i += 256) { ((float*)sW1)[i] = l1w[i]; ((float*)sW2)[i] = l2w[i]; }
  int c = t & 63, rg = t >> 6;
  float g1 = ln1g[c], be1 = ln1b[c];
  for (int it = 0; it < 16; ++it) {
    int r = it * 4 + rg;
    size_t idx = (size_t)(r0 + r) * 64 + c;
    float x = A[idx] + Bz[idx];
    float s = x, ss = x * x;
#pragma unroll
    for (int off = 32; off; off >>= 1) { s += __shfl_xor(s, off); ss += __shfl_xor(ss, off); }
    float mu = s * (1.f / 64.f);
    float var = ss * (1.f / 64.f) - mu * mu;
    sSrc[r][c] = (x - mu) * rsqrtf(var + EPSV) * g1 + be1;
  }
  __syncthreads();
#pragma unroll
  for (int p = 0; p < 2; ++p) {
    int idx = t + 256 * p;
    int row = idx >> 3, j = idx & 7;
    float acc = l1b[j];
    for (int cc = 0; cc < 64; ++cc) acc += sSrc[row][cc] * sW1[cc][j];
    acc = 0.5f * acc * (1.f + erff(acc * 0.70710678118654752440f));
    sH[row][j] = acc;
  }
  __syncthreads();
  float g2 = ln2g[c], be2 = ln2b[c];
  float l2bc = l2b[c];
  for (int it = 0; it < 16; ++it) {
    int r = it * 4 + rg;
    float o = l2bc;
#pragma unroll
    for (int j = 0; j < 8; ++j) o += sH[r][j] * sW2[j][c];
    float x = sSrc[r][c] + o;
    float s = x, ss = x * x;
#pragma unroll
    for (int off = 32; off; off >>= 1) { s += __shfl_xor(s, off); ss += __shfl_xor(ss, off); }
    float mu = s * (1.f / 64.f);
    float var = ss * (1.f / 64.f) - mu * mu;
    outp[(size_t)(r0 + r) * 64 + c] = (x - mu) * rsqrtf(var + EPSV) * g2 + be2;
  }
}

// ---------------- per-head MFMA attention + fused output projection -> fp32 ----------------
template <int NKV, int KVSHIFT>
__global__ __launch_bounds__(512) void k_attnP(const unsigned short* __restrict__ Qb,
                                               const unsigned short* __restrict__ Kb,
                                               const unsigned short* __restrict__ VTb,
                                               const unsigned short* __restrict__ WT,
                                               const float* __restrict__ bias,
                                               float* __restrict__ out) {
  constexpr int NCT = NKV / 16;
  constexpr int NKS = NKV / 32;
  int blk = blockIdx.x;
  const unsigned short* Qp = Qb + (size_t)blk * 128 * 64;
  const unsigned short* Kp = Kb + (size_t)(blk >> KVSHIFT) * NKV * 64;
  const unsigned short* VTp = VTb + (size_t)(blk >> KVSHIFT) * 64 * NKV;
  int t = threadIdx.x;
  int h = t >> 6, lane = t & 63, lr = lane & 15, g = lane >> 4;
  __shared__ unsigned short sP[8][16 * NKV];
  __shared__ unsigned short sO[128 * 64];
  unsigned short* myP = sP[h];

  short8 kbf[NCT];
#pragma unroll
  for (int ct = 0; ct < NCT; ++ct)
    kbf[ct] = *(const short8*)(Kp + (size_t)(ct * 16 + lr) * 64 + h * 8);

  short8 vbf[NKS];
  if (lr < 8) {
    int vr = h * 8 + lr;
#pragma unroll
    for (int ks = 0; ks < NKS; ++ks)
      vbf[ks] = *(const short8*)(VTp + (size_t)vr * NKV + ks * 32 + g * 8);
  } else if (lr == 8) {
    const short ONE = (short)0x3F80;  // bf16 1.0
#pragma unroll
    for (int ks = 0; ks < NKS; ++ks)
      vbf[ks] = short8{ONE, ONE, ONE, ONE, ONE, ONE, ONE, ONE};
  } else {
#pragma unroll
    for (int ks = 0; ks < NKS; ++ks)
      vbf[ks] = short8{0, 0, 0, 0, 0, 0, 0, 0};
  }
  int srcl = (lane & 48) | 8;

  for (int mt = 0; mt < 8; ++mt) {
    short8 qa = short8{0, 0, 0, 0, 0, 0, 0, 0};
    if (g == 0) qa = *(const short8*)(Qp + (size_t)(mt * 16 + lr) * 64 + h * 8);

    f32x4 sacc[NCT];
#pragma unroll
    for (int ct = 0; ct < NCT; ++ct) sacc[ct] = f32x4{0.f, 0.f, 0.f, 0.f};
#pragma unroll
    for (int ct = 0; ct < NCT; ++ct)
      sacc[ct] = __builtin_amdgcn_mfma_f32_16x16x32_bf16(qa, kbf[ct], sacc[ct], 0, 0, 0);

#pragma unroll
    for (int ct = 0; ct < NCT; ++ct)
#pragma unroll
      for (int reg = 0; reg < 4; ++reg)
        sacc[ct][reg] = __expf(sacc[ct][reg] * SCL);

#pragma unroll
    for (int reg = 0; reg < 4; ++reg) {
      int row = g * 4 + reg;
#pragma unroll
      for (int c4 = 0; c4 < NCT; c4 += 4) {
        ushort4 pk;
        pk.x = f2bf(sacc[c4 + 0][reg]); pk.y = f2bf(sacc[c4 + 1][reg]);
        pk.z = f2bf(sacc[c4 + 2][reg]); pk.w = f2bf(sacc[c4 + 3][reg]);
        int bo = ((row * NKV + lr * NCT + c4) * 2) ^ ((row & 7) << 4);
        *(ushort4*)((char*)myP + bo) = pk;
      }
    }

    f32x4 oacc = f32x4{0.f, 0.f, 0.f, 0.f};
#pragma unroll
    for (int ks = 0; ks < NKS; ++ks) {
      int bo = ((lr * NKV + ks * 32 + g * 8) * 2) ^ ((lr & 7) << 4);
      short8 pa = *(const short8*)((char*)myP + bo);
      oacc = __builtin_amdgcn_mfma_f32_16x16x32_bf16(pa, vbf[ks], oacc, 0, 0, 0);
    }
    float inv4[4];
#pragma unroll
    for (int reg = 0; reg < 4; ++reg)
      inv4[reg] = 1.f / __shfl(oacc[reg], srcl);
    if (lr < 8) {
#pragma unroll
      for (int reg = 0; reg < 4; ++reg) {
        int row = mt * 16 + g * 4 + reg;
        int col = h * 8 + lr;
        int bo = ((row * 64 + col) * 2) ^ ((row & 7) << 4);
        *(unsigned short*)((char*)sO + bo) = f2bf(oacc[reg] * inv4[reg]);
      }
    }
  }
  __syncthreads();

  int row = h * 16 + lr;
  int bo0 = ((row * 64 + g * 8) * 2) ^ ((row & 7) << 4);
  int bo1 = ((row * 64 + 32 + g * 8) * 2) ^ ((row & 7) << 4);
  short8 af0 = *(const short8*)((char*)sO + bo0);
  short8 af1 = *(const short8*)((char*)sO + bo1);
  f32x4 acc[4];
#pragma unroll
  for (int ct = 0; ct < 4; ++ct) acc[ct] = f32x4{0.f, 0.f, 0.f, 0.f};
#pragma unroll
  for (int ct = 0; ct < 4; ++ct) {
    short8 b0 = *(const short8*)(WT + (size_t)(ct * 16 + lr) * 64 + g * 8);
    short8 b1 = *(const short8*)(WT + (size_t)(ct * 16 + lr) * 64 + 32 + g * 8);
    acc[ct] = __builtin_amdgcn_mfma_f32_16x16x32_bf16(af0, b0, acc[ct], 0, 0, 0);
    acc[ct] = __builtin_amdgcn_mfma_f32_16x16x32_bf16(af1, b1, acc[ct], 0, 0, 0);
  }
  float* op = out + (size_t)blk * 128 * 64;
#pragma unroll
  for (int ct = 0; ct < 4; ++ct) {
    int o = ct * 16 + lr;
    float bv = bias[o];
#pragma unroll
    for (int reg = 0; reg < 4; ++reg)
      op[(size_t)(h * 16 + g * 4 + reg) * 64 + o] = acc[ct][reg] + bv;
  }
}

// ---------------- GroupNorm stats: y(fp32) + 4 bf16 -> bf16 sum + partials (64-chunk) ----------------
__global__ __launch_bounds__(256) void k_gn_partB(const float* __restrict__ p0,
                                                  const unsigned short* __restrict__ q1,
                                                  const unsigned short* __restrict__ q2,
                                                  const unsigned short* __restrict__ q3,
                                                  const unsigned short* __restrict__ q4,
                                                  unsigned short* __restrict__ sumOut,
                                                  float* __restrict__ part) {
  int bg = blockIdx.y, blk = blockIdx.x, t = threadIdx.x;
  size_t start = (size_t)bg * ((size_t)CPG * NN) + (size_t)blk * 8192;
  const float4* f0 = (const float4*)(p0 + start);
  const ushort4* b1 = (const ushort4*)(q1 + start);
  const ushort4* b2 = (const ushort4*)(q2 + start);
  const ushort4* b3 = (const ushort4*)(q3 + start);
  const ushort4* b4 = (const ushort4*)(q4 + start);
  ushort4* so = (ushort4*)(sumOut + start);
  float s = 0.f, ss = 0.f;
  for (int i = t; i < 2048; i += 256) {
    float4 x = f0[i];
    ushort4 u;
    u = b1[i]; x.x += bf2f(u.x); x.y += bf2f(u.y); x.z += bf2f(u.z); x.w += bf2f(u.w);
    u = b2[i]; x.x += bf2f(u.x); x.y += bf2f(u.y); x.z += bf2f(u.z); x.w += bf2f(u.w);
    u = b3[i]; x.x += bf2f(u.x); x.y += bf2f(u.y); x.z += bf2f(u.z); x.w += bf2f(u.w);
    u = b4[i]; x.x += bf2f(u.x); x.y += bf2f(u.y); x.z += bf2f(u.z); x.w += bf2f(u.w);
    ushort4 pk;
    pk.x = f2bf(x.x); pk.y = f2bf(x.y); pk.z = f2bf(x.z); pk.w = f2bf(x.w);
    so[i] = pk;
    s += x.x + x.y + x.z + x.w;
    ss += x.x * x.x + x.y * x.y + x.z * x.z + x.w * x.w;
  }
  __shared__ float rs[256], rq[256];
  rs[t] = s; rq[t] = ss; __syncthreads();
  for (int off = 128; off; off >>= 1) { if (t < off) { rs[t] += rs[t + off]; rq[t] += rq[t + off]; } __syncthreads(); }
  if (t == 0) { part[(bg * 64 + blk) * 2] = rs[0]; part[(bg * 64 + blk) * 2 + 1] = rq[0]; }
}

// out = GN(p0); single accumulated (sum,ss) pair per bg at pA
__global__ __launch_bounds__(256) void k_gn_apply(const float* __restrict__ p0,
                                                  const float* __restrict__ pA, const float* __restrict__ g,
                                                  const float* __restrict__ be,
                                                  float* __restrict__ out) {
  size_t i4 = (size_t)blockIdx.x * 256 + threadIdx.x;
  size_t i = i4 * 4;
  int chan = (int)(i >> 15) & 63;
  int bg = (int)(i >> 19);
  __shared__ float smu, srr;
  if (threadIdx.x == 0) {
    float inv = 1.f / (float)((size_t)CPG * NN);
    float mu = pA[bg * 2] * inv;
    float var = pA[bg * 2 + 1] * inv - mu * mu;
    smu = mu; srr = rsqrtf(var + EPSV);
  }
  __syncthreads();
  float mu = smu, rr = srr;
  float4 x = ((const float4*)p0)[i4];
  float gc = g[chan], bc = be[chan];
  float4 v;
  v.x = (x.x - mu) * rr * gc + bc;
  v.y = (x.y - mu) * rr * gc + bc;
  v.z = (x.z - mu) * rr * gc + bc;
  v.w = (x.w - mu) * rr * gc + bc;
  ((float4*)out)[i4] = v;
}

// out = GN_l(SLb) + GN_s(SSb) + GN_t(STb); bf16 inputs.
// which0: 64-chunk partials at part+0; which1/2: single pairs at part+2048 / part+4096.
__global__ __launch_bounds__(256) void k_gn_apply3B(const unsigned short* __restrict__ SLb,
                                                    const unsigned short* __restrict__ SSb,
                                                    const unsigned short* __restrict__ STb,
                                                    const float* __restrict__ part,
                                                    const float* __restrict__ gl, const float* __restrict__ bl_,
                                                    const float* __restrict__ gs, const float* __restrict__ bs_,
                                                    const float* __restrict__ gt, const float* __restrict__ bt_,
                                                    float* __restrict__ out) {
  size_t i4 = (size_t)blockIdx.x * 256 + threadIdx.x;
  size_t i = i4 * 4;
  int chan = (int)(i >> 15) & 63;
  int bg = (int)(i >> 19);
  __shared__ float smu[3], srr[3];
  int t = threadIdx.x;
  float inv = 1.f / (float)((size_t)CPG * NN);
  if (t < 64) {
    float s = part[(bg * 64 + t) * 2], ss = part[(bg * 64 + t) * 2 + 1];
#pragma unroll
    for (int off = 32; off; off >>= 1) { s += __shfl_xor(s, off); ss += __shfl_xor(ss, off); }
    if (t == 0) {
      float mu = s * inv;
      float var = ss * inv - mu * mu;
      smu[0] = mu; srr[0] = rsqrtf(var + EPSV);
    }
  } else if (t == 64) {
    float mu = part[2048 + bg * 2] * inv;
    float var = part[2048 + bg * 2 + 1] * inv - mu * mu;
    smu[1] = mu; srr[1] = rsqrtf(var + EPSV);
  } else if (t == 65) {
    float mu = part[4096 + bg * 2] * inv;
    float var = part[4096 + bg * 2 + 1] * inv - mu * mu;
    smu[2] = mu; srr[2] = rsqrtf(var + EPSV);
  }
  __syncthreads();
  float gL = gl[chan] * srr[0], bL = bl_[chan] - smu[0] * gl[chan] * srr[0];
  float gS = gs[chan] * srr[1], bS = bs_[chan] - smu[1] * gs[chan] * srr[1];
  float gT = gt[chan] * srr[2], bT = bt_[chan] - smu[2] * gt[chan] * srr[2];
  ushort4 ul = ((const ushort4*)SLb)[i4];
  ushort4 us = ((const ushort4*)SSb)[i4];
  ushort4 ut = ((const ushort4*)STb)[i4];
  float4 v;
  v.x = bf2f(ul.x) * gL + bL + bf2f(us.x) * gS + bS + bf2f(ut.x) * gT + bT;
  v.y = bf2f(ul.y) * gL + bL + bf2f(us.y) * gS + bS + bf2f(ut.y) * gT + bT;
  v.z = bf2f(ul.z) * gL + bL + bf2f(us.z) * gS + bS + bf2f(ut.z) * gT + bT;
  v.w = bf2f(ul.w) * gL + bL + bf2f(us.w) * gS + bS + bf2f(ut.w) * gT + bT;
  ((float4*)out)[i4] = v;
}

extern "C" void kernel_launch(void* const* d_in, const int* in_sizes, int n_in,
                              void* d_out, int out_size, void* d_ws, size_t ws_size,
                              hipStream_t stream) {
  (void)in_sizes; (void)n_in; (void)out_size; (void)ws_size;
  const float* y     = (const float*)d_in[0];
  const float* a1    = (const float*)d_in[1];
  const float* a2    = (const float*)d_in[2];
  const float* nv1   = (const float*)d_in[3];
  const float* nv2   = (const float*)d_in[4];
  const float* gcn_w = (const float*)d_in[5];
  const float* gcn_b = (const float*)d_in[6];
  const float* s_wq  = (const float*)d_in[7];
  const float* s_wk  = (const float*)d_in[8];
  const float* s_wv  = (const float*)d_in[9];
  const float* s_pk  = (const float*)d_in[10];
  const float* s_pv  = (const float*)d_in[11];
  const float* s_wo  = (const float*)d_in[12];
  const float* s_bo  = (const float*)d_in[13];
  const float* t_wq  = (const float*)d_in[14];
  const float* t_wk  = (const float*)d_in[15];
  const float* t_wv  = (const float*)d_in[16];
  const float* t_bq  = (const float*)d_in[17];
  const float* t_bk  = (const float*)d_in[18];
  const float* t_bv  = (const float*)d_in[19];
  const float* t_wo  = (const float*)d_in[20];
  const float* t_bo  = (const float*)d_in[21];
  const float* t_l1w = (const float*)d_in[22];
  const float* t_l1b = (const float*)d_in[23];
  const float* t_l2w = (const float*)d_in[24];
  const float* t_l2b = (const float*)d_in[25];
  const float* ln1g  = (const float*)d_in[26];
  const float* ln1b  = (const float*)d_in[27];
  const float* ln2g  = (const float*)d_in[28];
  const float* ln2b  = (const float*)d_in[29];
  const float* gnlg  = (const float*)d_in[30];
  const float* gnlb  = (const float*)d_in[31];
  const float* gnsg  = (const float*)d_in[32];
  const float* gnsb  = (const float*)d_in[33];
  const float* gntg  = (const float*)d_in[34];
  const float* gntb  = (const float*)d_in[35];
  const float* ff1w  = (const float*)d_in[36];
  const float* ff1b  = (const float*)d_in[37];
  const float* ff2w  = (const float*)d_in[38];
  const float* ff2b  = (const float*)d_in[39];
  const float* gn2g  = (const float*)d_in[40];
  const float* gn2b  = (const float*)d_in[41];

  float* ws = (float*)d_ws;
  float* part  = ws + 65536;
  unsigned short* a1_bf   = (unsigned short*)(ws + 131072);
  unsigned short* a2_bf   = (unsigned short*)(ws + 163840);
  unsigned short* adp_bf  = (unsigned short*)(ws + 196608);
  unsigned short* gcnw_bf = (unsigned short*)(ws + 229376);
  unsigned short* xs_bf   = (unsigned short*)(ws + 262144);
  unsigned short* swoT = (unsigned short*)(ws + 2359296);
  unsigned short* twoT = (unsigned short*)(ws + 2361344);
  unsigned short* ff1T = (unsigned short*)(ws + 2363392);
  unsigned short* ff2T = (unsigned short*)(ws + 2367488);
  unsigned short* swqT = (unsigned short*)(ws + 2371584);
  unsigned short* swkT = (unsigned short*)(ws + 2373632);
  unsigned short* swvT = (unsigned short*)(ws + 2375680);
  unsigned short* twqT = (unsigned short*)(ws + 2377728);
  unsigned short* twkT = (unsigned short*)(ws + 2379776);
  unsigned short* twvT = (unsigned short*)(ws + 2381824);
  unsigned short* PkT  = (unsigned short*)(ws + 2383872);
  unsigned short* PvT  = (unsigned short*)(ws + 2392064);
  unsigned short* kpb  = (unsigned short*)(ws + 131072);
  unsigned short* vptb = (unsigned short*)(ws + 1179648);
  const size_t SLOT = 4194304;
  float* G0 = ws + SLOT * 1;
  float* G1 = ws + SLOT * 2;
  float* G2 = ws + SLOT * 3;
  float* G3 = ws + SLOT * 4;
  float* G4 = ws + SLOT * 5;
  float* G5 = ws + SLOT * 6;
  float* G6 = ws + SLOT * 7;
  unsigned short* U1 = (unsigned short*)G3;
  unsigned short* U2 = (unsigned short*)G3 + 4194304;
  unsigned short* U3 = (unsigned short*)G4;
  unsigned short* U4 = (unsigned short*)G4 + 4194304;
  unsigned short* U5 = (unsigned short*)G5;
  unsigned short* U6 = (unsigned short*)G5 + 4194304;
  unsigned short* s0bf = (unsigned short*)G1;
  unsigned short* Q1bf = (unsigned short*)G0;
  unsigned short* Q3bf = (unsigned short*)G0 + 4194304;
  unsigned short* Q2bf = (unsigned short*)G6;
  unsigned short* SLb  = (unsigned short*)G3;   // GCN branch sum (bf16)
  unsigned short* SSb  = (unsigned short*)G1;   // spatial branch sum
  unsigned short* STb  = (unsigned short*)G2;   // temporal branch sum
  unsigned short* qbuf = (unsigned short*)G0;
  unsigned short* xkT = (unsigned short*)G4;
  unsigned short* xvT = (unsigned short*)G5;
  unsigned short* kbuf = (unsigned short*)G4;
  unsigned short* vtbuf = (unsigned short*)G5;
  unsigned short* xt_bf = (unsigned short*)G6;
  float* out = (float*)d_out;

  const long BS = 2097152;

  // ---- setup casts (+ zero GN atomic accumulators at part+2048/+4096/+6144) ----
  k_adp<<<256, 256, 0, stream>>>(nv1, nv2, adp_bf);
  k_castW<<<960, 256, 0, stream>>>(a1, a2, gcn_w, s_wo, t_wo, ff1w, ff2w,
                                   s_wq, s_wk, s_wv, t_wq, t_wk, t_wv, s_pk, s_pv,
                                   a1_bf, a2_bf, gcnw_bf, swoT, twoT, ff1T, ff2T,
                                   swqT, swkT, swvT, twqT, twkT, twvT, PkT, PvT, part);

  // ---- xs bf16 (B,L,K,C) ----
  k_tr<<<dim3(512, 8), 256, 0, stream>>>(y, nullptr, nullptr, xs_bf, nullptr,
                                         BS, 128, 32768, 1, BS, 64, 1, 16384, 64, 128);

  // ---- AdaptiveGCN: branch sum (bf16) -> G3, partials -> part+0 ----
  k_mix0<<<1024, 64, 0, stream>>>(xs_bf, gcnw_bf, gcn_b, s0bf);
  k_mix6<<<dim3(1024, 3), 64, 0, stream>>>(xs_bf, gcnw_bf, U1, U2, U3, U4, U5, U6);
  k_adj2M<<<512, 256, 0, stream>>>(a1_bf, U2, U1, Q1bf);
  k_adj2M<<<512, 256, 0, stream>>>(a2_bf, U4, U3, Q2bf);
  k_adj2M<<<512, 256, 0, stream>>>(adp_bf, U6, U5, Q3bf);
  k_gn_partB<<<dim3(64, 8), 256, 0, stream>>>(y, s0bf, Q1bf, Q2bf, Q3bf, SLb, part);

  // ---- Linformer spatial attention: attn+proj fused -> G4 fp32; tr fuses GN stats ----
  k_qkvs_M<<<1024, 256, 0, stream>>>(xs_bf, swqT, swkT, swvT, qbuf, xkT, xvT);
  k_sprojM<<<dim3(256, 2), 256, 0, stream>>>(xkT, xvT, PkT, PvT, kpb, vptb);
  k_attnP<64, 1><<<512, 512, 0, stream>>>(qbuf, kpb, vptb, swoT, s_bo, G4);
  k_tr<<<dim3(512, 8), 256, 0, stream>>>(G4, nullptr, y, SSb, part + 2048,
                                         BS, 64, 16384, 1, BS, 128, 1, 32768, 128, 64);

  // ---- temporal transformer layer: attn+proj fused -> G6 fp32; sum bf16 -> G2 ----
  k_tr<<<dim3(512, 8), 256, 0, stream>>>(y, G2, nullptr, xt_bf, nullptr,
                                         BS, 128, 32768, 1, BS, 8192, 1, 64, 64, 128);
  k_qkvt_M<<<1024, 256, 0, stream>>>(xt_bf, twqT, twkT, twvT, t_bq, t_bk, t_bv, qbuf, kbuf, vtbuf);
  k_attnP<128, 0><<<512, 512, 0, stream>>>(qbuf, kbuf, vtbuf, twoT, t_bo, G6);
  k_tffn<<<1024, 256, 0, stream>>>(G2, G6, t_l1w, t_l1b, t_l2w, t_l2b,
                                   ln1g, ln1b, ln2g, ln2b, G0);
  k_tr<<<dim3(512, 8), 256, 0, stream>>>(G0, nullptr, y, STb, part + 4096,
                                         BS, 8192, 64, 1, BS, 128, 1, 32768, 128, 64);

  // ---- fused triple-GN: y_in2 = GN_l + GN_s + GN_t -> G4 fp32 ----
  k_gn_apply3B<<<4096, 256, 0, stream>>>(SLb, SSb, STb, part, gnlg, gnlb, gnsg, gnsb, gntg, gntb, G4);

  // ---- fuse + channel FFN + final GroupNorm (stats fused into last tr) ----
  k_tr<<<dim3(512, 8), 256, 0, stream>>>(G4, nullptr, nullptr, (unsigned short*)G5, nullptr,
                                         BS, 128, 32768, 1, BS, 8192, 1, 64, 64, 128);
  k_cffn<<<1024, 256, 0, stream>>>((unsigned short*)G5, ff1T, ff2T, ff1b, ff2b, G6);
  k_tr<<<dim3(512, 8), 256, 0, stream>>>(G6, out, G4, nullptr, part + 6144,
                                         BS, 8192, 64, 1, BS, 128, 1, 32768, 128, 64);
  k_gn_apply<<<4096, 256, 0, stream>>>(out, part + 6144, gn2g, gn2b, out);
}

// Round 27
// 339.112 us; speedup vs baseline: 1.8377x; 1.8377x over previous
//
#include <hip/hip_runtime.h>
#include <hip/hip_bf16.h>
#include <math.h>

constexpr int CC = 64, KK = 256, LL = 128;
constexpr int NN = KK * LL;          // 32768
constexpr int PR = 64;               // Linformer projection
constexpr int CPG = 16;              // channels per group (C / 4)
constexpr float EPSV = 1e-5f;
constexpr float SCL = 0.35355339059327373f;  // 1/sqrt(8)

typedef __attribute__((ext_vector_type(8))) short short8;      // 8 bf16 (4 VGPR)
typedef __attribute__((ext_vector_type(4))) float f32x4;       // MFMA 16x16 acc

__device__ __forceinline__ unsigned short f2bf(float x) {
  __hip_bfloat16 h = __float2bfloat16(x);
  union { __hip_bfloat16 b; unsigned short u; } v; v.b = h;
  return v.u;
}
__device__ __forceinline__ float bf2f(unsigned short x) {
  union { unsigned int u; float f; } v; v.u = ((unsigned int)x) << 16;
  return v.f;
}

// ---------------- adaptive adjacency: softmax(relu(nv1@nv2), axis=1) -> bf16 ----------------
__global__ __launch_bounds__(256) void k_adp(const float* __restrict__ nv1,
                                             const float* __restrict__ nv2,
                                             unsigned short* __restrict__ adp_bf) {
  int w = blockIdx.x, v = threadIdx.x;
  float s = 0.f;
  for (int d = 0; d < 10; ++d) s += nv1[w * 10 + d] * nv2[d * KK + v];
  s = fmaxf(s, 0.f);
  __shared__ float red[256];
  red[v] = s; __syncthreads();
  for (int off = 128; off; off >>= 1) { if (v < off) red[v] = fmaxf(red[v], red[v + off]); __syncthreads(); }
  float m = red[0]; __syncthreads();
  float e = expf(s - m);
  red[v] = e; __syncthreads();
  for (int off = 128; off; off >>= 1) { if (v < off) red[v] += red[v + off]; __syncthreads(); }
  adp_bf[w * KK + v] = f2bf(e / red[0]);
}

// ---------------- fused cast: a1,a2,gcn_w plain; 10 weights transposed; s_pk/s_pv transposed; grid 960 ----------------
__global__ __launch_bounds__(256) void k_castW(const float* __restrict__ s0, const float* __restrict__ s1,
                                               const float* __restrict__ s2,
                                               const float* __restrict__ swo, const float* __restrict__ two,
                                               const float* __restrict__ f1, const float* __restrict__ f2,
                                               const float* __restrict__ swq, const float* __restrict__ swk,
                                               const float* __restrict__ swv,
                                               const float* __restrict__ twq, const float* __restrict__ twk,
                                               const float* __restrict__ twv,
                                               const float* __restrict__ pk, const float* __restrict__ pv,
                                               unsigned short* __restrict__ d0, unsigned short* __restrict__ d1,
                                               unsigned short* __restrict__ d2,
                                               unsigned short* __restrict__ swoT, unsigned short* __restrict__ twoT,
                                               unsigned short* __restrict__ ff1T, unsigned short* __restrict__ ff2T,
                                               unsigned short* __restrict__ swqT, unsigned short* __restrict__ swkT,
                                               unsigned short* __restrict__ swvT,
                                               unsigned short* __restrict__ twqT, unsigned short* __restrict__ twkT,
                                               unsigned short* __restrict__ twvT,
                                               unsigned short* __restrict__ PkT, unsigned short* __restrict__ PvT) {
  int i = blockIdx.x * 256 + threadIdx.x;
  if (i < 65536) d0[i] = f2bf(s0[i]);
  else if (i < 131072) d1[i - 65536] = f2bf(s1[i - 65536]);
  else if (i < 159744) d2[i - 131072] = f2bf(s2[i - 131072]);
  else if (i >= 163840) {
    int j = i - 163840;
    if (j < 4096) { int r = j >> 6, c = j & 63; swoT[c * 64 + r] = f2bf(swo[j]); }
    else if (j < 8192) { int q = j - 4096; int r = q >> 6, c = q & 63; twoT[c * 64 + r] = f2bf(two[q]); }
    else if (j < 16384) { int q = j - 8192; int r = q >> 7, c = q & 127; ff1T[c * 64 + r] = f2bf(f1[q]); }
    else if (j < 24576) { int q = j - 16384; int r = q >> 6, c = q & 63; ff2T[c * 128 + r] = f2bf(f2[q]); }
    else if (j < 28672) { int q = j - 24576; int r = q >> 6, c = q & 63; swqT[c * 64 + r] = f2bf(swq[q]); }
    else if (j < 32768) { int q = j - 28672; int r = q >> 6, c = q & 63; swkT[c * 64 + r] = f2bf(swk[q]); }
    else if (j < 36864) { int q = j - 32768; int r = q >> 6, c = q & 63; swvT[c * 64 + r] = f2bf(swv[q]); }
    else if (j < 40960) { int q = j - 36864; int r = q >> 6, c = q & 63; twqT[c * 64 + r] = f2bf(twq[q]); }
    else if (j < 45056) { int q = j - 40960; int r = q >> 6, c = q & 63; twkT[c * 64 + r] = f2bf(twk[q]); }
    else if (j < 49152) { int q = j - 45056; int r = q >> 6, c = q & 63; twvT[c * 64 + r] = f2bf(twv[q]); }
    else if (j < 65536) { int q = j - 49152; int n = q >> 6, c = q & 63; PkT[c * 256 + n] = f2bf(pk[q]); }
    else if (j < 81920) { int q = j - 65536; int n = q >> 6, c = q & 63; PvT[c * 256 + n] = f2bf(pv[q]); }
  }
}

// ---------------- s0 term (bf16 out) ----------------
__global__ __launch_bounds__(64) void k_mix0(const unsigned short* __restrict__ Xbf,
                                             const unsigned short* __restrict__ Wbf,
                                             const float* __restrict__ bias,
                                             unsigned short* __restrict__ s0) {
  int pb = blockIdx.x;
  int lh = pb & 1;
  int k = (pb >> 1) & 255;
  int b = pb >> 9;
  int lane = threadIdx.x;
  int lr = lane & 15, g = lane >> 4;
  short8 af[4][2], bfv[4][2];
#pragma unroll
  for (int ot = 0; ot < 4; ++ot)
#pragma unroll
    for (int kc = 0; kc < 2; ++kc)
      af[ot][kc] = *(const short8*)(Wbf + (size_t)(ot * 16 + lr) * 448 + kc * 32 + g * 8);
#pragma unroll
  for (int ct = 0; ct < 4; ++ct)
#pragma unroll
    for (int kc = 0; kc < 2; ++kc)
      bfv[ct][kc] = *(const short8*)(Xbf + ((size_t)(b * 128 + lh * 64 + ct * 16 + lr) * 256 + k) * 64 + kc * 32 + g * 8);
  f32x4 acc[4][4];
#pragma unroll
  for (int ot = 0; ot < 4; ++ot)
#pragma unroll
    for (int ct = 0; ct < 4; ++ct) acc[ot][ct] = f32x4{0.f, 0.f, 0.f, 0.f};
#pragma unroll
  for (int kc = 0; kc < 2; ++kc)
#pragma unroll
    for (int ot = 0; ot < 4; ++ot)
#pragma unroll
      for (int ct = 0; ct < 4; ++ct)
        acc[ot][ct] = __builtin_amdgcn_mfma_f32_16x16x32_bf16(af[ot][kc], bfv[ct][kc], acc[ot][ct], 0, 0, 0);
#pragma unroll
  for (int ot = 0; ot < 4; ++ot)
#pragma unroll
    for (int ct = 0; ct < 4; ++ct) {
#pragma unroll
      for (int reg = 0; reg < 4; ++reg) {
        int o = ot * 16 + g * 4 + reg;
        s0[(size_t)(b * 64 + o) * NN + (size_t)k * 128 + lh * 64 + ct * 16 + lr] = f2bf(acc[ot][ct][reg] + bias[o]);
      }
    }
}

// ---------------- U terms ----------------
__global__ __launch_bounds__(64) void k_mix6(const unsigned short* __restrict__ Xbf,
                                             const unsigned short* __restrict__ Wbf,
                                             unsigned short* __restrict__ U1, unsigned short* __restrict__ U2,
                                             unsigned short* __restrict__ U3, unsigned short* __restrict__ U4,
                                             unsigned short* __restrict__ U5, unsigned short* __restrict__ U6) {
  int pb = blockIdx.x;
  int sy = blockIdx.y;
  int b = pb >> 9;
  int rem = pb & 511;
  int l = rem >> 2;
  int kq = (rem & 3) * 64;
  size_t posbase = ((size_t)(b * 128 + l)) * 256 + kq;
  int lane = threadIdx.x;
  int lr = lane & 15, g = lane >> 4;

  short8 af[4][2];
#pragma unroll
  for (int rt = 0; rt < 4; ++rt)
#pragma unroll
    for (int kc = 0; kc < 2; ++kc)
      af[rt][kc] = *(const short8*)(Xbf + (posbase + rt * 16 + lr) * 64 + kc * 32 + g * 8);

  for (int si = 0; si < 2; ++si) {
    int s = sy * 2 + 1 + si;
    short8 bfv[4][2];
#pragma unroll
    for (int ct = 0; ct < 4; ++ct)
#pragma unroll
      for (int kc = 0; kc < 2; ++kc)
        bfv[ct][kc] = *(const short8*)(Wbf + (size_t)(ct * 16 + lr) * 448 + s * 64 + kc * 32 + g * 8);
    f32x4 acc[4][4];
#pragma unroll
    for (int rt = 0; rt < 4; ++rt)
#pragma unroll
      for (int ct = 0; ct < 4; ++ct) acc[rt][ct] = f32x4{0.f, 0.f, 0.f, 0.f};
#pragma unroll
    for (int kc = 0; kc < 2; ++kc)
#pragma unroll
      for (int rt = 0; rt < 4; ++rt)
#pragma unroll
        for (int ct = 0; ct < 4; ++ct)
          acc[rt][ct] = __builtin_amdgcn_mfma_f32_16x16x32_bf16(af[rt][kc], bfv[ct][kc], acc[rt][ct], 0, 0, 0);
    unsigned short* dst = (s == 1) ? U1 : (s == 2) ? U2 : (s == 3) ? U3
                        : (s == 4) ? U4 : (s == 5) ? U5 : U6;
#pragma unroll
    for (int rt = 0; rt < 4; ++rt)
#pragma unroll
      for (int ct = 0; ct < 4; ++ct) {
        int o = ct * 16 + lr;
        int k = kq + rt * 16 + g * 4;
        ushort4 pk;
        pk.x = f2bf(acc[rt][ct][0]); pk.y = f2bf(acc[rt][ct][1]);
        pk.z = f2bf(acc[rt][ct][2]); pk.w = f2bf(acc[rt][ct][3]);
        *(ushort4*)&dst[((size_t)(b * 64 + o) * 128 + l) * 256 + k] = pk;
      }
  }
}

// ---------------- fused 2-hop (bf16 out) ----------------
__global__ __launch_bounds__(256) void k_adj2M(const unsigned short* __restrict__ Abf,
                                               const unsigned short* __restrict__ Ueven,
                                               const unsigned short* __restrict__ Uodd,
                                               unsigned short* __restrict__ out) {
  __shared__ unsigned short sH[32 * 256];
  int lq = blockIdx.x & 3, bc = blockIdx.x >> 2;
  int tid = threadIdx.x, wid = tid >> 6, lane = tid & 63;
  int lr = lane & 15, g = lane >> 4;
  int wbase = wid * 64;
  const unsigned short* aP = Abf + (size_t)(wbase + lr) * 256 + g * 8;
  const unsigned short* bP = Ueven + ((size_t)bc * 128 + lq * 32 + lr) * 256 + g * 8;

  f32x4 acc[4][2];
#pragma unroll
  for (int i = 0; i < 4; ++i)
#pragma unroll
    for (int j = 0; j < 2; ++j) acc[i][j] = f32x4{0.f, 0.f, 0.f, 0.f};
  for (int k0 = 0; k0 < 256; k0 += 32) {
    short8 af[4], bfv[2];
#pragma unroll
    for (int i = 0; i < 4; ++i) af[i] = *(const short8*)(aP + (size_t)i * 16 * 256 + k0);
#pragma unroll
    for (int i = 0; i < 2; ++i) bfv[i] = *(const short8*)(bP + (size_t)i * 16 * 256 + k0);
#pragma unroll
    for (int rm = 0; rm < 4; ++rm)
#pragma unroll
      for (int cn = 0; cn < 2; ++cn)
        acc[rm][cn] = __builtin_amdgcn_mfma_f32_16x16x32_bf16(af[rm], bfv[cn], acc[rm][cn], 0, 0, 0);
  }
  {
    const unsigned short* aT = Uodd + (size_t)bc * NN + (size_t)(lq * 32) * 256;
#pragma unroll
    for (int rm = 0; rm < 4; ++rm)
#pragma unroll
      for (int cn = 0; cn < 2; ++cn) {
        int l = cn * 16 + lr;
        int v = wbase + rm * 16 + g * 4;
        ushort4 av = *(const ushort4*)&aT[(size_t)l * 256 + v];
        ushort4 pk;
        pk.x = f2bf(acc[rm][cn][0] + bf2f(av.x));
        pk.y = f2bf(acc[rm][cn][1] + bf2f(av.y));
        pk.z = f2bf(acc[rm][cn][2] + bf2f(av.z));
        pk.w = f2bf(acc[rm][cn][3] + bf2f(av.w));
        int bo = ((l * 256 + v) * 2) ^ ((l & 7) << 4);
        *(ushort4*)((char*)sH + bo) = pk;
      }
  }
  __syncthreads();

  f32x4 c2[4][2];
#pragma unroll
  for (int i = 0; i < 4; ++i)
#pragma unroll
    for (int j = 0; j < 2; ++j) c2[i][j] = f32x4{0.f, 0.f, 0.f, 0.f};
  for (int k0 = 0; k0 < 256; k0 += 32) {
    short8 af[4], bfv[2];
#pragma unroll
    for (int i = 0; i < 4; ++i) af[i] = *(const short8*)(aP + (size_t)i * 16 * 256 + k0);
#pragma unroll
    for (int cn = 0; cn < 2; ++cn) {
      int l = cn * 16 + lr;
      int bo = ((l * 256 + k0 + g * 8) * 2) ^ ((l & 7) << 4);
      bfv[cn] = *(const short8*)((char*)sH + bo);
    }
#pragma unroll
    for (int rm = 0; rm < 4; ++rm)
#pragma unroll
      for (int cn = 0; cn < 2; ++cn)
        c2[rm][cn] = __builtin_amdgcn_mfma_f32_16x16x32_bf16(af[rm], bfv[cn], c2[rm][cn], 0, 0, 0);
  }
  unsigned short* dst = out + (size_t)bc * NN + lq * 32;
#pragma unroll
  for (int rm = 0; rm < 4; ++rm)
#pragma unroll
    for (int cn = 0; cn < 2; ++cn) {
      int col = cn * 16 + lr;
      int row = wbase + rm * 16 + g * 4;
#pragma unroll
      for (int j = 0; j < 4; ++j)
        dst[(size_t)(row + j) * 128 + col] = f2bf(c2[rm][cn][j]);
    }
}

// ---------------- generic (c,l)-plane transpose; optional dst/add/bf16 ----------------
__global__ __launch_bounds__(256) void k_tr(const float* __restrict__ src, float* __restrict__ dst,
                                            const float* __restrict__ add,
                                            unsigned short* __restrict__ dstBf,
                                            long sb, long sk, long sc, long sl,
                                            long db, long dk, long dc, long dl, int nC, int nL) {
  int outer = blockIdx.x;
  int b = outer >> 8, k = outer & 255;
  int tilesL = nL >> 5;
  int tC = blockIdx.y / tilesL, tL = blockIdx.y % tilesL;
  int c0 = tC << 5, l0 = tL << 5;
  __shared__ float s[32][33];
  int tx = threadIdx.x & 31, ty = threadIdx.x >> 5;
  const float* sp = src + (long)b * sb + (long)k * sk;
#pragma unroll
  for (int j = 0; j < 4; ++j) {
    int cc = c0 + ty + j * 8;
    s[ty + j * 8][tx] = sp[(long)cc * sc + (long)(l0 + tx) * sl];
  }
  __syncthreads();
  long dbase = (long)b * db + (long)k * dk;
#pragma unroll
  for (int j = 0; j < 4; ++j) {
    int ll = l0 + ty + j * 8;
    long off = dbase + (long)(c0 + tx) * dc + (long)ll * dl;
    float val = s[tx][ty + j * 8];
    if (add) val += add[off];
    if (dst) dst[off] = val;
    if (dstBf) dstBf[off] = f2bf(val);
  }
}

// ---------------- spatial QKV (MFMA, bf16 in/out): Q RM; K^T,V^T [bl][c][n] ----------------
__global__ __launch_bounds__(256) void k_qkvs_M(const unsigned short* __restrict__ Xbf,
                                                const unsigned short* __restrict__ wqT,
                                                const unsigned short* __restrict__ wkT,
                                                const unsigned short* __restrict__ wvT,
                                                unsigned short* __restrict__ qb,
                                                unsigned short* __restrict__ xkT,
                                                unsigned short* __restrict__ xvT) {
  int r0 = blockIdx.x * 64;
  int t = threadIdx.x, w = t >> 6, lane = t & 63;
  int lr = lane & 15, g = lane >> 4;
  const unsigned short* aP = Xbf + (size_t)(r0 + w * 16 + lr) * 64 + g * 8;
  short8 ax0 = *(const short8*)aP;
  short8 ax1 = *(const short8*)(aP + 32);
  {
    f32x4 acc[4];
#pragma unroll
    for (int ct = 0; ct < 4; ++ct) acc[ct] = f32x4{0.f, 0.f, 0.f, 0.f};
#pragma unroll
    for (int ct = 0; ct < 4; ++ct) {
      short8 b0 = *(const short8*)(wqT + (size_t)(ct * 16 + lr) * 64 + g * 8);
      short8 b1 = *(const short8*)(wqT + (size_t)(ct * 16 + lr) * 64 + 32 + g * 8);
      acc[ct] = __builtin_amdgcn_mfma_f32_16x16x32_bf16(ax0, b0, acc[ct], 0, 0, 0);
      acc[ct] = __builtin_amdgcn_mfma_f32_16x16x32_bf16(ax1, b1, acc[ct], 0, 0, 0);
    }
#pragma unroll
    for (int ct = 0; ct < 4; ++ct)
#pragma unroll
      for (int reg = 0; reg < 4; ++reg)
        qb[(size_t)(r0 + w * 16 + g * 4 + reg) * 64 + ct * 16 + lr] = f2bf(acc[ct][reg]);
  }
  short8 bx0[4], bx1[4];
#pragma unroll
  for (int ct = 0; ct < 4; ++ct) {
    const unsigned short* bP = Xbf + (size_t)(r0 + ct * 16 + lr) * 64 + g * 8;
    bx0[ct] = *(const short8*)bP;
    bx1[ct] = *(const short8*)(bP + 32);
  }
  int bl = r0 >> 8, nb = r0 & 255;
#pragma unroll
  for (int which = 0; which < 2; ++which) {
    const unsigned short* WT = which ? wvT : wkT;
    unsigned short* dstb = which ? xvT : xkT;
    short8 aw0 = *(const short8*)(WT + (size_t)(w * 16 + lr) * 64 + g * 8);
    short8 aw1 = *(const short8*)(WT + (size_t)(w * 16 + lr) * 64 + 32 + g * 8);
    f32x4 acc[4];
#pragma unroll
    for (int ct = 0; ct < 4; ++ct) {
      acc[ct] = f32x4{0.f, 0.f, 0.f, 0.f};
      acc[ct] = __builtin_amdgcn_mfma_f32_16x16x32_bf16(aw0, bx0[ct], acc[ct], 0, 0, 0);
      acc[ct] = __builtin_amdgcn_mfma_f32_16x16x32_bf16(aw1, bx1[ct], acc[ct], 0, 0, 0);
    }
#pragma unroll
    for (int ct = 0; ct < 4; ++ct)
#pragma unroll
      for (int reg = 0; reg < 4; ++reg) {
        int o = w * 16 + g * 4 + reg;
        dstb[(size_t)bl * 16384 + (size_t)o * 256 + nb + ct * 16 + lr] = f2bf(acc[ct][reg]);
      }
  }
}

// ---------------- temporal QKV (MFMA, bf16 in/out); V^T stored with sigma-permuted l-columns ----------------
// sigma(c) = (c&15)*8 + (c>>4)  [NKV=128, NCT=8] — must match k_attnP's P slot layout.
__global__ __launch_bounds__(256) void k_qkvt_M(const unsigned short* __restrict__ Xbf,
                                                const unsigned short* __restrict__ wqT,
                                                const unsigned short* __restrict__ wkT,
                                                const unsigned short* __restrict__ wvT,
                                                const float* __restrict__ bq, const float* __restrict__ bk_,
                                                const float* __restrict__ bv,
                                                unsigned short* __restrict__ qb,
                                                unsigned short* __restrict__ kb,
                                                unsigned short* __restrict__ vt) {
  int r0 = blockIdx.x * 64;
  int t = threadIdx.x, w = t >> 6, lane = t & 63;
  int lr = lane & 15, g = lane >> 4;
  const unsigned short* aP = Xbf + (size_t)(r0 + w * 16 + lr) * 64 + g * 8;
  short8 ax0 = *(const short8*)aP;
  short8 ax1 = *(const short8*)(aP + 32);
#pragma unroll
  for (int which = 0; which < 2; ++which) {
    const unsigned short* WT = which ? wkT : wqT;
    const float* bias = which ? bk_ : bq;
    unsigned short* dstb = which ? kb : qb;
    f32x4 acc[4];
#pragma unroll
    for (int ct = 0; ct < 4; ++ct) {
      acc[ct] = f32x4{0.f, 0.f, 0.f, 0.f};
      short8 b0 = *(const short8*)(WT + (size_t)(ct * 16 + lr) * 64 + g * 8);
      short8 b1 = *(const short8*)(WT + (size_t)(ct * 16 + lr) * 64 + 32 + g * 8);
      acc[ct] = __builtin_amdgcn_mfma_f32_16x16x32_bf16(ax0, b0, acc[ct], 0, 0, 0);
      acc[ct] = __builtin_amdgcn_mfma_f32_16x16x32_bf16(ax1, b1, acc[ct], 0, 0, 0);
    }
#pragma unroll
    for (int ct = 0; ct < 4; ++ct) {
      float bvv = bias[ct * 16 + lr];
#pragma unroll
      for (int reg = 0; reg < 4; ++reg)
        dstb[(size_t)(r0 + w * 16 + g * 4 + reg) * 64 + ct * 16 + lr] = f2bf(acc[ct][reg] + bvv);
    }
  }
  short8 bx0[4], bx1[4];
#pragma unroll
  for (int ct = 0; ct < 4; ++ct) {
    const unsigned short* bP = Xbf + (size_t)(r0 + ct * 16 + lr) * 64 + g * 8;
    bx0[ct] = *(const short8*)bP;
    bx1[ct] = *(const short8*)(bP + 32);
  }
  int bkk = r0 >> 7, lbase = r0 & 127;
  short8 aw0 = *(const short8*)(wvT + (size_t)(w * 16 + lr) * 64 + g * 8);
  short8 aw1 = *(const short8*)(wvT + (size_t)(w * 16 + lr) * 64 + 32 + g * 8);
  f32x4 acc[4];
#pragma unroll
  for (int ct = 0; ct < 4; ++ct) {
    acc[ct] = f32x4{0.f, 0.f, 0.f, 0.f};
    acc[ct] = __builtin_amdgcn_mfma_f32_16x16x32_bf16(aw0, bx0[ct], acc[ct], 0, 0, 0);
    acc[ct] = __builtin_amdgcn_mfma_f32_16x16x32_bf16(aw1, bx1[ct], acc[ct], 0, 0, 0);
  }
  int lb4 = lbase >> 4;   // 0 or 4
#pragma unroll
  for (int ct = 0; ct < 4; ++ct)
#pragma unroll
    for (int reg = 0; reg < 4; ++reg) {
      int o = w * 16 + g * 4 + reg;
      // col c = lbase + ct*16 + lr -> sigma(c) = lr*8 + lb4 + ct
      vt[(size_t)bkk * 8192 + (size_t)o * 128 + lr * 8 + lb4 + ct] = f2bf(acc[ct][reg] + bv[o]);
    }
}

// ---------------- MFMA sproj; V^T output stored with sigma-permuted p-columns ----------------
// sigma(p) = (p&15)*4 + (p>>4)  [NKV=64, NCT=4] — must match k_attnP's P slot layout.
__global__ __launch_bounds__(256) void k_sprojM(const unsigned short* __restrict__ XkT,
                                                const unsigned short* __restrict__ XvT,
                                                const unsigned short* __restrict__ PkT,
                                                const unsigned short* __restrict__ PvT,
                                                unsigned short* __restrict__ kpb,
                                                unsigned short* __restrict__ vptb) {
  int bl = blockIdx.x;
  int which = blockIdx.y;
  int t = threadIdx.x, w = t >> 6, lane = t & 63;
  int lr = lane & 15, g = lane >> 4;
  const unsigned short* Abase = which ? PvT : XkT + (size_t)bl * 16384;
  const unsigned short* Bbase = which ? XvT + (size_t)bl * 16384 : PkT;
  const unsigned short* aP = Abase + (size_t)(w * 16 + lr) * 256 + g * 8;
  f32x4 acc[4];
#pragma unroll
  for (int ct = 0; ct < 4; ++ct) acc[ct] = f32x4{0.f, 0.f, 0.f, 0.f};
  for (int k0 = 0; k0 < 256; k0 += 32) {
    short8 af = *(const short8*)(aP + k0);
#pragma unroll
    for (int ct = 0; ct < 4; ++ct) {
      short8 bf = *(const short8*)(Bbase + (size_t)(ct * 16 + lr) * 256 + k0 + g * 8);
      acc[ct] = __builtin_amdgcn_mfma_f32_16x16x32_bf16(af, bf, acc[ct], 0, 0, 0);
    }
  }
  if (!which) {
    unsigned short* dst = kpb + (size_t)bl * 4096;
#pragma unroll
    for (int ct = 0; ct < 4; ++ct) {
      int p = ct * 16 + lr;
      int c0 = w * 16 + g * 4;
      ushort4 pk;
      pk.x = f2bf(acc[ct][0]); pk.y = f2bf(acc[ct][1]);
      pk.z = f2bf(acc[ct][2]); pk.w = f2bf(acc[ct][3]);
      *(ushort4*)&dst[(size_t)p * 64 + c0] = pk;
    }
  } else {
    unsigned short* dst = vptb + (size_t)bl * 4096;
#pragma unroll
    for (int ct = 0; ct < 4; ++ct) {
      int c = ct * 16 + lr;
      // p = w*16 + g*4 + reg -> sigma(p) = (g*4+reg)*4 + w
#pragma unroll
      for (int reg = 0; reg < 4; ++reg)
        dst[(size_t)c * 64 + (g * 4 + reg) * 4 + w] = f2bf(acc[ct][reg]);
    }
  }
}

// ---------------- fused channel FFN (MFMA) ----------------
__global__ __launch_bounds__(256) void k_cffn(const unsigned short* __restrict__ in,
                                              const unsigned short* __restrict__ ff1T,
                                              const unsigned short* __restrict__ ff2T,
                                              const float* __restrict__ b1,
                                              const float* __restrict__ b2,
                                              float* __restrict__ out) {
  __shared__ unsigned short sH[4][16 * 128];
  int r0 = blockIdx.x * 64;
  int t = threadIdx.x, w = t >> 6, lane = t & 63;
  int lr = lane & 15, g = lane >> 4;
  unsigned short* myH = sH[w];
  const unsigned short* aP = in + (size_t)(r0 + w * 16 + lr) * 64 + g * 8;
  short8 af0 = *(const short8*)aP;
  short8 af1 = *(const short8*)(aP + 32);
  f32x4 acc1[8];
#pragma unroll
  for (int ct = 0; ct < 8; ++ct) acc1[ct] = f32x4{0.f, 0.f, 0.f, 0.f};
#pragma unroll
  for (int ct = 0; ct < 8; ++ct) {
    short8 b0 = *(const short8*)(ff1T + (size_t)(ct * 16 + lr) * 64 + g * 8);
    short8 bx = *(const short8*)(ff1T + (size_t)(ct * 16 + lr) * 64 + 32 + g * 8);
    acc1[ct] = __builtin_amdgcn_mfma_f32_16x16x32_bf16(af0, b0, acc1[ct], 0, 0, 0);
    acc1[ct] = __builtin_amdgcn_mfma_f32_16x16x32_bf16(af1, bx, acc1[ct], 0, 0, 0);
  }
#pragma unroll
  for (int ct = 0; ct < 8; ++ct) {
    int o = ct * 16 + lr;
    float bv = b1[o];
#pragma unroll
    for (int reg = 0; reg < 4; ++reg) {
      int m = g * 4 + reg;
      float h = fmaxf(acc1[ct][reg] + bv, 0.f);
      int bo = ((m * 128 + o) * 2) ^ ((m & 7) << 4);
      *(unsigned short*)((char*)myH + bo) = f2bf(h);
    }
  }
  __syncthreads();
  short8 ha[4];
#pragma unroll
  for (int ks = 0; ks < 4; ++ks) {
    int bo = ((lr * 128 + ks * 32 + g * 8) * 2) ^ ((lr & 7) << 4);
    ha[ks] = *(const short8*)((char*)myH + bo);
  }
  f32x4 acc2[4];
#pragma unroll
  for (int ct = 0; ct < 4; ++ct) acc2[ct] = f32x4{0.f, 0.f, 0.f, 0.f};
#pragma unroll
  for (int ct = 0; ct < 4; ++ct)
#pragma unroll
    for (int ks = 0; ks < 4; ++ks) {
      short8 b0 = *(const short8*)(ff2T + (size_t)(ct * 16 + lr) * 128 + ks * 32 + g * 8);
      acc2[ct] = __builtin_amdgcn_mfma_f32_16x16x32_bf16(ha[ks], b0, acc2[ct], 0, 0, 0);
    }
#pragma unroll
  for (int ct = 0; ct < 4; ++ct) {
    int o = ct * 16 + lr;
    float bv = b2[o];
#pragma unroll
    for (int reg = 0; reg < 4; ++reg)
      out[(size_t)(r0 + w * 16 + g * 4 + reg) * 64 + o] = acc2[ct][reg] + bv;
  }
}

// ---------------- fused LN1 -> FFN(64->8 gelu ->64) -> LN2 ----------------
__global__ __launch_bounds__(256) void k_tffn(const float* __restrict__ A, const float* __restrict__ Bz,
                                              const float* __restrict__ l1w, const float* __restrict__ l1b,
                                              const float* __restrict__ l2w, const float* __restrict__ l2b,
                                              const float* __restrict__ ln1g, const float* __restrict__ ln1b,
                                              const float* __restrict__ ln2g, const float* __restrict__ ln2b,
                                              float* __restrict__ outp) {
  int r0 = blockIdx.x * 64;
  __shared__ float sSrc[64][65];
  __shared__ float sH[64][8];
  __shared__ float sW1[64][8];
  __shared__ float sW2[8][64];
  int t = threadIdx.x;
  for (int i = t; i < 512; i += 256) { ((float*)sW1)[i] = l1w[i]; ((float*)sW2)[i] = l2w[i]; }
  int c = t & 63, rg = t >> 6;
  float g1 = ln1g[c], be1 = ln1b[c];
  for (int it = 0; it < 16; ++it) {
    int r = it * 4 + rg;
    size_t idx = (size_t)(r0 + r) * 64 + c;
    float x = A[idx] + Bz[idx];
    float s = x, ss = x * x;
#pragma unroll
    for (int off = 32; off; off >>= 1) { s += __shfl_xor(s, off); ss += __shfl_xor(ss, off); }
    float mu = s * (1.f / 64.f);
    float var = ss * (1.f / 64.f) - mu * mu;
    sSrc[r][c] = (x - mu) * rsqrtf(var + EPSV) * g1 + be1;
  }
  __syncthreads();
#pragma unroll
  for (int p = 0; p < 2; ++p) {
    int idx = t + 256 * p;
    int row = idx >> 3, j = idx & 7;
    float acc = l1b[j];
    for (int cc = 0; cc < 64; ++cc) acc += sSrc[row][cc] * sW1[cc][j];
    acc = 0.5f * acc * (1.f + erff(acc * 0.70710678118654752440f));
    sH[row][j] = acc;
  }
  __syncthreads();
  float g2 = ln2g[c], be2 = ln2b[c];
  float l2bc = l2b[c];
  for (int it = 0; it < 16; ++it) {
    int r = it * 4 + rg;
    float o = l2bc;
#pragma unroll
    for (int j = 0; j < 8; ++j) o += sH[r][j] * sW2[j][c];
    float x = sSrc[r][c] + o;
    float s = x, ss = x * x;
#pragma unroll
    for (int off = 32; off; off >>= 1) { s += __shfl_xor(s, off); ss += __shfl_xor(ss, off); }
    float mu = s * (1.f / 64.f);
    float var = ss * (1.f / 64.f) - mu * mu;
    outp[(size_t)(r0 + r) * 64 + c] = (x - mu) * rsqrtf(var + EPSV) * g2 + be2;
  }
}

// ---------------- per-head MFMA attention + fused output projection -> fp32 ----------------
// P stored in sigma-permuted column layout (ushort4 stores). Softmax denominator computed
// FREE by the PV MFMA: lane lr==8 supplies an all-ones B-row, so output col 8 = row-sum of P.
template <int NKV, int KVSHIFT>
__global__ __launch_bounds__(512) void k_attnP(const unsigned short* __restrict__ Qb,
                                               const unsigned short* __restrict__ Kb,
                                               const unsigned short* __restrict__ VTb,
                                               const unsigned short* __restrict__ WT,
                                               const float* __restrict__ bias,
                                               float* __restrict__ out) {
  constexpr int NCT = NKV / 16;
  constexpr int NKS = NKV / 32;
  int blk = blockIdx.x;
  const unsigned short* Qp = Qb + (size_t)blk * 128 * 64;
  const unsigned short* Kp = Kb + (size_t)(blk >> KVSHIFT) * NKV * 64;
  const unsigned short* VTp = VTb + (size_t)(blk >> KVSHIFT) * 64 * NKV;
  int t = threadIdx.x;
  int h = t >> 6, lane = t & 63, lr = lane & 15, g = lane >> 4;
  __shared__ unsigned short sP[8][16 * NKV];
  __shared__ unsigned short sO[128 * 64];
  unsigned short* myP = sP[h];

  short8 kbf[NCT];
#pragma unroll
  for (int ct = 0; ct < NCT; ++ct)
    kbf[ct] = *(const short8*)(Kp + (size_t)(ct * 16 + lr) * 64 + h * 8);

  short8 vbf[NKS];
  if (lr < 8) {
    int vr = h * 8 + lr;
#pragma unroll
    for (int ks = 0; ks < NKS; ++ks)
      vbf[ks] = *(const short8*)(VTp + (size_t)vr * NKV + ks * 32 + g * 8);
  } else if (lr == 8) {
    const short ONE = (short)0x3F80;  // bf16 1.0
#pragma unroll
    for (int ks = 0; ks < NKS; ++ks)
      vbf[ks] = short8{ONE, ONE, ONE, ONE, ONE, ONE, ONE, ONE};
  } else {
#pragma unroll
    for (int ks = 0; ks < NKS; ++ks)
      vbf[ks] = short8{0, 0, 0, 0, 0, 0, 0, 0};
  }
  int srcl = (lane & 48) | 8;   // lane holding this row-group's col-8 (row sums)

  for (int mt = 0; mt < 8; ++mt) {
    short8 qa = short8{0, 0, 0, 0, 0, 0, 0, 0};
    if (g == 0) qa = *(const short8*)(Qp + (size_t)(mt * 16 + lr) * 64 + h * 8);

    f32x4 sacc[NCT];
#pragma unroll
    for (int ct = 0; ct < NCT; ++ct) sacc[ct] = f32x4{0.f, 0.f, 0.f, 0.f};
#pragma unroll
    for (int ct = 0; ct < NCT; ++ct)
      sacc[ct] = __builtin_amdgcn_mfma_f32_16x16x32_bf16(qa, kbf[ct], sacc[ct], 0, 0, 0);

#pragma unroll
    for (int ct = 0; ct < NCT; ++ct)
#pragma unroll
      for (int reg = 0; reg < 4; ++reg)
        sacc[ct][reg] = __expf(sacc[ct][reg] * SCL);

    // P store: slot sigma(c) = lr*NCT + ct -> contiguous NCT values per row
#pragma unroll
    for (int reg = 0; reg < 4; ++reg) {
      int row = g * 4 + reg;
#pragma unroll
      for (int c4 = 0; c4 < NCT; c4 += 4) {
        ushort4 pk;
        pk.x = f2bf(sacc[c4 + 0][reg]); pk.y = f2bf(sacc[c4 + 1][reg]);
        pk.z = f2bf(sacc[c4 + 2][reg]); pk.w = f2bf(sacc[c4 + 3][reg]);
        int bo = ((row * NKV + lr * NCT + c4) * 2) ^ ((row & 7) << 4);
        *(ushort4*)((char*)myP + bo) = pk;
      }
    }
    // no barrier: myP is wave-private

    f32x4 oacc = f32x4{0.f, 0.f, 0.f, 0.f};
#pragma unroll
    for (int ks = 0; ks < NKS; ++ks) {
      int bo = ((lr * NKV + ks * 32 + g * 8) * 2) ^ ((lr & 7) << 4);
      short8 pa = *(const short8*)((char*)myP + bo);
      oacc = __builtin_amdgcn_mfma_f32_16x16x32_bf16(pa, vbf[ks], oacc, 0, 0, 0);
    }
    float inv4[4];
#pragma unroll
    for (int reg = 0; reg < 4; ++reg)
      inv4[reg] = 1.f / __shfl(oacc[reg], srcl);
    if (lr < 8) {
#pragma unroll
      for (int reg = 0; reg < 4; ++reg) {
        int row = mt * 16 + g * 4 + reg;
        int col = h * 8 + lr;
        int bo = ((row * 64 + col) * 2) ^ ((row & 7) << 4);
        *(unsigned short*)((char*)sO + bo) = f2bf(oacc[reg] * inv4[reg]);
      }
    }
  }
  __syncthreads();

  int row = h * 16 + lr;
  int bo0 = ((row * 64 + g * 8) * 2) ^ ((row & 7) << 4);
  int bo1 = ((row * 64 + 32 + g * 8) * 2) ^ ((row & 7) << 4);
  short8 af0 = *(const short8*)((char*)sO + bo0);
  short8 af1 = *(const short8*)((char*)sO + bo1);
  f32x4 acc[4];
#pragma unroll
  for (int ct = 0; ct < 4; ++ct) acc[ct] = f32x4{0.f, 0.f, 0.f, 0.f};
#pragma unroll
  for (int ct = 0; ct < 4; ++ct) {
    short8 b0 = *(const short8*)(WT + (size_t)(ct * 16 + lr) * 64 + g * 8);
    short8 b1 = *(const short8*)(WT + (size_t)(ct * 16 + lr) * 64 + 32 + g * 8);
    acc[ct] = __builtin_amdgcn_mfma_f32_16x16x32_bf16(af0, b0, acc[ct], 0, 0, 0);
    acc[ct] = __builtin_amdgcn_mfma_f32_16x16x32_bf16(af1, b1, acc[ct], 0, 0, 0);
  }
  float* op = out + (size_t)blk * 128 * 64;
#pragma unroll
  for (int ct = 0; ct < 4; ++ct) {
    int o = ct * 16 + lr;
    float bv = bias[o];
#pragma unroll
    for (int reg = 0; reg < 4; ++reg)
      op[(size_t)(h * 16 + g * 4 + reg) * 64 + o] = acc[ct][reg] + bv;
  }
}

// ---------------- GroupNorm stats (fp32 single input) ----------------
__global__ __launch_bounds__(256) void k_gn_part(const float* __restrict__ p0,
                                                 float* __restrict__ part) {
  int bg = blockIdx.y, blk = blockIdx.x, t = threadIdx.x;
  size_t start = (size_t)bg * ((size_t)CPG * NN) + (size_t)blk * 8192;
  const float4* q0 = (const float4*)(p0 + start);
  float s = 0.f, ss = 0.f;
  for (int i = t; i < 2048; i += 256) {
    float4 x = q0[i];
    s += x.x + x.y + x.z + x.w;
    ss += x.x * x.x + x.y * x.y + x.z * x.z + x.w * x.w;
  }
  __shared__ float rs[256], rq[256];
  rs[t] = s; rq[t] = ss; __syncthreads();
  for (int off = 128; off; off >>= 1) { if (t < off) { rs[t] += rs[t + off]; rq[t] += rq[t + off]; } __syncthreads(); }
  if (t == 0) { part[(bg * 64 + blk) * 2] = rs[0]; part[(bg * 64 + blk) * 2 + 1] = rq[0]; }
}

// ---------------- GroupNorm stats (bf16 single input) ----------------
__global__ __launch_bounds__(256) void k_gn_part1B(const unsigned short* __restrict__ p0,
                                                   float* __restrict__ part) {
  int bg = blockIdx.y, blk = blockIdx.x, t = threadIdx.x;
  size_t start = (size_t)bg * ((size_t)CPG * NN) + (size_t)blk * 8192;
  const ushort4* q0 = (const ushort4*)(p0 + start);
  float s = 0.f, ss = 0.f;
  for (int i = t; i < 2048; i += 256) {
    ushort4 u = q0[i];
    float a = bf2f(u.x), b = bf2f(u.y), c = bf2f(u.z), d = bf2f(u.w);
    s += a + b + c + d;
    ss += a * a + b * b + c * c + d * d;
  }
  __shared__ float rs[256], rq[256];
  rs[t] = s; rq[t] = ss; __syncthreads();
  for (int off = 128; off; off >>= 1) { if (t < off) { rs[t] += rs[t + off]; rq[t] += rq[t + off]; } __syncthreads(); }
  if (t == 0) { part[(bg * 64 + blk) * 2] = rs[0]; part[(bg * 64 + blk) * 2 + 1] = rq[0]; }
}

// ---------------- GroupNorm stats: y(fp32) + 4 bf16 -> bf16 sum + partials ----------------
__global__ __launch_bounds__(256) void k_gn_partB(const float* __restrict__ p0,
                                                  const unsigned short* __restrict__ q1,
                                                  const unsigned short* __restrict__ q2,
                                                  const unsigned short* __restrict__ q3,
                                                  const unsigned short* __restrict__ q4,
                                                  unsigned short* __restrict__ sumOut,
                                                  float* __restrict__ part) {
  int bg = blockIdx.y, blk = blockIdx.x, t = threadIdx.x;
  size_t start = (size_t)bg * ((size_t)CPG * NN) + (size_t)blk * 8192;
  const float4* f0 = (const float4*)(p0 + start);
  const ushort4* b1 = (const ushort4*)(q1 + start);
  const ushort4* b2 = (const ushort4*)(q2 + start);
  const ushort4* b3 = (const ushort4*)(q3 + start);
  const ushort4* b4 = (const ushort4*)(q4 + start);
  ushort4* so = (ushort4*)(sumOut + start);
  float s = 0.f, ss = 0.f;
  for (int i = t; i < 2048; i += 256) {
    float4 x = f0[i];
    ushort4 u;
    u = b1[i]; x.x += bf2f(u.x); x.y += bf2f(u.y); x.z += bf2f(u.z); x.w += bf2f(u.w);
    u = b2[i]; x.x += bf2f(u.x); x.y += bf2f(u.y); x.z += bf2f(u.z); x.w += bf2f(u.w);
    u = b3[i]; x.x += bf2f(u.x); x.y += bf2f(u.y); x.z += bf2f(u.z); x.w += bf2f(u.w);
    u = b4[i]; x.x += bf2f(u.x); x.y += bf2f(u.y); x.z += bf2f(u.z); x.w += bf2f(u.w);
    ushort4 pk;
    pk.x = f2bf(x.x); pk.y = f2bf(x.y); pk.z = f2bf(x.z); pk.w = f2bf(x.w);
    so[i] = pk;
    s += x.x + x.y + x.z + x.w;
    ss += x.x * x.x + x.y * x.y + x.z * x.z + x.w * x.w;
  }
  __shared__ float rs[256], rq[256];
  rs[t] = s; rq[t] = ss; __syncthreads();
  for (int off = 128; off; off >>= 1) { if (t < off) { rs[t] += rs[t + off]; rq[t] += rq[t + off]; } __syncthreads(); }
  if (t == 0) { part[(bg * 64 + blk) * 2] = rs[0]; part[(bg * 64 + blk) * 2 + 1] = rq[0]; }
}

// out = GN(p0) — reduces 64 partials per block (final GN)
__global__ __launch_bounds__(256) void k_gn_apply(const float* __restrict__ p0,
                                                  const float* __restrict__ part, const float* __restrict__ g,
                                                  const float* __restrict__ be,
                                                  float* __restrict__ out) {
  size_t i4 = (size_t)blockIdx.x * 256 + threadIdx.x;
  size_t i = i4 * 4;
  int chan = (int)(i >> 15) & 63;
  int bg = (int)(i >> 19);
  __shared__ float smu, srr;
  int t = threadIdx.x;
  if (t < 64) {
    float s = part[(bg * 64 + t) * 2], ss = part[(bg * 64 + t) * 2 + 1];
#pragma unroll
    for (int off = 32; off; off >>= 1) { s += __shfl_xor(s, off); ss += __shfl_xor(ss, off); }
    if (t == 0) {
      float inv = 1.f / (float)((size_t)CPG * NN);
      float mu = s * inv;
      float var = ss * inv - mu * mu;
      smu = mu; srr = rsqrtf(var + EPSV);
    }
  }
  __syncthreads();
  float mu = smu, rr = srr;
  float4 x = ((const float4*)p0)[i4];
  float gc = g[chan], bc = be[chan];
  float4 v;
  v.x = (x.x - mu) * rr * gc + bc;
  v.y = (x.y - mu) * rr * gc + bc;
  v.z = (x.z - mu) * rr * gc + bc;
  v.w = (x.w - mu) * rr * gc + bc;
  ((float4*)out)[i4] = v;
}

// out = GN_l(SLb) + GN_s(SSb) + GN_t(STb); bf16 inputs; three partial sets at part+0/+2048/+4096
__global__ __launch_bounds__(256) void k_gn_apply3B(const unsigned short* __restrict__ SLb,
                                                    const unsigned short* __restrict__ SSb,
                                                    const unsigned short* __restrict__ STb,
                                                    const float* __restrict__ part,
                                                    const float* __restrict__ gl, const float* __restrict__ bl_,
                                                    const float* __restrict__ gs, const float* __restrict__ bs_,
                                                    const float* __restrict__ gt, const float* __restrict__ bt_,
                                                    float* __restrict__ out) {
  size_t i4 = (size_t)blockIdx.x * 256 + threadIdx.x;
  size_t i = i4 * 4;
  int chan = (int)(i >> 15) & 63;
  int bg = (int)(i >> 19);
  __shared__ float smu[3], srr[3];
  int t = threadIdx.x;
  if (t < 192) {
    int which = t >> 6, tt = t & 63;
    const float* pp = part + which * 2048;
    float s = pp[(bg * 64 + tt) * 2], ss = pp[(bg * 64 + tt) * 2 + 1];
#pragma unroll
    for (int off = 32; off; off >>= 1) { s += __shfl_xor(s, off); ss += __shfl_xor(ss, off); }
    if (tt == 0) {
      float inv = 1.f / (float)((size_t)CPG * NN);
      float mu = s * inv;
      float var = ss * inv - mu * mu;
      smu[which] = mu; srr[which] = rsqrtf(var + EPSV);
    }
  }
  __syncthreads();
  float gL = gl[chan] * srr[0], bL = bl_[chan] - smu[0] * gl[chan] * srr[0];
  float gS = gs[chan] * srr[1], bS = bs_[chan] - smu[1] * gs[chan] * srr[1];
  float gT = gt[chan] * srr[2], bT = bt_[chan] - smu[2] * gt[chan] * srr[2];
  ushort4 ul = ((const ushort4*)SLb)[i4];
  ushort4 us = ((const ushort4*)SSb)[i4];
  ushort4 ut = ((const ushort4*)STb)[i4];
  float4 v;
  v.x = bf2f(ul.x) * gL + bL + bf2f(us.x) * gS + bS + bf2f(ut.x) * gT + bT;
  v.y = bf2f(ul.y) * gL + bL + bf2f(us.y) * gS + bS + bf2f(ut.y) * gT + bT;
  v.z = bf2f(ul.z) * gL + bL + bf2f(us.z) * gS + bS + bf2f(ut.z) * gT + bT;
  v.w = bf2f(ul.w) * gL + bL + bf2f(us.w) * gS + bS + bf2f(ut.w) * gT + bT;
  ((float4*)out)[i4] = v;
}

extern "C" void kernel_launch(void* const* d_in, const int* in_sizes, int n_in,
                              void* d_out, int out_size, void* d_ws, size_t ws_size,
                              hipStream_t stream) {
  (void)in_sizes; (void)n_in; (void)out_size; (void)ws_size;
  const float* y     = (const float*)d_in[0];
  const float* a1    = (const float*)d_in[1];
  const float* a2    = (const float*)d_in[2];
  const float* nv1   = (const float*)d_in[3];
  const float* nv2   = (const float*)d_in[4];
  const float* gcn_w = (const float*)d_in[5];
  const float* gcn_b = (const float*)d_in[6];
  const float* s_wq  = (const float*)d_in[7];
  const float* s_wk  = (const float*)d_in[8];
  const float* s_wv  = (const float*)d_in[9];
  const float* s_pk  = (const float*)d_in[10];
  const float* s_pv  = (const float*)d_in[11];
  const float* s_wo  = (const float*)d_in[12];
  const float* s_bo  = (const float*)d_in[13];
  const float* t_wq  = (const float*)d_in[14];
  const float* t_wk  = (const float*)d_in[15];
  const float* t_wv  = (const float*)d_in[16];
  const float* t_bq  = (const float*)d_in[17];
  const float* t_bk  = (const float*)d_in[18];
  const float* t_bv  = (const float*)d_in[19];
  const float* t_wo  = (const float*)d_in[20];
  const float* t_bo  = (const float*)d_in[21];
  const float* t_l1w = (const float*)d_in[22];
  const float* t_l1b = (const float*)d_in[23];
  const float* t_l2w = (const float*)d_in[24];
  const float* t_l2b = (const float*)d_in[25];
  const float* ln1g  = (const float*)d_in[26];
  const float* ln1b  = (const float*)d_in[27];
  const float* ln2g  = (const float*)d_in[28];
  const float* ln2b  = (const float*)d_in[29];
  const float* gnlg  = (const float*)d_in[30];
  const float* gnlb  = (const float*)d_in[31];
  const float* gnsg  = (const float*)d_in[32];
  const float* gnsb  = (const float*)d_in[33];
  const float* gntg  = (const float*)d_in[34];
  const float* gntb  = (const float*)d_in[35];
  const float* ff1w  = (const float*)d_in[36];
  const float* ff1b  = (const float*)d_in[37];
  const float* ff2w  = (const float*)d_in[38];
  const float* ff2b  = (const float*)d_in[39];
  const float* gn2g  = (const float*)d_in[40];
  const float* gn2b  = (const float*)d_in[41];

  float* ws = (float*)d_ws;
  float* part  = ws + 65536;
  unsigned short* a1_bf   = (unsigned short*)(ws + 131072);
  unsigned short* a2_bf   = (unsigned short*)(ws + 163840);
  unsigned short* adp_bf  = (unsigned short*)(ws + 196608);
  unsigned short* gcnw_bf = (unsigned short*)(ws + 229376);
  unsigned short* xs_bf   = (unsigned short*)(ws + 262144);
  unsigned short* swoT = (unsigned short*)(ws + 2359296);
  unsigned short* twoT = (unsigned short*)(ws + 2361344);
  unsigned short* ff1T = (unsigned short*)(ws + 2363392);
  unsigned short* ff2T = (unsigned short*)(ws + 2367488);
  unsigned short* swqT = (unsigned short*)(ws + 2371584);
  unsigned short* swkT = (unsigned short*)(ws + 2373632);
  unsigned short* swvT = (unsigned short*)(ws + 2375680);
  unsigned short* twqT = (unsigned short*)(ws + 2377728);
  unsigned short* twkT = (unsigned short*)(ws + 2379776);
  unsigned short* twvT = (unsigned short*)(ws + 2381824);
  unsigned short* PkT  = (unsigned short*)(ws + 2383872);
  unsigned short* PvT  = (unsigned short*)(ws + 2392064);
  unsigned short* kpb  = (unsigned short*)(ws + 131072);
  unsigned short* vptb = (unsigned short*)(ws + 1179648);
  const size_t SLOT = 4194304;
  float* G0 = ws + SLOT * 1;
  float* G1 = ws + SLOT * 2;
  float* G2 = ws + SLOT * 3;
  float* G3 = ws + SLOT * 4;
  float* G4 = ws + SLOT * 5;
  float* G5 = ws + SLOT * 6;
  float* G6 = ws + SLOT * 7;
  unsigned short* U1 = (unsigned short*)G3;
  unsigned short* U2 = (unsigned short*)G3 + 4194304;
  unsigned short* U3 = (unsigned short*)G4;
  unsigned short* U4 = (unsigned short*)G4 + 4194304;
  unsigned short* U5 = (unsigned short*)G5;
  unsigned short* U6 = (unsigned short*)G5 + 4194304;
  unsigned short* s0bf = (unsigned short*)G1;
  unsigned short* Q1bf = (unsigned short*)G0;
  unsigned short* Q3bf = (unsigned short*)G0 + 4194304;
  unsigned short* Q2bf = (unsigned short*)G6;
  unsigned short* SLb  = (unsigned short*)G3;   // GCN branch sum (bf16)
  unsigned short* SSb  = (unsigned short*)G1;   // spatial branch sum
  unsigned short* STb  = (unsigned short*)G2;   // temporal branch sum
  unsigned short* qbuf = (unsigned short*)G0;
  unsigned short* xkT = (unsigned short*)G4;
  unsigned short* xvT = (unsigned short*)G5;
  unsigned short* kbuf = (unsigned short*)G4;
  unsigned short* vtbuf = (unsigned short*)G5;
  unsigned short* xt_bf = (unsigned short*)G6;
  float* out = (float*)d_out;

  const long BS = 2097152;

  // ---- setup casts ----
  k_adp<<<256, 256, 0, stream>>>(nv1, nv2, adp_bf);
  k_castW<<<960, 256, 0, stream>>>(a1, a2, gcn_w, s_wo, t_wo, ff1w, ff2w,
                                   s_wq, s_wk, s_wv, t_wq, t_wk, t_wv, s_pk, s_pv,
                                   a1_bf, a2_bf, gcnw_bf, swoT, twoT, ff1T, ff2T,
                                   swqT, swkT, swvT, twqT, twkT, twvT, PkT, PvT);

  // ---- xs bf16 (B,L,K,C) ----
  k_tr<<<dim3(512, 8), 256, 0, stream>>>(y, nullptr, nullptr, xs_bf, BS, 128, 32768, 1, BS, 64, 1, 16384, 64, 128);

  // ---- AdaptiveGCN: branch sum (bf16) -> G3, partials -> part+0 ----
  k_mix0<<<1024, 64, 0, stream>>>(xs_bf, gcnw_bf, gcn_b, s0bf);
  k_mix6<<<dim3(1024, 3), 64, 0, stream>>>(xs_bf, gcnw_bf, U1, U2, U3, U4, U5, U6);
  k_adj2M<<<512, 256, 0, stream>>>(a1_bf, U2, U1, Q1bf);
  k_adj2M<<<512, 256, 0, stream>>>(a2_bf, U4, U3, Q2bf);
  k_adj2M<<<512, 256, 0, stream>>>(adp_bf, U6, U5, Q3bf);
  k_gn_partB<<<dim3(64, 8), 256, 0, stream>>>(y, s0bf, Q1bf, Q2bf, Q3bf, SLb, part);

  // ---- Linformer spatial attention: attn+proj fused -> G4 fp32 ----
  k_qkvs_M<<<1024, 256, 0, stream>>>(xs_bf, swqT, swkT, swvT, qbuf, xkT, xvT);
  k_sprojM<<<dim3(256, 2), 256, 0, stream>>>(xkT, xvT, PkT, PvT, kpb, vptb);
  k_attnP<64, 1><<<512, 512, 0, stream>>>(qbuf, kpb, vptb, swoT, s_bo, G4);
  k_tr<<<dim3(512, 8), 256, 0, stream>>>(G4, nullptr, y, SSb, BS, 64, 16384, 1, BS, 128, 1, 32768, 128, 64);
  k_gn_part1B<<<dim3(64, 8), 256, 0, stream>>>(SSb, part + 2048);

  // ---- temporal transformer layer: attn+proj fused -> G6 fp32; sum bf16 -> G2 ----
  k_tr<<<dim3(512, 8), 256, 0, stream>>>(y, G2, nullptr, xt_bf, BS, 128, 32768, 1, BS, 8192, 1, 64, 64, 128);
  k_qkvt_M<<<1024, 256, 0, stream>>>(xt_bf, twqT, twkT, twvT, t_bq, t_bk, t_bv, qbuf, kbuf, vtbuf);
  k_attnP<128, 0><<<512, 512, 0, stream>>>(qbuf, kbuf, vtbuf, twoT, t_bo, G6);
  k_tffn<<<1024, 256, 0, stream>>>(G2, G6, t_l1w, t_l1b, t_l2w, t_l2b,
                                   ln1g, ln1b, ln2g, ln2b, G0);
  k_tr<<<dim3(512, 8), 256, 0, stream>>>(G0, nullptr, y, STb, BS, 8192, 64, 1, BS, 128, 1, 32768, 128, 64);
  k_gn_part1B<<<dim3(64, 8), 256, 0, stream>>>(STb, part + 4096);

  // ---- fused triple-GN: y_in2 = GN_l + GN_s + GN_t -> G4 fp32 ----
  k_gn_apply3B<<<4096, 256, 0, stream>>>(SLb, SSb, STb, part, gnlg, gnlb, gnsg, gnsb, gntg, gntb, G4);

  // ---- fuse + channel FFN + final GroupNorm ----
  k_tr<<<dim3(512, 8), 256, 0, stream>>>(G4, nullptr, nullptr, (unsigned short*)G5,
                                         BS, 128, 32768, 1, BS, 8192, 1, 64, 64, 128);
  k_cffn<<<1024, 256, 0, stream>>>((unsigned short*)G5, ff1T, ff2T, ff1b, ff2b, G6);
  k_tr<<<dim3(512, 8), 256, 0, stream>>>(G6, out, G4, nullptr, BS, 8192, 64, 1, BS, 128, 1, 32768, 128, 64);
  k_gn_part<<<dim3(64, 8), 256, 0, stream>>>(out, part);
  k_gn_apply<<<4096, 256, 0, stream>>>(out, part, gn2g, gn2b, out);
}

// Round 28
// 323.026 us; speedup vs baseline: 1.9292x; 1.0498x over previous
//
#include <hip/hip_runtime.h>
#include <hip/hip_bf16.h>
#include <math.h>

constexpr int CC = 64, KK = 256, LL = 128;
constexpr int NN = KK * LL;          // 32768
constexpr int PR = 64;               // Linformer projection
constexpr int CPG = 16;              // channels per group (C / 4)
constexpr float EPSV = 1e-5f;
constexpr float SCL = 0.35355339059327373f;  // 1/sqrt(8)

typedef __attribute__((ext_vector_type(8))) short short8;      // 8 bf16 (4 VGPR)
typedef __attribute__((ext_vector_type(4))) float f32x4;       // MFMA 16x16 acc

__device__ __forceinline__ unsigned short f2bf(float x) {
  __hip_bfloat16 h = __float2bfloat16(x);
  union { __hip_bfloat16 b; unsigned short u; } v; v.b = h;
  return v.u;
}
__device__ __forceinline__ float bf2f(unsigned short x) {
  union { unsigned int u; float f; } v; v.u = ((unsigned int)x) << 16;
  return v.f;
}

// ---------------- merged setup: blocks <960 = weight casts; blocks >=960 = adaptive adjacency ----------------
__global__ __launch_bounds__(256) void k_setup(const float* __restrict__ s0, const float* __restrict__ s1,
                                               const float* __restrict__ s2,
                                               const float* __restrict__ swo, const float* __restrict__ two,
                                               const float* __restrict__ f1, const float* __restrict__ f2,
                                               const float* __restrict__ swq, const float* __restrict__ swk,
                                               const float* __restrict__ swv,
                                               const float* __restrict__ twq, const float* __restrict__ twk,
                                               const float* __restrict__ twv,
                                               const float* __restrict__ pk, const float* __restrict__ pv,
                                               const float* __restrict__ nv1, const float* __restrict__ nv2,
                                               unsigned short* __restrict__ d0, unsigned short* __restrict__ d1,
                                               unsigned short* __restrict__ d2,
                                               unsigned short* __restrict__ swoT, unsigned short* __restrict__ twoT,
                                               unsigned short* __restrict__ ff1T, unsigned short* __restrict__ ff2T,
                                               unsigned short* __restrict__ swqT, unsigned short* __restrict__ swkT,
                                               unsigned short* __restrict__ swvT,
                                               unsigned short* __restrict__ twqT, unsigned short* __restrict__ twkT,
                                               unsigned short* __restrict__ twvT,
                                               unsigned short* __restrict__ PkT, unsigned short* __restrict__ PvT,
                                               unsigned short* __restrict__ adp_bf) {
  __shared__ float red[256];
  if (blockIdx.x < 960) {
    int i = blockIdx.x * 256 + threadIdx.x;
    if (i < 65536) d0[i] = f2bf(s0[i]);
    else if (i < 131072) d1[i - 65536] = f2bf(s1[i - 65536]);
    else if (i < 159744) d2[i - 131072] = f2bf(s2[i - 131072]);
    else if (i >= 163840) {
      int j = i - 163840;
      if (j < 4096) { int r = j >> 6, c = j & 63; swoT[c * 64 + r] = f2bf(swo[j]); }
      else if (j < 8192) { int q = j - 4096; int r = q >> 6, c = q & 63; twoT[c * 64 + r] = f2bf(two[q]); }
      else if (j < 16384) { int q = j - 8192; int r = q >> 7, c = q & 127; ff1T[c * 64 + r] = f2bf(f1[q]); }
      else if (j < 24576) { int q = j - 16384; int r = q >> 6, c = q & 63; ff2T[c * 128 + r] = f2bf(f2[q]); }
      else if (j < 28672) { int q = j - 24576; int r = q >> 6, c = q & 63; swqT[c * 64 + r] = f2bf(swq[q]); }
      else if (j < 32768) { int q = j - 28672; int r = q >> 6, c = q & 63; swkT[c * 64 + r] = f2bf(swk[q]); }
      else if (j < 36864) { int q = j - 32768; int r = q >> 6, c = q & 63; swvT[c * 64 + r] = f2bf(swv[q]); }
      else if (j < 40960) { int q = j - 36864; int r = q >> 6, c = q & 63; twqT[c * 64 + r] = f2bf(twq[q]); }
      else if (j < 45056) { int q = j - 40960; int r = q >> 6, c = q & 63; twkT[c * 64 + r] = f2bf(twk[q]); }
      else if (j < 49152) { int q = j - 45056; int r = q >> 6, c = q & 63; twvT[c * 64 + r] = f2bf(twv[q]); }
      else if (j < 65536) { int q = j - 49152; int n = q >> 6, c = q & 63; PkT[c * 256 + n] = f2bf(pk[q]); }
      else if (j < 81920) { int q = j - 65536; int n = q >> 6, c = q & 63; PvT[c * 256 + n] = f2bf(pv[q]); }
    }
  } else {
    int w = blockIdx.x - 960, v = threadIdx.x;
    float s = 0.f;
    for (int d = 0; d < 10; ++d) s += nv1[w * 10 + d] * nv2[d * KK + v];
    s = fmaxf(s, 0.f);
    red[v] = s; __syncthreads();
    for (int off = 128; off; off >>= 1) { if (v < off) red[v] = fmaxf(red[v], red[v + off]); __syncthreads(); }
    float m = red[0]; __syncthreads();
    float e = expf(s - m);
    red[v] = e; __syncthreads();
    for (int off = 128; off; off >>= 1) { if (v < off) red[v] += red[v + off]; __syncthreads(); }
    adp_bf[w * KK + v] = f2bf(e / red[0]);
  }
}

// ---------------- merged GCN mixes: blocks <1024 = s0 term; else U terms ----------------
__global__ __launch_bounds__(64) void k_mixall(const unsigned short* __restrict__ Xbf,
                                               const unsigned short* __restrict__ Wbf,
                                               const float* __restrict__ bias,
                                               unsigned short* __restrict__ s0out,
                                               unsigned short* __restrict__ U1, unsigned short* __restrict__ U2,
                                               unsigned short* __restrict__ U3, unsigned short* __restrict__ U4,
                                               unsigned short* __restrict__ U5, unsigned short* __restrict__ U6) {
  int lane = threadIdx.x;
  int lr = lane & 15, g = lane >> 4;
  if (blockIdx.x < 1024) {
    int pb = blockIdx.x;
    int lh = pb & 1;
    int k = (pb >> 1) & 255;
    int b = pb >> 9;
    short8 af[4][2], bfv[4][2];
#pragma unroll
    for (int ot = 0; ot < 4; ++ot)
#pragma unroll
      for (int kc = 0; kc < 2; ++kc)
        af[ot][kc] = *(const short8*)(Wbf + (size_t)(ot * 16 + lr) * 448 + kc * 32 + g * 8);
#pragma unroll
    for (int ct = 0; ct < 4; ++ct)
#pragma unroll
      for (int kc = 0; kc < 2; ++kc)
        bfv[ct][kc] = *(const short8*)(Xbf + ((size_t)(b * 128 + lh * 64 + ct * 16 + lr) * 256 + k) * 64 + kc * 32 + g * 8);
    f32x4 acc[4][4];
#pragma unroll
    for (int ot = 0; ot < 4; ++ot)
#pragma unroll
      for (int ct = 0; ct < 4; ++ct) acc[ot][ct] = f32x4{0.f, 0.f, 0.f, 0.f};
#pragma unroll
    for (int kc = 0; kc < 2; ++kc)
#pragma unroll
      for (int ot = 0; ot < 4; ++ot)
#pragma unroll
        for (int ct = 0; ct < 4; ++ct)
          acc[ot][ct] = __builtin_amdgcn_mfma_f32_16x16x32_bf16(af[ot][kc], bfv[ct][kc], acc[ot][ct], 0, 0, 0);
#pragma unroll
    for (int ot = 0; ot < 4; ++ot)
#pragma unroll
      for (int ct = 0; ct < 4; ++ct) {
#pragma unroll
        for (int reg = 0; reg < 4; ++reg) {
          int o = ot * 16 + g * 4 + reg;
          s0out[(size_t)(b * 64 + o) * NN + (size_t)k * 128 + lh * 64 + ct * 16 + lr] = f2bf(acc[ot][ct][reg] + bias[o]);
        }
      }
  } else {
    int idx = blockIdx.x - 1024;
    int pb = idx & 1023;
    int sy = idx >> 10;
    int b = pb >> 9;
    int rem = pb & 511;
    int l = rem >> 2;
    int kq = (rem & 3) * 64;
    size_t posbase = ((size_t)(b * 128 + l)) * 256 + kq;

    short8 af[4][2];
#pragma unroll
    for (int rt = 0; rt < 4; ++rt)
#pragma unroll
      for (int kc = 0; kc < 2; ++kc)
        af[rt][kc] = *(const short8*)(Xbf + (posbase + rt * 16 + lr) * 64 + kc * 32 + g * 8);

    for (int si = 0; si < 2; ++si) {
      int s = sy * 2 + 1 + si;
      short8 bfv[4][2];
#pragma unroll
      for (int ct = 0; ct < 4; ++ct)
#pragma unroll
        for (int kc = 0; kc < 2; ++kc)
          bfv[ct][kc] = *(const short8*)(Wbf + (size_t)(ct * 16 + lr) * 448 + s * 64 + kc * 32 + g * 8);
      f32x4 acc[4][4];
#pragma unroll
      for (int rt = 0; rt < 4; ++rt)
#pragma unroll
        for (int ct = 0; ct < 4; ++ct) acc[rt][ct] = f32x4{0.f, 0.f, 0.f, 0.f};
#pragma unroll
      for (int kc = 0; kc < 2; ++kc)
#pragma unroll
        for (int rt = 0; rt < 4; ++rt)
#pragma unroll
          for (int ct = 0; ct < 4; ++ct)
            acc[rt][ct] = __builtin_amdgcn_mfma_f32_16x16x32_bf16(af[rt][kc], bfv[ct][kc], acc[rt][ct], 0, 0, 0);
      unsigned short* dst = (s == 1) ? U1 : (s == 2) ? U2 : (s == 3) ? U3
                          : (s == 4) ? U4 : (s == 5) ? U5 : U6;
#pragma unroll
      for (int rt = 0; rt < 4; ++rt)
#pragma unroll
        for (int ct = 0; ct < 4; ++ct) {
          int o = ct * 16 + lr;
          int k = kq + rt * 16 + g * 4;
          ushort4 pk;
          pk.x = f2bf(acc[rt][ct][0]); pk.y = f2bf(acc[rt][ct][1]);
          pk.z = f2bf(acc[rt][ct][2]); pk.w = f2bf(acc[rt][ct][3]);
          *(ushort4*)&dst[((size_t)(b * 64 + o) * 128 + l) * 256 + k] = pk;
        }
    }
  }
}

// ---------------- fused 2-hop (bf16 out); grid (512,3) covers all three adjacency terms ----------------
__global__ __launch_bounds__(256) void k_adj3(const unsigned short* __restrict__ A0,
                                              const unsigned short* __restrict__ A1,
                                              const unsigned short* __restrict__ A2,
                                              const unsigned short* __restrict__ U1, const unsigned short* __restrict__ U2,
                                              const unsigned short* __restrict__ U3, const unsigned short* __restrict__ U4,
                                              const unsigned short* __restrict__ U5, const unsigned short* __restrict__ U6,
                                              unsigned short* __restrict__ O0, unsigned short* __restrict__ O1,
                                              unsigned short* __restrict__ O2) {
  int which = blockIdx.y;
  const unsigned short* Abf = (which == 0) ? A0 : (which == 1) ? A1 : A2;
  const unsigned short* Ueven = (which == 0) ? U2 : (which == 1) ? U4 : U6;
  const unsigned short* Uodd  = (which == 0) ? U1 : (which == 1) ? U3 : U5;
  unsigned short* out = (which == 0) ? O0 : (which == 1) ? O1 : O2;

  __shared__ unsigned short sH[32 * 256];
  int lq = blockIdx.x & 3, bc = blockIdx.x >> 2;
  int tid = threadIdx.x, wid = tid >> 6, lane = tid & 63;
  int lr = lane & 15, g = lane >> 4;
  int wbase = wid * 64;
  const unsigned short* aP = Abf + (size_t)(wbase + lr) * 256 + g * 8;
  const unsigned short* bP = Ueven + ((size_t)bc * 128 + lq * 32 + lr) * 256 + g * 8;

  f32x4 acc[4][2];
#pragma unroll
  for (int i = 0; i < 4; ++i)
#pragma unroll
    for (int j = 0; j < 2; ++j) acc[i][j] = f32x4{0.f, 0.f, 0.f, 0.f};
  for (int k0 = 0; k0 < 256; k0 += 32) {
    short8 af[4], bfv[2];
#pragma unroll
    for (int i = 0; i < 4; ++i) af[i] = *(const short8*)(aP + (size_t)i * 16 * 256 + k0);
#pragma unroll
    for (int i = 0; i < 2; ++i) bfv[i] = *(const short8*)(bP + (size_t)i * 16 * 256 + k0);
#pragma unroll
    for (int rm = 0; rm < 4; ++rm)
#pragma unroll
      for (int cn = 0; cn < 2; ++cn)
        acc[rm][cn] = __builtin_amdgcn_mfma_f32_16x16x32_bf16(af[rm], bfv[cn], acc[rm][cn], 0, 0, 0);
  }
  {
    const unsigned short* aT = Uodd + (size_t)bc * NN + (size_t)(lq * 32) * 256;
#pragma unroll
    for (int rm = 0; rm < 4; ++rm)
#pragma unroll
      for (int cn = 0; cn < 2; ++cn) {
        int l = cn * 16 + lr;
        int v = wbase + rm * 16 + g * 4;
        ushort4 av = *(const ushort4*)&aT[(size_t)l * 256 + v];
        ushort4 pk;
        pk.x = f2bf(acc[rm][cn][0] + bf2f(av.x));
        pk.y = f2bf(acc[rm][cn][1] + bf2f(av.y));
        pk.z = f2bf(acc[rm][cn][2] + bf2f(av.z));
        pk.w = f2bf(acc[rm][cn][3] + bf2f(av.w));
        int bo = ((l * 256 + v) * 2) ^ ((l & 7) << 4);
        *(ushort4*)((char*)sH + bo) = pk;
      }
  }
  __syncthreads();

  f32x4 c2[4][2];
#pragma unroll
  for (int i = 0; i < 4; ++i)
#pragma unroll
    for (int j = 0; j < 2; ++j) c2[i][j] = f32x4{0.f, 0.f, 0.f, 0.f};
  for (int k0 = 0; k0 < 256; k0 += 32) {
    short8 af[4], bfv[2];
#pragma unroll
    for (int i = 0; i < 4; ++i) af[i] = *(const short8*)(aP + (size_t)i * 16 * 256 + k0);
#pragma unroll
    for (int cn = 0; cn < 2; ++cn) {
      int l = cn * 16 + lr;
      int bo = ((l * 256 + k0 + g * 8) * 2) ^ ((l & 7) << 4);
      bfv[cn] = *(const short8*)((char*)sH + bo);
    }
#pragma unroll
    for (int rm = 0; rm < 4; ++rm)
#pragma unroll
      for (int cn = 0; cn < 2; ++cn)
        c2[rm][cn] = __builtin_amdgcn_mfma_f32_16x16x32_bf16(af[rm], bfv[cn], c2[rm][cn], 0, 0, 0);
  }
  unsigned short* dst = out + (size_t)bc * NN + lq * 32;
#pragma unroll
  for (int rm = 0; rm < 4; ++rm)
#pragma unroll
    for (int cn = 0; cn < 2; ++cn) {
      int col = cn * 16 + lr;
      int row = wbase + rm * 16 + g * 4;
#pragma unroll
      for (int j = 0; j < 4; ++j)
        dst[(size_t)(row + j) * 128 + col] = f2bf(c2[rm][cn][j]);
    }
}

// ---------------- generic (c,l)-plane transpose; optional dst/add/bf16 ----------------
__global__ __launch_bounds__(256) void k_tr(const float* __restrict__ src, float* __restrict__ dst,
                                            const float* __restrict__ add,
                                            unsigned short* __restrict__ dstBf,
                                            long sb, long sk, long sc, long sl,
                                            long db, long dk, long dc, long dl, int nC, int nL) {
  int outer = blockIdx.x;
  int b = outer >> 8, k = outer & 255;
  int tilesL = nL >> 5;
  int tC = blockIdx.y / tilesL, tL = blockIdx.y % tilesL;
  int c0 = tC << 5, l0 = tL << 5;
  __shared__ float s[32][33];
  int tx = threadIdx.x & 31, ty = threadIdx.x >> 5;
  const float* sp = src + (long)b * sb + (long)k * sk;
#pragma unroll
  for (int j = 0; j < 4; ++j) {
    int cc = c0 + ty + j * 8;
    s[ty + j * 8][tx] = sp[(long)cc * sc + (long)(l0 + tx) * sl];
  }
  __syncthreads();
  long dbase = (long)b * db + (long)k * dk;
#pragma unroll
  for (int j = 0; j < 4; ++j) {
    int ll = l0 + ty + j * 8;
    long off = dbase + (long)(c0 + tx) * dc + (long)ll * dl;
    float val = s[tx][ty + j * 8];
    if (add) val += add[off];
    if (dst) dst[off] = val;
    if (dstBf) dstBf[off] = f2bf(val);
  }
}

// ---------------- merged: spatial QKV (blocks <1024) + temporal pre-transpose (blocks >=1024) ----------------
__global__ __launch_bounds__(256) void k_qkvs_tr(const unsigned short* __restrict__ Xbf,
                                                 const unsigned short* __restrict__ wqT,
                                                 const unsigned short* __restrict__ wkT,
                                                 const unsigned short* __restrict__ wvT,
                                                 unsigned short* __restrict__ qb,
                                                 unsigned short* __restrict__ xkT,
                                                 unsigned short* __restrict__ xvT,
                                                 const float* __restrict__ y,
                                                 float* __restrict__ xtF,
                                                 unsigned short* __restrict__ xtBf) {
  __shared__ float sTile[32][33];
  if (blockIdx.x >= 1024) {
    // temporal pre-transpose: y (B,C,K,L) -> xt (B,K,L,C) fp32 + bf16
    int tb = blockIdx.x - 1024;
    int outer = tb >> 3, yy = tb & 7;
    int b = outer >> 8, k = outer & 255;
    int tC = yy >> 2, tL = yy & 3;
    int c0 = tC << 5, l0 = tL << 5;
    int tx = threadIdx.x & 31, ty = threadIdx.x >> 5;
    const float* sp = y + (long)b * 2097152 + (long)k * 128;
#pragma unroll
    for (int j = 0; j < 4; ++j) {
      int cc = c0 + ty + j * 8;
      sTile[ty + j * 8][tx] = sp[(long)cc * 32768 + (long)(l0 + tx)];
    }
    __syncthreads();
    long dbase = (long)b * 2097152 + (long)k * 8192;
#pragma unroll
    for (int j = 0; j < 4; ++j) {
      int ll = l0 + ty + j * 8;
      long off = dbase + (long)(c0 + tx) + (long)ll * 64;
      float val = sTile[tx][ty + j * 8];
      xtF[off] = val;
      xtBf[off] = f2bf(val);
    }
    return;
  }
  int r0 = blockIdx.x * 64;
  int t = threadIdx.x, w = t >> 6, lane = t & 63;
  int lr = lane & 15, g = lane >> 4;
  const unsigned short* aP = Xbf + (size_t)(r0 + w * 16 + lr) * 64 + g * 8;
  short8 ax0 = *(const short8*)aP;
  short8 ax1 = *(const short8*)(aP + 32);
  {
    f32x4 acc[4];
#pragma unroll
    for (int ct = 0; ct < 4; ++ct) acc[ct] = f32x4{0.f, 0.f, 0.f, 0.f};
#pragma unroll
    for (int ct = 0; ct < 4; ++ct) {
      short8 b0 = *(const short8*)(wqT + (size_t)(ct * 16 + lr) * 64 + g * 8);
      short8 b1 = *(const short8*)(wqT + (size_t)(ct * 16 + lr) * 64 + 32 + g * 8);
      acc[ct] = __builtin_amdgcn_mfma_f32_16x16x32_bf16(ax0, b0, acc[ct], 0, 0, 0);
      acc[ct] = __builtin_amdgcn_mfma_f32_16x16x32_bf16(ax1, b1, acc[ct], 0, 0, 0);
    }
#pragma unroll
    for (int ct = 0; ct < 4; ++ct)
#pragma unroll
      for (int reg = 0; reg < 4; ++reg)
        qb[(size_t)(r0 + w * 16 + g * 4 + reg) * 64 + ct * 16 + lr] = f2bf(acc[ct][reg]);
  }
  short8 bx0[4], bx1[4];
#pragma unroll
  for (int ct = 0; ct < 4; ++ct) {
    const unsigned short* bP = Xbf + (size_t)(r0 + ct * 16 + lr) * 64 + g * 8;
    bx0[ct] = *(const short8*)bP;
    bx1[ct] = *(const short8*)(bP + 32);
  }
  int bl = r0 >> 8, nb = r0 & 255;
#pragma unroll
  for (int which = 0; which < 2; ++which) {
    const unsigned short* WT = which ? wvT : wkT;
    unsigned short* dstb = which ? xvT : xkT;
    short8 aw0 = *(const short8*)(WT + (size_t)(w * 16 + lr) * 64 + g * 8);
    short8 aw1 = *(const short8*)(WT + (size_t)(w * 16 + lr) * 64 + 32 + g * 8);
    f32x4 acc[4];
#pragma unroll
    for (int ct = 0; ct < 4; ++ct) {
      acc[ct] = f32x4{0.f, 0.f, 0.f, 0.f};
      acc[ct] = __builtin_amdgcn_mfma_f32_16x16x32_bf16(aw0, bx0[ct], acc[ct], 0, 0, 0);
      acc[ct] = __builtin_amdgcn_mfma_f32_16x16x32_bf16(aw1, bx1[ct], acc[ct], 0, 0, 0);
    }
#pragma unroll
    for (int ct = 0; ct < 4; ++ct)
#pragma unroll
      for (int reg = 0; reg < 4; ++reg) {
        int o = w * 16 + g * 4 + reg;
        dstb[(size_t)bl * 16384 + (size_t)o * 256 + nb + ct * 16 + lr] = f2bf(acc[ct][reg]);
      }
  }
}

// ---------------- merged: temporal QKV (blocks <1024) + gn_part1B on SSb (blocks >=1024) ----------------
__global__ __launch_bounds__(256) void k_qkvt_gn(const unsigned short* __restrict__ Xbf,
                                                 const unsigned short* __restrict__ wqT,
                                                 const unsigned short* __restrict__ wkT,
                                                 const unsigned short* __restrict__ wvT,
                                                 const float* __restrict__ bq, const float* __restrict__ bk_,
                                                 const float* __restrict__ bv,
                                                 unsigned short* __restrict__ qb,
                                                 unsigned short* __restrict__ kb,
                                                 unsigned short* __restrict__ vt,
                                                 const unsigned short* __restrict__ gnIn,
                                                 float* __restrict__ gnPart) {
  __shared__ float rs[256], rq[256];
  if (blockIdx.x >= 1024) {
    int tb = blockIdx.x - 1024;
    int blk = tb & 63, bg = tb >> 6, t = threadIdx.x;
    size_t start = (size_t)bg * ((size_t)CPG * NN) + (size_t)blk * 8192;
    const ushort4* q0 = (const ushort4*)(gnIn + start);
    float s = 0.f, ss = 0.f;
    for (int i = t; i < 2048; i += 256) {
      ushort4 u = q0[i];
      float a = bf2f(u.x), b = bf2f(u.y), c = bf2f(u.z), d = bf2f(u.w);
      s += a + b + c + d;
      ss += a * a + b * b + c * c + d * d;
    }
    rs[t] = s; rq[t] = ss; __syncthreads();
    for (int off = 128; off; off >>= 1) { if (t < off) { rs[t] += rs[t + off]; rq[t] += rq[t + off]; } __syncthreads(); }
    if (t == 0) { gnPart[(bg * 64 + blk) * 2] = rs[0]; gnPart[(bg * 64 + blk) * 2 + 1] = rq[0]; }
    return;
  }
  int r0 = blockIdx.x * 64;
  int t = threadIdx.x, w = t >> 6, lane = t & 63;
  int lr = lane & 15, g = lane >> 4;
  const unsigned short* aP = Xbf + (size_t)(r0 + w * 16 + lr) * 64 + g * 8;
  short8 ax0 = *(const short8*)aP;
  short8 ax1 = *(const short8*)(aP + 32);
#pragma unroll
  for (int which = 0; which < 2; ++which) {
    const unsigned short* WT = which ? wkT : wqT;
    const float* bias = which ? bk_ : bq;
    unsigned short* dstb = which ? kb : qb;
    f32x4 acc[4];
#pragma unroll
    for (int ct = 0; ct < 4; ++ct) {
      acc[ct] = f32x4{0.f, 0.f, 0.f, 0.f};
      short8 b0 = *(const short8*)(WT + (size_t)(ct * 16 + lr) * 64 + g * 8);
      short8 b1 = *(const short8*)(WT + (size_t)(ct * 16 + lr) * 64 + 32 + g * 8);
      acc[ct] = __builtin_amdgcn_mfma_f32_16x16x32_bf16(ax0, b0, acc[ct], 0, 0, 0);
      acc[ct] = __builtin_amdgcn_mfma_f32_16x16x32_bf16(ax1, b1, acc[ct], 0, 0, 0);
    }
#pragma unroll
    for (int ct = 0; ct < 4; ++ct) {
      float bvv = bias[ct * 16 + lr];
#pragma unroll
      for (int reg = 0; reg < 4; ++reg)
        dstb[(size_t)(r0 + w * 16 + g * 4 + reg) * 64 + ct * 16 + lr] = f2bf(acc[ct][reg] + bvv);
    }
  }
  short8 bx0[4], bx1[4];
#pragma unroll
  for (int ct = 0; ct < 4; ++ct) {
    const unsigned short* bP = Xbf + (size_t)(r0 + ct * 16 + lr) * 64 + g * 8;
    bx0[ct] = *(const short8*)bP;
    bx1[ct] = *(const short8*)(bP + 32);
  }
  int bkk = r0 >> 7, lbase = r0 & 127;
  short8 aw0 = *(const short8*)(wvT + (size_t)(w * 16 + lr) * 64 + g * 8);
  short8 aw1 = *(const short8*)(wvT + (size_t)(w * 16 + lr) * 64 + 32 + g * 8);
  f32x4 acc[4];
#pragma unroll
  for (int ct = 0; ct < 4; ++ct) {
    acc[ct] = f32x4{0.f, 0.f, 0.f, 0.f};
    acc[ct] = __builtin_amdgcn_mfma_f32_16x16x32_bf16(aw0, bx0[ct], acc[ct], 0, 0, 0);
    acc[ct] = __builtin_amdgcn_mfma_f32_16x16x32_bf16(aw1, bx1[ct], acc[ct], 0, 0, 0);
  }
  int lb4 = lbase >> 4;   // 0 or 4
#pragma unroll
  for (int ct = 0; ct < 4; ++ct)
#pragma unroll
    for (int reg = 0; reg < 4; ++reg) {
      int o = w * 16 + g * 4 + reg;
      // col c = lbase + ct*16 + lr -> sigma(c) = lr*8 + lb4 + ct
      vt[(size_t)bkk * 8192 + (size_t)o * 128 + lr * 8 + lb4 + ct] = f2bf(acc[ct][reg] + bv[o]);
    }
}

// ---------------- MFMA sproj; V^T output stored with sigma-permuted p-columns ----------------
__global__ __launch_bounds__(256) void k_sprojM(const unsigned short* __restrict__ XkT,
                                                const unsigned short* __restrict__ XvT,
                                                const unsigned short* __restrict__ PkT,
                                                const unsigned short* __restrict__ PvT,
                                                unsigned short* __restrict__ kpb,
                                                unsigned short* __restrict__ vptb) {
  int bl = blockIdx.x;
  int which = blockIdx.y;
  int t = threadIdx.x, w = t >> 6, lane = t & 63;
  int lr = lane & 15, g = lane >> 4;
  const unsigned short* Abase = which ? PvT : XkT + (size_t)bl * 16384;
  const unsigned short* Bbase = which ? XvT + (size_t)bl * 16384 : PkT;
  const unsigned short* aP = Abase + (size_t)(w * 16 + lr) * 256 + g * 8;
  f32x4 acc[4];
#pragma unroll
  for (int ct = 0; ct < 4; ++ct) acc[ct] = f32x4{0.f, 0.f, 0.f, 0.f};
  for (int k0 = 0; k0 < 256; k0 += 32) {
    short8 af = *(const short8*)(aP + k0);
#pragma unroll
    for (int ct = 0; ct < 4; ++ct) {
      short8 bf = *(const short8*)(Bbase + (size_t)(ct * 16 + lr) * 256 + k0 + g * 8);
      acc[ct] = __builtin_amdgcn_mfma_f32_16x16x32_bf16(af, bf, acc[ct], 0, 0, 0);
    }
  }
  if (!which) {
    unsigned short* dst = kpb + (size_t)bl * 4096;
#pragma unroll
    for (int ct = 0; ct < 4; ++ct) {
      int p = ct * 16 + lr;
      int c0 = w * 16 + g * 4;
      ushort4 pk;
      pk.x = f2bf(acc[ct][0]); pk.y = f2bf(acc[ct][1]);
      pk.z = f2bf(acc[ct][2]); pk.w = f2bf(acc[ct][3]);
      *(ushort4*)&dst[(size_t)p * 64 + c0] = pk;
    }
  } else {
    unsigned short* dst = vptb + (size_t)bl * 4096;
#pragma unroll
    for (int ct = 0; ct < 4; ++ct) {
      int c = ct * 16 + lr;
      // p = w*16 + g*4 + reg -> sigma(p) = (g*4+reg)*4 + w
#pragma unroll
      for (int reg = 0; reg < 4; ++reg)
        dst[(size_t)c * 64 + (g * 4 + reg) * 4 + w] = f2bf(acc[ct][reg]);
    }
  }
}

// ---------------- fused channel FFN (MFMA) ----------------
__global__ __launch_bounds__(256) void k_cffn(const unsigned short* __restrict__ in,
                                              const unsigned short* __restrict__ ff1T,
                                              const unsigned short* __restrict__ ff2T,
                                              const float* __restrict__ b1,
                                              const float* __restrict__ b2,
                                              float* __restrict__ out) {
  __shared__ unsigned short sH[4][16 * 128];
  int r0 = blockIdx.x * 64;
  int t = threadIdx.x, w = t >> 6, lane = t & 63;
  int lr = lane & 15, g = lane >> 4;
  unsigned short* myH = sH[w];
  const unsigned short* aP = in + (size_t)(r0 + w * 16 + lr) * 64 + g * 8;
  short8 af0 = *(const short8*)aP;
  short8 af1 = *(const short8*)(aP + 32);
  f32x4 acc1[8];
#pragma unroll
  for (int ct = 0; ct < 8; ++ct) acc1[ct] = f32x4{0.f, 0.f, 0.f, 0.f};
#pragma unroll
  for (int ct = 0; ct < 8; ++ct) {
    short8 b0 = *(const short8*)(ff1T + (size_t)(ct * 16 + lr) * 64 + g * 8);
    short8 bx = *(const short8*)(ff1T + (size_t)(ct * 16 + lr) * 64 + 32 + g * 8);
    acc1[ct] = __builtin_amdgcn_mfma_f32_16x16x32_bf16(af0, b0, acc1[ct], 0, 0, 0);
    acc1[ct] = __builtin_amdgcn_mfma_f32_16x16x32_bf16(af1, bx, acc1[ct], 0, 0, 0);
  }
#pragma unroll
  for (int ct = 0; ct < 8; ++ct) {
    int o = ct * 16 + lr;
    float bv = b1[o];
#pragma unroll
    for (int reg = 0; reg < 4; ++reg) {
      int m = g * 4 + reg;
      float h = fmaxf(acc1[ct][reg] + bv, 0.f);
      int bo = ((m * 128 + o) * 2) ^ ((m & 7) << 4);
      *(unsigned short*)((char*)myH + bo) = f2bf(h);
    }
  }
  __syncthreads();
  short8 ha[4];
#pragma unroll
  for (int ks = 0; ks < 4; ++ks) {
    int bo = ((lr * 128 + ks * 32 + g * 8) * 2) ^ ((lr & 7) << 4);
    ha[ks] = *(const short8*)((char*)myH + bo);
  }
  f32x4 acc2[4];
#pragma unroll
  for (int ct = 0; ct < 4; ++ct) acc2[ct] = f32x4{0.f, 0.f, 0.f, 0.f};
#pragma unroll
  for (int ct = 0; ct < 4; ++ct)
#pragma unroll
    for (int ks = 0; ks < 4; ++ks) {
      short8 b0 = *(const short8*)(ff2T + (size_t)(ct * 16 + lr) * 128 + ks * 32 + g * 8);
      acc2[ct] = __builtin_amdgcn_mfma_f32_16x16x32_bf16(ha[ks], b0, acc2[ct], 0, 0, 0);
    }
#pragma unroll
  for (int ct = 0; ct < 4; ++ct) {
    int o = ct * 16 + lr;
    float bv = b2[o];
#pragma unroll
    for (int reg = 0; reg < 4; ++reg)
      out[(size_t)(r0 + w * 16 + g * 4 + reg) * 64 + o] = acc2[ct][reg] + bv;
  }
}

// ---------------- fused LN1 -> FFN(64->8 gelu ->64) -> LN2 ----------------
__global__ __launch_bounds__(256) void k_tffn(const float* __restrict__ A, const float* __restrict__ Bz,
                                              const float* __restrict__ l1w, const float* __restrict__ l1b,
                                              const float* __restrict__ l2w, const float* __restrict__ l2b,
                                              const float* __restrict__ ln1g, const float* __restrict__ ln1b,
                                              const float* __restrict__ ln2g, const float* __restrict__ ln2b,
                                              float* __restrict__ outp) {
  int r0 = blockIdx.x * 64;
  __shared__ float sSrc[64][65];
  __shared__ float sH[64][8];
  __shared__ float sW1[64][8];
  __shared__ float sW2[8][64];
  int t = threadIdx.x;
  for (int i = t; i < 512; i += 256) { ((float*)sW1)[i] = l1w[i]; ((float*)sW2)[i] = l2w[i]; }
  int c = t & 63, rg = t >> 6;
  float g1 = ln1g[c], be1 = ln1b[c];
  for (int it = 0; it < 16; ++it) {
    int r = it * 4 + rg;
    size_t idx = (size_t)(r0 + r) * 64 + c;
    float x = A[idx] + Bz[idx];
    float s = x, ss = x * x;
#pragma unroll
    for (int off = 32; off; off >>= 1) { s += __shfl_xor(s, off); ss += __shfl_xor(ss, off); }
    float mu = s * (1.f / 64.f);
    float var = ss * (1.f / 64.f) - mu * mu;
    sSrc[r][c] = (x - mu) * rsqrtf(var + EPSV) * g1 + be1;
  }
  __syncthreads();
#pragma unroll
  for (int p = 0; p < 2; ++p) {
    int idx = t + 256 * p;
    int row = idx >> 3, j = idx & 7;
    float acc = l1b[j];
    for (int cc = 0; cc < 64; ++cc) acc += sSrc[row][cc] * sW1[cc][j];
    acc = 0.5f * acc * (1.f + erff(acc * 0.70710678118654752440f));
    sH[row][j] = acc;
  }
  __syncthreads();
  float g2 = ln2g[c], be2 = ln2b[c];
  float l2bc = l2b[c];
  for (int it = 0; it < 16; ++it) {
    int r = it * 4 + rg;
    float o = l2bc;
#pragma unroll
    for (int j = 0; j < 8; ++j) o += sH[r][j] * sW2[j][c];
    float x = sSrc[r][c] + o;
    float s = x, ss = x * x;
#pragma unroll
    for (int off = 32; off; off >>= 1) { s += __shfl_xor(s, off); ss += __shfl_xor(ss, off); }
    float mu = s * (1.f / 64.f);
    float var = ss * (1.f / 64.f) - mu * mu;
    outp[(size_t)(r0 + r) * 64 + c] = (x - mu) * rsqrtf(var + EPSV) * g2 + be2;
  }
}

// ---------------- per-head MFMA attention + fused output projection -> fp32 ----------------
// P stored in sigma-permuted column layout (ushort4 stores). Softmax denominator computed
// FREE by the PV MFMA: lane lr==8 supplies an all-ones B-row, so output col 8 = row-sum of P.
template <int NKV, int KVSHIFT>
__global__ __launch_bounds__(512) void k_attnP(const unsigned short* __restrict__ Qb,
                                               const unsigned short* __restrict__ Kb,
                                               const unsigned short* __restrict__ VTb,
                                               const unsigned short* __restrict__ WT,
                                               const float* __restrict__ bias,
                                               float* __restrict__ out) {
  constexpr int NCT = NKV / 16;
  constexpr int NKS = NKV / 32;
  int blk = blockIdx.x;
  const unsigned short* Qp = Qb + (size_t)blk * 128 * 64;
  const unsigned short* Kp = Kb + (size_t)(blk >> KVSHIFT) * NKV * 64;
  const unsigned short* VTp = VTb + (size_t)(blk >> KVSHIFT) * 64 * NKV;
  int t = threadIdx.x;
  int h = t >> 6, lane = t & 63, lr = lane & 15, g = lane >> 4;
  __shared__ unsigned short sP[8][16 * NKV];
  __shared__ unsigned short sO[128 * 64];
  unsigned short* myP = sP[h];

  short8 kbf[NCT];
#pragma unroll
  for (int ct = 0; ct < NCT; ++ct)
    kbf[ct] = *(const short8*)(Kp + (size_t)(ct * 16 + lr) * 64 + h * 8);

  short8 vbf[NKS];
  if (lr < 8) {
    int vr = h * 8 + lr;
#pragma unroll
    for (int ks = 0; ks < NKS; ++ks)
      vbf[ks] = *(const short8*)(VTp + (size_t)vr * NKV + ks * 32 + g * 8);
  } else if (lr == 8) {
    const short ONE = (short)0x3F80;  // bf16 1.0
#pragma unroll
    for (int ks = 0; ks < NKS; ++ks)
      vbf[ks] = short8{ONE, ONE, ONE, ONE, ONE, ONE, ONE, ONE};
  } else {
#pragma unroll
    for (int ks = 0; ks < NKS; ++ks)
      vbf[ks] = short8{0, 0, 0, 0, 0, 0, 0, 0};
  }
  int srcl = (lane & 48) | 8;   // lane holding this row-group's col-8 (row sums)

  for (int mt = 0; mt < 8; ++mt) {
    short8 qa = short8{0, 0, 0, 0, 0, 0, 0, 0};
    if (g == 0) qa = *(const short8*)(Qp + (size_t)(mt * 16 + lr) * 64 + h * 8);

    f32x4 sacc[NCT];
#pragma unroll
    for (int ct = 0; ct < NCT; ++ct) sacc[ct] = f32x4{0.f, 0.f, 0.f, 0.f};
#pragma unroll
    for (int ct = 0; ct < NCT; ++ct)
      sacc[ct] = __builtin_amdgcn_mfma_f32_16x16x32_bf16(qa, kbf[ct], sacc[ct], 0, 0, 0);

#pragma unroll
    for (int ct = 0; ct < NCT; ++ct)
#pragma unroll
      for (int reg = 0; reg < 4; ++reg)
        sacc[ct][reg] = __expf(sacc[ct][reg] * SCL);

    // P store: slot sigma(c) = lr*NCT + ct -> contiguous NCT values per row
#pragma unroll
    for (int reg = 0; reg < 4; ++reg) {
      int row = g * 4 + reg;
#pragma unroll
      for (int c4 = 0; c4 < NCT; c4 += 4) {
        ushort4 pk;
        pk.x = f2bf(sacc[c4 + 0][reg]); pk.y = f2bf(sacc[c4 + 1][reg]);
        pk.z = f2bf(sacc[c4 + 2][reg]); pk.w = f2bf(sacc[c4 + 3][reg]);
        int bo = ((row * NKV + lr * NCT + c4) * 2) ^ ((row & 7) << 4);
        *(ushort4*)((char*)myP + bo) = pk;
      }
    }
    // no barrier: myP is wave-private

    f32x4 oacc = f32x4{0.f, 0.f, 0.f, 0.f};
#pragma unroll
    for (int ks = 0; ks < NKS; ++ks) {
      int bo = ((lr * NKV + ks * 32 + g * 8) * 2) ^ ((lr & 7) << 4);
      short8 pa = *(const short8*)((char*)myP + bo);
      oacc = __builtin_amdgcn_mfma_f32_16x16x32_bf16(pa, vbf[ks], oacc, 0, 0, 0);
    }
    float inv4[4];
#pragma unroll
    for (int reg = 0; reg < 4; ++reg)
      inv4[reg] = 1.f / __shfl(oacc[reg], srcl);
    if (lr < 8) {
#pragma unroll
      for (int reg = 0; reg < 4; ++reg) {
        int row = mt * 16 + g * 4 + reg;
        int col = h * 8 + lr;
        int bo = ((row * 64 + col) * 2) ^ ((row & 7) << 4);
        *(unsigned short*)((char*)sO + bo) = f2bf(oacc[reg] * inv4[reg]);
      }
    }
  }
  __syncthreads();

  int row = h * 16 + lr;
  int bo0 = ((row * 64 + g * 8) * 2) ^ ((row & 7) << 4);
  int bo1 = ((row * 64 + 32 + g * 8) * 2) ^ ((row & 7) << 4);
  short8 af0 = *(const short8*)((char*)sO + bo0);
  short8 af1 = *(const short8*)((char*)sO + bo1);
  f32x4 acc[4];
#pragma unroll
  for (int ct = 0; ct < 4; ++ct) acc[ct] = f32x4{0.f, 0.f, 0.f, 0.f};
#pragma unroll
  for (int ct = 0; ct < 4; ++ct) {
    short8 b0 = *(const short8*)(WT + (size_t)(ct * 16 + lr) * 64 + g * 8);
    short8 b1 = *(const short8*)(WT + (size_t)(ct * 16 + lr) * 64 + 32 + g * 8);
    acc[ct] = __builtin_amdgcn_mfma_f32_16x16x32_bf16(af0, b0, acc[ct], 0, 0, 0);
    acc[ct] = __builtin_amdgcn_mfma_f32_16x16x32_bf16(af1, b1, acc[ct], 0, 0, 0);
  }
  float* op = out + (size_t)blk * 128 * 64;
#pragma unroll
  for (int ct = 0; ct < 4; ++ct) {
    int o = ct * 16 + lr;
    float bv = bias[o];
#pragma unroll
    for (int reg = 0; reg < 4; ++reg)
      op[(size_t)(h * 16 + g * 4 + reg) * 64 + o] = acc[ct][reg] + bv;
  }
}

// ---------------- GroupNorm stats (fp32 single input) ----------------
__global__ __launch_bounds__(256) void k_gn_part(const float* __restrict__ p0,
                                                 float* __restrict__ part) {
  int bg = blockIdx.y, blk = blockIdx.x, t = threadIdx.x;
  size_t start = (size_t)bg * ((size_t)CPG * NN) + (size_t)blk * 8192;
  const float4* q0 = (const float4*)(p0 + start);
  float s = 0.f, ss = 0.f;
  for (int i = t; i < 2048; i += 256) {
    float4 x = q0[i];
    s += x.x + x.y + x.z + x.w;
    ss += x.x * x.x + x.y * x.y + x.z * x.z + x.w * x.w;
  }
  __shared__ float rs[256], rq[256];
  rs[t] = s; rq[t] = ss; __syncthreads();
  for (int off = 128; off; off >>= 1) { if (t < off) { rs[t] += rs[t + off]; rq[t] += rq[t + off]; } __syncthreads(); }
  if (t == 0) { part[(bg * 64 + blk) * 2] = rs[0]; part[(bg * 64 + blk) * 2 + 1] = rq[0]; }
}

// ---------------- GroupNorm stats (bf16 single input) ----------------
__global__ __launch_bounds__(256) void k_gn_part1B(const unsigned short* __restrict__ p0,
                                                   float* __restrict__ part) {
  int bg = blockIdx.y, blk = blockIdx.x, t = threadIdx.x;
  size_t start = (size_t)bg * ((size_t)CPG * NN) + (size_t)blk * 8192;
  const ushort4* q0 = (const ushort4*)(p0 + start);
  float s = 0.f, ss = 0.f;
  for (int i = t; i < 2048; i += 256) {
    ushort4 u = q0[i];
    float a = bf2f(u.x), b = bf2f(u.y), c = bf2f(u.z), d = bf2f(u.w);
    s += a + b + c + d;
    ss += a * a + b * b + c * c + d * d;
  }
  __shared__ float rs[256], rq[256];
  rs[t] = s; rq[t] = ss; __syncthreads();
  for (int off = 128; off; off >>= 1) { if (t < off) { rs[t] += rs[t + off]; rq[t] += rq[t + off]; } __syncthreads(); }
  if (t == 0) { part[(bg * 64 + blk) * 2] = rs[0]; part[(bg * 64 + blk) * 2 + 1] = rq[0]; }
}

// ---------------- GroupNorm stats: y(fp32) + 4 bf16 -> bf16 sum + partials ----------------
__global__ __launch_bounds__(256) void k_gn_partB(const float* __restrict__ p0,
                                                  const unsigned short* __restrict__ q1,
                                                  const unsigned short* __restrict__ q2,
                                                  const unsigned short* __restrict__ q3,
                                                  const unsigned short* __restrict__ q4,
                                                  unsigned short* __restrict__ sumOut,
                                                  float* __restrict__ part) {
  int bg = blockIdx.y, blk = blockIdx.x, t = threadIdx.x;
  size_t start = (size_t)bg * ((size_t)CPG * NN) + (size_t)blk * 8192;
  const float4* f0 = (const float4*)(p0 + start);
  const ushort4* b1 = (const ushort4*)(q1 + start);
  const ushort4* b2 = (const ushort4*)(q2 + start);
  const ushort4* b3 = (const ushort4*)(q3 + start);
  const ushort4* b4 = (const ushort4*)(q4 + start);
  ushort4* so = (ushort4*)(sumOut + start);
  float s = 0.f, ss = 0.f;
  for (int i = t; i < 2048; i += 256) {
    float4 x = f0[i];
    ushort4 u;
    u = b1[i]; x.x += bf2f(u.x); x.y += bf2f(u.y); x.z += bf2f(u.z); x.w += bf2f(u.w);
    u = b2[i]; x.x += bf2f(u.x); x.y += bf2f(u.y); x.z += bf2f(u.z); x.w += bf2f(u.w);
    u = b3[i]; x.x += bf2f(u.x); x.y += bf2f(u.y); x.z += bf2f(u.z); x.w += bf2f(u.w);
    u = b4[i]; x.x += bf2f(u.x); x.y += bf2f(u.y); x.z += bf2f(u.z); x.w += bf2f(u.w);
    ushort4 pk;
    pk.x = f2bf(x.x); pk.y = f2bf(x.y); pk.z = f2bf(x.z); pk.w = f2bf(x.w);
    so[i] = pk;
    s += x.x + x.y + x.z + x.w;
    ss += x.x * x.x + x.y * x.y + x.z * x.z + x.w * x.w;
  }
  __shared__ float rs[256], rq[256];
  rs[t] = s; rq[t] = ss; __syncthreads();
  for (int off = 128; off; off >>= 1) { if (t < off) { rs[t] += rs[t + off]; rq[t] += rq[t + off]; } __syncthreads(); }
  if (t == 0) { part[(bg * 64 + blk) * 2] = rs[0]; part[(bg * 64 + blk) * 2 + 1] = rq[0]; }
}

// out = GN(p0) — reduces 64 partials per block (final GN)
__global__ __launch_bounds__(256) void k_gn_apply(const float* __restrict__ p0,
                                                  const float* __restrict__ part, const float* __restrict__ g,
                                                  const float* __restrict__ be,
                                                  float* __restrict__ out) {
  size_t i4 = (size_t)blockIdx.x * 256 + threadIdx.x;
  size_t i = i4 * 4;
  int chan = (int)(i >> 15) & 63;
  int bg = (int)(i >> 19);
  __shared__ float smu, srr;
  int t = threadIdx.x;
  if (t < 64) {
    float s = part[(bg * 64 + t) * 2], ss = part[(bg * 64 + t) * 2 + 1];
#pragma unroll
    for (int off = 32; off; off >>= 1) { s += __shfl_xor(s, off); ss += __shfl_xor(ss, off); }
    if (t == 0) {
      float inv = 1.f / (float)((size_t)CPG * NN);
      float mu = s * inv;
      float var = ss * inv - mu * mu;
      smu = mu; srr = rsqrtf(var + EPSV);
    }
  }
  __syncthreads();
  float mu = smu, rr = srr;
  float4 x = ((const float4*)p0)[i4];
  float gc = g[chan], bc = be[chan];
  float4 v;
  v.x = (x.x - mu) * rr * gc + bc;
  v.y = (x.y - mu) * rr * gc + bc;
  v.z = (x.z - mu) * rr * gc + bc;
  v.w = (x.w - mu) * rr * gc + bc;
  ((float4*)out)[i4] = v;
}

// out = GN_l(SLb) + GN_s(SSb) + GN_t(STb); bf16 inputs; three partial sets at part+0/+2048/+4096
__global__ __launch_bounds__(256) void k_gn_apply3B(const unsigned short* __restrict__ SLb,
                                                    const unsigned short* __restrict__ SSb,
                                                    const unsigned short* __restrict__ STb,
                                                    const float* __restrict__ part,
                                                    const float* __restrict__ gl, const float* __restrict__ bl_,
                                                    const float* __restrict__ gs, const float* __restrict__ bs_,
                                                    const float* __restrict__ gt, const float* __restrict__ bt_,
                                                    float* __restrict__ out) {
  size_t i4 = (size_t)blockIdx.x * 256 + threadIdx.x;
  size_t i = i4 * 4;
  int chan = (int)(i >> 15) & 63;
  int bg = (int)(i >> 19);
  __shared__ float smu[3], srr[3];
  int t = threadIdx.x;
  if (t < 192) {
    int which = t >> 6, tt = t & 63;
    const float* pp = part + which * 2048;
    float s = pp[(bg * 64 + tt) * 2], ss = pp[(bg * 64 + tt) * 2 + 1];
#pragma unroll
    for (int off = 32; off; off >>= 1) { s += __shfl_xor(s, off); ss += __shfl_xor(ss, off); }
    if (tt == 0) {
      float inv = 1.f / (float)((size_t)CPG * NN);
      float mu = s * inv;
      float var = ss * inv - mu * mu;
      smu[which] = mu; srr[which] = rsqrtf(var + EPSV);
    }
  }
  __syncthreads();
  float gL = gl[chan] * srr[0], bL = bl_[chan] - smu[0] * gl[chan] * srr[0];
  float gS = gs[chan] * srr[1], bS = bs_[chan] - smu[1] * gs[chan] * srr[1];
  float gT = gt[chan] * srr[2], bT = bt_[chan] - smu[2] * gt[chan] * srr[2];
  ushort4 ul = ((const ushort4*)SLb)[i4];
  ushort4 us = ((const ushort4*)SSb)[i4];
  ushort4 ut = ((const ushort4*)STb)[i4];
  float4 v;
  v.x = bf2f(ul.x) * gL + bL + bf2f(us.x) * gS + bS + bf2f(ut.x) * gT + bT;
  v.y = bf2f(ul.y) * gL + bL + bf2f(us.y) * gS + bS + bf2f(ut.y) * gT + bT;
  v.z = bf2f(ul.z) * gL + bL + bf2f(us.z) * gS + bS + bf2f(ut.z) * gT + bT;
  v.w = bf2f(ul.w) * gL + bL + bf2f(us.w) * gS + bS + bf2f(ut.w) * gT + bT;
  ((float4*)out)[i4] = v;
}

extern "C" void kernel_launch(void* const* d_in, const int* in_sizes, int n_in,
                              void* d_out, int out_size, void* d_ws, size_t ws_size,
                              hipStream_t stream) {
  (void)in_sizes; (void)n_in; (void)out_size; (void)ws_size;
  const float* y     = (const float*)d_in[0];
  const float* a1    = (const float*)d_in[1];
  const float* a2    = (const float*)d_in[2];
  const float* nv1   = (const float*)d_in[3];
  const float* nv2   = (const float*)d_in[4];
  const float* gcn_w = (const float*)d_in[5];
  const float* gcn_b = (const float*)d_in[6];
  const float* s_wq  = (const float*)d_in[7];
  const float* s_wk  = (const float*)d_in[8];
  const float* s_wv  = (const float*)d_in[9];
  const float* s_pk  = (const float*)d_in[10];
  const float* s_pv  = (const float*)d_in[11];
  const float* s_wo  = (const float*)d_in[12];
  const float* s_bo  = (const float*)d_in[13];
  const float* t_wq  = (const float*)d_in[14];
  const float* t_wk  = (const float*)d_in[15];
  const float* t_wv  = (const float*)d_in[16];
  const float* t_bq  = (const float*)d_in[17];
  const float* t_bk  = (const float*)d_in[18];
  const float* t_bv  = (const float*)d_in[19];
  const float* t_wo  = (const float*)d_in[20];
  const float* t_bo  = (const float*)d_in[21];
  const float* t_l1w = (const float*)d_in[22];
  const float* t_l1b = (const float*)d_in[23];
  const float* t_l2w = (const float*)d_in[24];
  const float* t_l2b = (const float*)d_in[25];
  const float* ln1g  = (const float*)d_in[26];
  const float* ln1b  = (const float*)d_in[27];
  const float* ln2g  = (const float*)d_in[28];
  const float* ln2b  = (const float*)d_in[29];
  const float* gnlg  = (const float*)d_in[30];
  const float* gnlb  = (const float*)d_in[31];
  const float* gnsg  = (const float*)d_in[32];
  const float* gnsb  = (const float*)d_in[33];
  const float* gntg  = (const float*)d_in[34];
  const float* gntb  = (const float*)d_in[35];
  const float* ff1w  = (const float*)d_in[36];
  const float* ff1b  = (const float*)d_in[37];
  const float* ff2w  = (const float*)d_in[38];
  const float* ff2b  = (const float*)d_in[39];
  const float* gn2g  = (const float*)d_in[40];
  const float* gn2b  = (const float*)d_in[41];

  float* ws = (float*)d_ws;
  float* part  = ws + 65536;
  unsigned short* a1_bf   = (unsigned short*)(ws + 131072);
  unsigned short* a2_bf   = (unsigned short*)(ws + 163840);
  unsigned short* adp_bf  = (unsigned short*)(ws + 196608);
  unsigned short* gcnw_bf = (unsigned short*)(ws + 229376);
  unsigned short* xs_bf   = (unsigned short*)(ws + 262144);
  unsigned short* swoT = (unsigned short*)(ws + 2359296);
  unsigned short* twoT = (unsigned short*)(ws + 2361344);
  unsigned short* ff1T = (unsigned short*)(ws + 2363392);
  unsigned short* ff2T = (unsigned short*)(ws + 2367488);
  unsigned short* swqT = (unsigned short*)(ws + 2371584);
  unsigned short* swkT = (unsigned short*)(ws + 2373632);
  unsigned short* swvT = (unsigned short*)(ws + 2375680);
  unsigned short* twqT = (unsigned short*)(ws + 2377728);
  unsigned short* twkT = (unsigned short*)(ws + 2379776);
  unsigned short* twvT = (unsigned short*)(ws + 2381824);
  unsigned short* PkT  = (unsigned short*)(ws + 2383872);
  unsigned short* PvT  = (unsigned short*)(ws + 2392064);
  unsigned short* kpb  = (unsigned short*)(ws + 131072);
  unsigned short* vptb = (unsigned short*)(ws + 1179648);
  const size_t SLOT = 4194304;
  float* G0 = ws + SLOT * 1;
  float* G1 = ws + SLOT * 2;
  float* G2 = ws + SLOT * 3;
  float* G3 = ws + SLOT * 4;
  float* G4 = ws + SLOT * 5;
  float* G5 = ws + SLOT * 6;
  float* G6 = ws + SLOT * 7;
  unsigned short* U1 = (unsigned short*)G3;
  unsigned short* U2 = (unsigned short*)G3 + 4194304;
  unsigned short* U3 = (unsigned short*)G4;
  unsigned short* U4 = (unsigned short*)G4 + 4194304;
  unsigned short* U5 = (unsigned short*)G5;
  unsigned short* U6 = (unsigned short*)G5 + 4194304;
  unsigned short* s0bf = (unsigned short*)G1;
  unsigned short* Q1bf = (unsigned short*)G0;
  unsigned short* Q3bf = (unsigned short*)G0 + 4194304;
  unsigned short* Q2bf = (unsigned short*)G6;
  unsigned short* SLb  = (unsigned short*)G3;   // GCN branch sum (bf16)
  unsigned short* SSb  = (unsigned short*)G1;   // spatial branch sum
  unsigned short* STb  = (unsigned short*)G2;   // temporal branch sum
  unsigned short* qbuf = (unsigned short*)G0;
  unsigned short* xkT = (unsigned short*)G4;
  unsigned short* xvT = (unsigned short*)G5;
  unsigned short* kbuf = (unsigned short*)G4;
  unsigned short* vtbuf = (unsigned short*)G5;
  unsigned short* xt_bf = (unsigned short*)G6;
  float* out = (float*)d_out;

  const long BS = 2097152;

  // ---- merged setup: weight casts + adaptive adjacency ----
  k_setup<<<1216, 256, 0, stream>>>(a1, a2, gcn_w, s_wo, t_wo, ff1w, ff2w,
                                    s_wq, s_wk, s_wv, t_wq, t_wk, t_wv, s_pk, s_pv, nv1, nv2,
                                    a1_bf, a2_bf, gcnw_bf, swoT, twoT, ff1T, ff2T,
                                    swqT, swkT, swvT, twqT, twkT, twvT, PkT, PvT, adp_bf);

  // ---- xs bf16 (B,L,K,C) ----
  k_tr<<<dim3(512, 8), 256, 0, stream>>>(y, nullptr, nullptr, xs_bf, BS, 128, 32768, 1, BS, 64, 1, 16384, 64, 128);

  // ---- AdaptiveGCN (merged mixes + merged 2-hops) ----
  k_mixall<<<4096, 64, 0, stream>>>(xs_bf, gcnw_bf, gcn_b, s0bf, U1, U2, U3, U4, U5, U6);
  k_adj3<<<dim3(512, 3), 256, 0, stream>>>(a1_bf, a2_bf, adp_bf, U1, U2, U3, U4, U5, U6,
                                           Q1bf, Q2bf, Q3bf);
  k_gn_partB<<<dim3(64, 8), 256, 0, stream>>>(y, s0bf, Q1bf, Q2bf, Q3bf, SLb, part);

  // ---- spatial QKV + temporal pre-transpose (merged) ----
  k_qkvs_tr<<<5120, 256, 0, stream>>>(xs_bf, swqT, swkT, swvT, qbuf, xkT, xvT, y, G2, xt_bf);
  k_sprojM<<<dim3(256, 2), 256, 0, stream>>>(xkT, xvT, PkT, PvT, kpb, vptb);
  k_attnP<64, 1><<<512, 512, 0, stream>>>(qbuf, kpb, vptb, swoT, s_bo, G4);
  k_tr<<<dim3(512, 8), 256, 0, stream>>>(G4, nullptr, y, SSb, BS, 64, 16384, 1, BS, 128, 1, 32768, 128, 64);

  // ---- temporal QKV + spatial GN stats (merged) ----
  k_qkvt_gn<<<1536, 256, 0, stream>>>(xt_bf, twqT, twkT, twvT, t_bq, t_bk, t_bv,
                                      qbuf, kbuf, vtbuf, SSb, part + 2048);
  k_attnP<128, 0><<<512, 512, 0, stream>>>(qbuf, kbuf, vtbuf, twoT, t_bo, G6);
  k_tffn<<<1024, 256, 0, stream>>>(G2, G6, t_l1w, t_l1b, t_l2w, t_l2b,
                                   ln1g, ln1b, ln2g, ln2b, G0);
  k_tr<<<dim3(512, 8), 256, 0, stream>>>(G0, nullptr, y, STb, BS, 8192, 64, 1, BS, 128, 1, 32768, 128, 64);
  k_gn_part1B<<<dim3(64, 8), 256, 0, stream>>>(STb, part + 4096);

  // ---- fused triple-GN: y_in2 = GN_l + GN_s + GN_t -> G4 fp32 ----
  k_gn_apply3B<<<4096, 256, 0, stream>>>(SLb, SSb, STb, part, gnlg, gnlb, gnsg, gnsb, gntg, gntb, G4);

  // ---- fuse + channel FFN + final GroupNorm ----
  k_tr<<<dim3(512, 8), 256, 0, stream>>>(G4, nullptr, nullptr, (unsigned short*)G5,
                                         BS, 128, 32768, 1, BS, 8192, 1, 64, 64, 128);
  k_cffn<<<1024, 256, 0, stream>>>((unsigned short*)G5, ff1T, ff2T, ff1b, ff2b, G6);
  k_tr<<<dim3(512, 8), 256, 0, stream>>>(G6, out, G4, nullptr, BS, 8192, 64, 1, BS, 128, 1, 32768, 128, 64);
  k_gn_part<<<dim3(64, 8), 256, 0, stream>>>(out, part);
  k_gn_apply<<<4096, 256, 0, stream>>>(out, part, gn2g, gn2b, out);
}

// Round 29
// 322.317 us; speedup vs baseline: 1.9334x; 1.0022x over previous
//
#include <hip/hip_runtime.h>
#include <hip/hip_bf16.h>
#include <math.h>

constexpr int CC = 64, KK = 256, LL = 128;
constexpr int NN = KK * LL;          // 32768
constexpr int PR = 64;               // Linformer projection
constexpr int CPG = 16;              // channels per group (C / 4)
constexpr float EPSV = 1e-5f;
constexpr float SCL = 0.35355339059327373f;  // 1/sqrt(8)

typedef __attribute__((ext_vector_type(8))) short short8;      // 8 bf16 (4 VGPR)
typedef __attribute__((ext_vector_type(4))) float f32x4;       // MFMA 16x16 acc

__device__ __forceinline__ unsigned short f2bf(float x) {
  __hip_bfloat16 h = __float2bfloat16(x);
  union { __hip_bfloat16 b; unsigned short u; } v; v.b = h;
  return v.u;
}
__device__ __forceinline__ float bf2f(unsigned short x) {
  union { unsigned int u; float f; } v; v.u = ((unsigned int)x) << 16;
  return v.f;
}

// ---------------- merged setup: blocks <960 = weight casts; blocks >=960 = adaptive adjacency ----------------
__global__ __launch_bounds__(256) void k_setup(const float* __restrict__ s0, const float* __restrict__ s1,
                                               const float* __restrict__ s2,
                                               const float* __restrict__ swo, const float* __restrict__ two,
                                               const float* __restrict__ f1, const float* __restrict__ f2,
                                               const float* __restrict__ swq, const float* __restrict__ swk,
                                               const float* __restrict__ swv,
                                               const float* __restrict__ twq, const float* __restrict__ twk,
                                               const float* __restrict__ twv,
                                               const float* __restrict__ pk, const float* __restrict__ pv,
                                               const float* __restrict__ nv1, const float* __restrict__ nv2,
                                               unsigned short* __restrict__ d0, unsigned short* __restrict__ d1,
                                               unsigned short* __restrict__ d2,
                                               unsigned short* __restrict__ swoT, unsigned short* __restrict__ twoT,
                                               unsigned short* __restrict__ ff1T, unsigned short* __restrict__ ff2T,
                                               unsigned short* __restrict__ swqT, unsigned short* __restrict__ swkT,
                                               unsigned short* __restrict__ swvT,
                                               unsigned short* __restrict__ twqT, unsigned short* __restrict__ twkT,
                                               unsigned short* __restrict__ twvT,
                                               unsigned short* __restrict__ PkT, unsigned short* __restrict__ PvT,
                                               unsigned short* __restrict__ adp_bf) {
  __shared__ float red[256];
  if (blockIdx.x < 960) {
    int i = blockIdx.x * 256 + threadIdx.x;
    if (i < 65536) d0[i] = f2bf(s0[i]);
    else if (i < 131072) d1[i - 65536] = f2bf(s1[i - 65536]);
    else if (i < 159744) d2[i - 131072] = f2bf(s2[i - 131072]);
    else if (i >= 163840) {
      int j = i - 163840;
      if (j < 4096) { int r = j >> 6, c = j & 63; swoT[c * 64 + r] = f2bf(swo[j]); }
      else if (j < 8192) { int q = j - 4096; int r = q >> 6, c = q & 63; twoT[c * 64 + r] = f2bf(two[q]); }
      else if (j < 16384) { int q = j - 8192; int r = q >> 7, c = q & 127; ff1T[c * 64 + r] = f2bf(f1[q]); }
      else if (j < 24576) { int q = j - 16384; int r = q >> 6, c = q & 63; ff2T[c * 128 + r] = f2bf(f2[q]); }
      else if (j < 28672) { int q = j - 24576; int r = q >> 6, c = q & 63; swqT[c * 64 + r] = f2bf(swq[q]); }
      else if (j < 32768) { int q = j - 28672; int r = q >> 6, c = q & 63; swkT[c * 64 + r] = f2bf(swk[q]); }
      else if (j < 36864) { int q = j - 32768; int r = q >> 6, c = q & 63; swvT[c * 64 + r] = f2bf(swv[q]); }
      else if (j < 40960) { int q = j - 36864; int r = q >> 6, c = q & 63; twqT[c * 64 + r] = f2bf(twq[q]); }
      else if (j < 45056) { int q = j - 40960; int r = q >> 6, c = q & 63; twkT[c * 64 + r] = f2bf(twk[q]); }
      else if (j < 49152) { int q = j - 45056; int r = q >> 6, c = q & 63; twvT[c * 64 + r] = f2bf(twv[q]); }
      else if (j < 65536) { int q = j - 49152; int n = q >> 6, c = q & 63; PkT[c * 256 + n] = f2bf(pk[q]); }
      else if (j < 81920) { int q = j - 65536; int n = q >> 6, c = q & 63; PvT[c * 256 + n] = f2bf(pv[q]); }
    }
  } else {
    int w = blockIdx.x - 960, v = threadIdx.x;
    float s = 0.f;
    for (int d = 0; d < 10; ++d) s += nv1[w * 10 + d] * nv2[d * KK + v];
    s = fmaxf(s, 0.f);
    red[v] = s; __syncthreads();
    for (int off = 128; off; off >>= 1) { if (v < off) red[v] = fmaxf(red[v], red[v + off]); __syncthreads(); }
    float m = red[0]; __syncthreads();
    float e = expf(s - m);
    red[v] = e; __syncthreads();
    for (int off = 128; off; off >>= 1) { if (v < off) red[v] += red[v + off]; __syncthreads(); }
    adp_bf[w * KK + v] = f2bf(e / red[0]);
  }
}

// ---------------- merged GCN mixes: blocks <1024 = s0 term; else U terms ----------------
__global__ __launch_bounds__(64) void k_mixall(const unsigned short* __restrict__ Xbf,
                                               const unsigned short* __restrict__ Wbf,
                                               const float* __restrict__ bias,
                                               unsigned short* __restrict__ s0out,
                                               unsigned short* __restrict__ U1, unsigned short* __restrict__ U2,
                                               unsigned short* __restrict__ U3, unsigned short* __restrict__ U4,
                                               unsigned short* __restrict__ U5, unsigned short* __restrict__ U6) {
  int lane = threadIdx.x;
  int lr = lane & 15, g = lane >> 4;
  if (blockIdx.x < 1024) {
    int pb = blockIdx.x;
    int lh = pb & 1;
    int k = (pb >> 1) & 255;
    int b = pb >> 9;
    short8 af[4][2], bfv[4][2];
#pragma unroll
    for (int ot = 0; ot < 4; ++ot)
#pragma unroll
      for (int kc = 0; kc < 2; ++kc)
        af[ot][kc] = *(const short8*)(Wbf + (size_t)(ot * 16 + lr) * 448 + kc * 32 + g * 8);
#pragma unroll
    for (int ct = 0; ct < 4; ++ct)
#pragma unroll
      for (int kc = 0; kc < 2; ++kc)
        bfv[ct][kc] = *(const short8*)(Xbf + ((size_t)(b * 128 + lh * 64 + ct * 16 + lr) * 256 + k) * 64 + kc * 32 + g * 8);
    f32x4 acc[4][4];
#pragma unroll
    for (int ot = 0; ot < 4; ++ot)
#pragma unroll
      for (int ct = 0; ct < 4; ++ct) acc[ot][ct] = f32x4{0.f, 0.f, 0.f, 0.f};
#pragma unroll
    for (int kc = 0; kc < 2; ++kc)
#pragma unroll
      for (int ot = 0; ot < 4; ++ot)
#pragma unroll
        for (int ct = 0; ct < 4; ++ct)
          acc[ot][ct] = __builtin_amdgcn_mfma_f32_16x16x32_bf16(af[ot][kc], bfv[ct][kc], acc[ot][ct], 0, 0, 0);
#pragma unroll
    for (int ot = 0; ot < 4; ++ot)
#pragma unroll
      for (int ct = 0; ct < 4; ++ct) {
#pragma unroll
        for (int reg = 0; reg < 4; ++reg) {
          int o = ot * 16 + g * 4 + reg;
          s0out[(size_t)(b * 64 + o) * NN + (size_t)k * 128 + lh * 64 + ct * 16 + lr] = f2bf(acc[ot][ct][reg] + bias[o]);
        }
      }
  } else {
    int idx = blockIdx.x - 1024;
    int pb = idx & 1023;
    int sy = idx >> 10;
    int b = pb >> 9;
    int rem = pb & 511;
    int l = rem >> 2;
    int kq = (rem & 3) * 64;
    size_t posbase = ((size_t)(b * 128 + l)) * 256 + kq;

    short8 af[4][2];
#pragma unroll
    for (int rt = 0; rt < 4; ++rt)
#pragma unroll
      for (int kc = 0; kc < 2; ++kc)
        af[rt][kc] = *(const short8*)(Xbf + (posbase + rt * 16 + lr) * 64 + kc * 32 + g * 8);

    for (int si = 0; si < 2; ++si) {
      int s = sy * 2 + 1 + si;
      short8 bfv[4][2];
#pragma unroll
      for (int ct = 0; ct < 4; ++ct)
#pragma unroll
        for (int kc = 0; kc < 2; ++kc)
          bfv[ct][kc] = *(const short8*)(Wbf + (size_t)(ct * 16 + lr) * 448 + s * 64 + kc * 32 + g * 8);
      f32x4 acc[4][4];
#pragma unroll
      for (int rt = 0; rt < 4; ++rt)
#pragma unroll
        for (int ct = 0; ct < 4; ++ct) acc[rt][ct] = f32x4{0.f, 0.f, 0.f, 0.f};
#pragma unroll
      for (int kc = 0; kc < 2; ++kc)
#pragma unroll
        for (int rt = 0; rt < 4; ++rt)
#pragma unroll
          for (int ct = 0; ct < 4; ++ct)
            acc[rt][ct] = __builtin_amdgcn_mfma_f32_16x16x32_bf16(af[rt][kc], bfv[ct][kc], acc[rt][ct], 0, 0, 0);
      unsigned short* dst = (s == 1) ? U1 : (s == 2) ? U2 : (s == 3) ? U3
                          : (s == 4) ? U4 : (s == 5) ? U5 : U6;
#pragma unroll
      for (int rt = 0; rt < 4; ++rt)
#pragma unroll
        for (int ct = 0; ct < 4; ++ct) {
          int o = ct * 16 + lr;
          int k = kq + rt * 16 + g * 4;
          ushort4 pk;
          pk.x = f2bf(acc[rt][ct][0]); pk.y = f2bf(acc[rt][ct][1]);
          pk.z = f2bf(acc[rt][ct][2]); pk.w = f2bf(acc[rt][ct][3]);
          *(ushort4*)&dst[((size_t)(b * 64 + o) * 128 + l) * 256 + k] = pk;
        }
    }
  }
}

// ---------------- fused 2-hop (bf16 out); grid (512,3); K-loops unrolled for load pipelining ----------------
__global__ __launch_bounds__(256) void k_adj3(const unsigned short* __restrict__ A0,
                                              const unsigned short* __restrict__ A1,
                                              const unsigned short* __restrict__ A2,
                                              const unsigned short* __restrict__ U1, const unsigned short* __restrict__ U2,
                                              const unsigned short* __restrict__ U3, const unsigned short* __restrict__ U4,
                                              const unsigned short* __restrict__ U5, const unsigned short* __restrict__ U6,
                                              unsigned short* __restrict__ O0, unsigned short* __restrict__ O1,
                                              unsigned short* __restrict__ O2) {
  int which = blockIdx.y;
  const unsigned short* Abf = (which == 0) ? A0 : (which == 1) ? A1 : A2;
  const unsigned short* Ueven = (which == 0) ? U2 : (which == 1) ? U4 : U6;
  const unsigned short* Uodd  = (which == 0) ? U1 : (which == 1) ? U3 : U5;
  unsigned short* out = (which == 0) ? O0 : (which == 1) ? O1 : O2;

  __shared__ unsigned short sH[32 * 256];
  int lq = blockIdx.x & 3, bc = blockIdx.x >> 2;
  int tid = threadIdx.x, wid = tid >> 6, lane = tid & 63;
  int lr = lane & 15, g = lane >> 4;
  int wbase = wid * 64;
  const unsigned short* aP = Abf + (size_t)(wbase + lr) * 256 + g * 8;
  const unsigned short* bP = Ueven + ((size_t)bc * 128 + lq * 32 + lr) * 256 + g * 8;

  f32x4 acc[4][2];
#pragma unroll
  for (int i = 0; i < 4; ++i)
#pragma unroll
    for (int j = 0; j < 2; ++j) acc[i][j] = f32x4{0.f, 0.f, 0.f, 0.f};
#pragma unroll
  for (int k0 = 0; k0 < 256; k0 += 32) {
    short8 af[4], bfv[2];
#pragma unroll
    for (int i = 0; i < 4; ++i) af[i] = *(const short8*)(aP + (size_t)i * 16 * 256 + k0);
#pragma unroll
    for (int i = 0; i < 2; ++i) bfv[i] = *(const short8*)(bP + (size_t)i * 16 * 256 + k0);
#pragma unroll
    for (int rm = 0; rm < 4; ++rm)
#pragma unroll
      for (int cn = 0; cn < 2; ++cn)
        acc[rm][cn] = __builtin_amdgcn_mfma_f32_16x16x32_bf16(af[rm], bfv[cn], acc[rm][cn], 0, 0, 0);
  }
  {
    const unsigned short* aT = Uodd + (size_t)bc * NN + (size_t)(lq * 32) * 256;
#pragma unroll
    for (int rm = 0; rm < 4; ++rm)
#pragma unroll
      for (int cn = 0; cn < 2; ++cn) {
        int l = cn * 16 + lr;
        int v = wbase + rm * 16 + g * 4;
        ushort4 av = *(const ushort4*)&aT[(size_t)l * 256 + v];
        ushort4 pk;
        pk.x = f2bf(acc[rm][cn][0] + bf2f(av.x));
        pk.y = f2bf(acc[rm][cn][1] + bf2f(av.y));
        pk.z = f2bf(acc[rm][cn][2] + bf2f(av.z));
        pk.w = f2bf(acc[rm][cn][3] + bf2f(av.w));
        int bo = ((l * 256 + v) * 2) ^ ((l & 7) << 4);
        *(ushort4*)((char*)sH + bo) = pk;
      }
  }
  __syncthreads();

  f32x4 c2[4][2];
#pragma unroll
  for (int i = 0; i < 4; ++i)
#pragma unroll
    for (int j = 0; j < 2; ++j) c2[i][j] = f32x4{0.f, 0.f, 0.f, 0.f};
#pragma unroll
  for (int k0 = 0; k0 < 256; k0 += 32) {
    short8 af[4], bfv[2];
#pragma unroll
    for (int i = 0; i < 4; ++i) af[i] = *(const short8*)(aP + (size_t)i * 16 * 256 + k0);
#pragma unroll
    for (int cn = 0; cn < 2; ++cn) {
      int l = cn * 16 + lr;
      int bo = ((l * 256 + k0 + g * 8) * 2) ^ ((l & 7) << 4);
      bfv[cn] = *(const short8*)((char*)sH + bo);
    }
#pragma unroll
    for (int rm = 0; rm < 4; ++rm)
#pragma unroll
      for (int cn = 0; cn < 2; ++cn)
        c2[rm][cn] = __builtin_amdgcn_mfma_f32_16x16x32_bf16(af[rm], bfv[cn], c2[rm][cn], 0, 0, 0);
  }
  unsigned short* dst = out + (size_t)bc * NN + lq * 32;
#pragma unroll
  for (int rm = 0; rm < 4; ++rm)
#pragma unroll
    for (int cn = 0; cn < 2; ++cn) {
      int col = cn * 16 + lr;
      int row = wbase + rm * 16 + g * 4;
#pragma unroll
      for (int j = 0; j < 4; ++j)
        dst[(size_t)(row + j) * 128 + col] = f2bf(c2[rm][cn][j]);
    }
}

// ---------------- generic (c,l)-plane transpose; optional dst/add/bf16 ----------------
__global__ __launch_bounds__(256) void k_tr(const float* __restrict__ src, float* __restrict__ dst,
                                            const float* __restrict__ add,
                                            unsigned short* __restrict__ dstBf,
                                            long sb, long sk, long sc, long sl,
                                            long db, long dk, long dc, long dl, int nC, int nL) {
  int outer = blockIdx.x;
  int b = outer >> 8, k = outer & 255;
  int tilesL = nL >> 5;
  int tC = blockIdx.y / tilesL, tL = blockIdx.y % tilesL;
  int c0 = tC << 5, l0 = tL << 5;
  __shared__ float s[32][33];
  int tx = threadIdx.x & 31, ty = threadIdx.x >> 5;
  const float* sp = src + (long)b * sb + (long)k * sk;
#pragma unroll
  for (int j = 0; j < 4; ++j) {
    int cc = c0 + ty + j * 8;
    s[ty + j * 8][tx] = sp[(long)cc * sc + (long)(l0 + tx) * sl];
  }
  __syncthreads();
  long dbase = (long)b * db + (long)k * dk;
#pragma unroll
  for (int j = 0; j < 4; ++j) {
    int ll = l0 + ty + j * 8;
    long off = dbase + (long)(c0 + tx) * dc + (long)ll * dl;
    float val = s[tx][ty + j * 8];
    if (add) val += add[off];
    if (dst) dst[off] = val;
    if (dstBf) dstBf[off] = f2bf(val);
  }
}

// ---------------- merged: spatial QKV (blocks <1024) + temporal pre-transpose (blocks >=1024) ----------------
__global__ __launch_bounds__(256) void k_qkvs_tr(const unsigned short* __restrict__ Xbf,
                                                 const unsigned short* __restrict__ wqT,
                                                 const unsigned short* __restrict__ wkT,
                                                 const unsigned short* __restrict__ wvT,
                                                 unsigned short* __restrict__ qb,
                                                 unsigned short* __restrict__ xkT,
                                                 unsigned short* __restrict__ xvT,
                                                 const float* __restrict__ y,
                                                 float* __restrict__ xtF,
                                                 unsigned short* __restrict__ xtBf) {
  __shared__ float sTile[32][33];
  if (blockIdx.x >= 1024) {
    int tb = blockIdx.x - 1024;
    int outer = tb >> 3, yy = tb & 7;
    int b = outer >> 8, k = outer & 255;
    int tC = yy >> 2, tL = yy & 3;
    int c0 = tC << 5, l0 = tL << 5;
    int tx = threadIdx.x & 31, ty = threadIdx.x >> 5;
    const float* sp = y + (long)b * 2097152 + (long)k * 128;
#pragma unroll
    for (int j = 0; j < 4; ++j) {
      int cc = c0 + ty + j * 8;
      sTile[ty + j * 8][tx] = sp[(long)cc * 32768 + (long)(l0 + tx)];
    }
    __syncthreads();
    long dbase = (long)b * 2097152 + (long)k * 8192;
#pragma unroll
    for (int j = 0; j < 4; ++j) {
      int ll = l0 + ty + j * 8;
      long off = dbase + (long)(c0 + tx) + (long)ll * 64;
      float val = sTile[tx][ty + j * 8];
      xtF[off] = val;
      xtBf[off] = f2bf(val);
    }
    return;
  }
  int r0 = blockIdx.x * 64;
  int t = threadIdx.x, w = t >> 6, lane = t & 63;
  int lr = lane & 15, g = lane >> 4;
  const unsigned short* aP = Xbf + (size_t)(r0 + w * 16 + lr) * 64 + g * 8;
  short8 ax0 = *(const short8*)aP;
  short8 ax1 = *(const short8*)(aP + 32);
  {
    f32x4 acc[4];
#pragma unroll
    for (int ct = 0; ct < 4; ++ct) acc[ct] = f32x4{0.f, 0.f, 0.f, 0.f};
#pragma unroll
    for (int ct = 0; ct < 4; ++ct) {
      short8 b0 = *(const short8*)(wqT + (size_t)(ct * 16 + lr) * 64 + g * 8);
      short8 b1 = *(const short8*)(wqT + (size_t)(ct * 16 + lr) * 64 + 32 + g * 8);
      acc[ct] = __builtin_amdgcn_mfma_f32_16x16x32_bf16(ax0, b0, acc[ct], 0, 0, 0);
      acc[ct] = __builtin_amdgcn_mfma_f32_16x16x32_bf16(ax1, b1, acc[ct], 0, 0, 0);
    }
#pragma unroll
    for (int ct = 0; ct < 4; ++ct)
#pragma unroll
      for (int reg = 0; reg < 4; ++reg)
        qb[(size_t)(r0 + w * 16 + g * 4 + reg) * 64 + ct * 16 + lr] = f2bf(acc[ct][reg]);
  }
  short8 bx0[4], bx1[4];
#pragma unroll
  for (int ct = 0; ct < 4; ++ct) {
    const unsigned short* bP = Xbf + (size_t)(r0 + ct * 16 + lr) * 64 + g * 8;
    bx0[ct] = *(const short8*)bP;
    bx1[ct] = *(const short8*)(bP + 32);
  }
  int bl = r0 >> 8, nb = r0 & 255;
#pragma unroll
  for (int which = 0; which < 2; ++which) {
    const unsigned short* WT = which ? wvT : wkT;
    unsigned short* dstb = which ? xvT : xkT;
    short8 aw0 = *(const short8*)(WT + (size_t)(w * 16 + lr) * 64 + g * 8);
    short8 aw1 = *(const short8*)(WT + (size_t)(w * 16 + lr) * 64 + 32 + g * 8);
    f32x4 acc[4];
#pragma unroll
    for (int ct = 0; ct < 4; ++ct) {
      acc[ct] = f32x4{0.f, 0.f, 0.f, 0.f};
      acc[ct] = __builtin_amdgcn_mfma_f32_16x16x32_bf16(aw0, bx0[ct], acc[ct], 0, 0, 0);
      acc[ct] = __builtin_amdgcn_mfma_f32_16x16x32_bf16(aw1, bx1[ct], acc[ct], 0, 0, 0);
    }
#pragma unroll
    for (int ct = 0; ct < 4; ++ct)
#pragma unroll
      for (int reg = 0; reg < 4; ++reg) {
        int o = w * 16 + g * 4 + reg;
        dstb[(size_t)bl * 16384 + (size_t)o * 256 + nb + ct * 16 + lr] = f2bf(acc[ct][reg]);
      }
  }
}

// ---------------- merged: temporal QKV (blocks <1024) + gn_part1B on SSb (blocks >=1024) ----------------
__global__ __launch_bounds__(256) void k_qkvt_gn(const unsigned short* __restrict__ Xbf,
                                                 const unsigned short* __restrict__ wqT,
                                                 const unsigned short* __restrict__ wkT,
                                                 const unsigned short* __restrict__ wvT,
                                                 const float* __restrict__ bq, const float* __restrict__ bk_,
                                                 const float* __restrict__ bv,
                                                 unsigned short* __restrict__ qb,
                                                 unsigned short* __restrict__ kb,
                                                 unsigned short* __restrict__ vt,
                                                 const unsigned short* __restrict__ gnIn,
                                                 float* __restrict__ gnPart) {
  __shared__ float rs[256], rq[256];
  if (blockIdx.x >= 1024) {
    int tb = blockIdx.x - 1024;
    int blk = tb & 63, bg = tb >> 6, t = threadIdx.x;
    size_t start = (size_t)bg * ((size_t)CPG * NN) + (size_t)blk * 8192;
    const ushort4* q0 = (const ushort4*)(gnIn + start);
    float s = 0.f, ss = 0.f;
    for (int i = t; i < 2048; i += 256) {
      ushort4 u = q0[i];
      float a = bf2f(u.x), b = bf2f(u.y), c = bf2f(u.z), d = bf2f(u.w);
      s += a + b + c + d;
      ss += a * a + b * b + c * c + d * d;
    }
    rs[t] = s; rq[t] = ss; __syncthreads();
    for (int off = 128; off; off >>= 1) { if (t < off) { rs[t] += rs[t + off]; rq[t] += rq[t + off]; } __syncthreads(); }
    if (t == 0) { gnPart[(bg * 64 + blk) * 2] = rs[0]; gnPart[(bg * 64 + blk) * 2 + 1] = rq[0]; }
    return;
  }
  int r0 = blockIdx.x * 64;
  int t = threadIdx.x, w = t >> 6, lane = t & 63;
  int lr = lane & 15, g = lane >> 4;
  const unsigned short* aP = Xbf + (size_t)(r0 + w * 16 + lr) * 64 + g * 8;
  short8 ax0 = *(const short8*)aP;
  short8 ax1 = *(const short8*)(aP + 32);
#pragma unroll
  for (int which = 0; which < 2; ++which) {
    const unsigned short* WT = which ? wkT : wqT;
    const float* bias = which ? bk_ : bq;
    unsigned short* dstb = which ? kb : qb;
    f32x4 acc[4];
#pragma unroll
    for (int ct = 0; ct < 4; ++ct) {
      acc[ct] = f32x4{0.f, 0.f, 0.f, 0.f};
      short8 b0 = *(const short8*)(WT + (size_t)(ct * 16 + lr) * 64 + g * 8);
      short8 b1 = *(const short8*)(WT + (size_t)(ct * 16 + lr) * 64 + 32 + g * 8);
      acc[ct] = __builtin_amdgcn_mfma_f32_16x16x32_bf16(ax0, b0, acc[ct], 0, 0, 0);
      acc[ct] = __builtin_amdgcn_mfma_f32_16x16x32_bf16(ax1, b1, acc[ct], 0, 0, 0);
    }
#pragma unroll
    for (int ct = 0; ct < 4; ++ct) {
      float bvv = bias[ct * 16 + lr];
#pragma unroll
      for (int reg = 0; reg < 4; ++reg)
        dstb[(size_t)(r0 + w * 16 + g * 4 + reg) * 64 + ct * 16 + lr] = f2bf(acc[ct][reg] + bvv);
    }
  }
  short8 bx0[4], bx1[4];
#pragma unroll
  for (int ct = 0; ct < 4; ++ct) {
    const unsigned short* bP = Xbf + (size_t)(r0 + ct * 16 + lr) * 64 + g * 8;
    bx0[ct] = *(const short8*)bP;
    bx1[ct] = *(const short8*)(bP + 32);
  }
  int bkk = r0 >> 7, lbase = r0 & 127;
  short8 aw0 = *(const short8*)(wvT + (size_t)(w * 16 + lr) * 64 + g * 8);
  short8 aw1 = *(const short8*)(wvT + (size_t)(w * 16 + lr) * 64 + 32 + g * 8);
  f32x4 acc[4];
#pragma unroll
  for (int ct = 0; ct < 4; ++ct) {
    acc[ct] = f32x4{0.f, 0.f, 0.f, 0.f};
    acc[ct] = __builtin_amdgcn_mfma_f32_16x16x32_bf16(aw0, bx0[ct], acc[ct], 0, 0, 0);
    acc[ct] = __builtin_amdgcn_mfma_f32_16x16x32_bf16(aw1, bx1[ct], acc[ct], 0, 0, 0);
  }
  int lb4 = lbase >> 4;   // 0 or 4
#pragma unroll
  for (int ct = 0; ct < 4; ++ct)
#pragma unroll
    for (int reg = 0; reg < 4; ++reg) {
      int o = w * 16 + g * 4 + reg;
      vt[(size_t)bkk * 8192 + (size_t)o * 128 + lr * 8 + lb4 + ct] = f2bf(acc[ct][reg] + bv[o]);
    }
}

// ---------------- MFMA sproj; V^T output sigma-permuted; K-loop unrolled ----------------
__global__ __launch_bounds__(256) void k_sprojM(const unsigned short* __restrict__ XkT,
                                                const unsigned short* __restrict__ XvT,
                                                const unsigned short* __restrict__ PkT,
                                                const unsigned short* __restrict__ PvT,
                                                unsigned short* __restrict__ kpb,
                                                unsigned short* __restrict__ vptb) {
  int bl = blockIdx.x;
  int which = blockIdx.y;
  int t = threadIdx.x, w = t >> 6, lane = t & 63;
  int lr = lane & 15, g = lane >> 4;
  const unsigned short* Abase = which ? PvT : XkT + (size_t)bl * 16384;
  const unsigned short* Bbase = which ? XvT + (size_t)bl * 16384 : PkT;
  const unsigned short* aP = Abase + (size_t)(w * 16 + lr) * 256 + g * 8;
  f32x4 acc[4];
#pragma unroll
  for (int ct = 0; ct < 4; ++ct) acc[ct] = f32x4{0.f, 0.f, 0.f, 0.f};
#pragma unroll
  for (int k0 = 0; k0 < 256; k0 += 32) {
    short8 af = *(const short8*)(aP + k0);
#pragma unroll
    for (int ct = 0; ct < 4; ++ct) {
      short8 bf = *(const short8*)(Bbase + (size_t)(ct * 16 + lr) * 256 + k0 + g * 8);
      acc[ct] = __builtin_amdgcn_mfma_f32_16x16x32_bf16(af, bf, acc[ct], 0, 0, 0);
    }
  }
  if (!which) {
    unsigned short* dst = kpb + (size_t)bl * 4096;
#pragma unroll
    for (int ct = 0; ct < 4; ++ct) {
      int p = ct * 16 + lr;
      int c0 = w * 16 + g * 4;
      ushort4 pk;
      pk.x = f2bf(acc[ct][0]); pk.y = f2bf(acc[ct][1]);
      pk.z = f2bf(acc[ct][2]); pk.w = f2bf(acc[ct][3]);
      *(ushort4*)&dst[(size_t)p * 64 + c0] = pk;
    }
  } else {
    unsigned short* dst = vptb + (size_t)bl * 4096;
#pragma unroll
    for (int ct = 0; ct < 4; ++ct) {
      int c = ct * 16 + lr;
#pragma unroll
      for (int reg = 0; reg < 4; ++reg)
        dst[(size_t)c * 64 + (g * 4 + reg) * 4 + w] = f2bf(acc[ct][reg]);
    }
  }
}

// ---------------- fused channel FFN (MFMA) ----------------
__global__ __launch_bounds__(256) void k_cffn(const unsigned short* __restrict__ in,
                                              const unsigned short* __restrict__ ff1T,
                                              const unsigned short* __restrict__ ff2T,
                                              const float* __restrict__ b1,
                                              const float* __restrict__ b2,
                                              float* __restrict__ out) {
  __shared__ unsigned short sH[4][16 * 128];
  int r0 = blockIdx.x * 64;
  int t = threadIdx.x, w = t >> 6, lane = t & 63;
  int lr = lane & 15, g = lane >> 4;
  unsigned short* myH = sH[w];
  const unsigned short* aP = in + (size_t)(r0 + w * 16 + lr) * 64 + g * 8;
  short8 af0 = *(const short8*)aP;
  short8 af1 = *(const short8*)(aP + 32);
  f32x4 acc1[8];
#pragma unroll
  for (int ct = 0; ct < 8; ++ct) acc1[ct] = f32x4{0.f, 0.f, 0.f, 0.f};
#pragma unroll
  for (int ct = 0; ct < 8; ++ct) {
    short8 b0 = *(const short8*)(ff1T + (size_t)(ct * 16 + lr) * 64 + g * 8);
    short8 bx = *(const short8*)(ff1T + (size_t)(ct * 16 + lr) * 64 + 32 + g * 8);
    acc1[ct] = __builtin_amdgcn_mfma_f32_16x16x32_bf16(af0, b0, acc1[ct], 0, 0, 0);
    acc1[ct] = __builtin_amdgcn_mfma_f32_16x16x32_bf16(af1, bx, acc1[ct], 0, 0, 0);
  }
#pragma unroll
  for (int ct = 0; ct < 8; ++ct) {
    int o = ct * 16 + lr;
    float bv = b1[o];
#pragma unroll
    for (int reg = 0; reg < 4; ++reg) {
      int m = g * 4 + reg;
      float h = fmaxf(acc1[ct][reg] + bv, 0.f);
      int bo = ((m * 128 + o) * 2) ^ ((m & 7) << 4);
      *(unsigned short*)((char*)myH + bo) = f2bf(h);
    }
  }
  __syncthreads();
  short8 ha[4];
#pragma unroll
  for (int ks = 0; ks < 4; ++ks) {
    int bo = ((lr * 128 + ks * 32 + g * 8) * 2) ^ ((lr & 7) << 4);
    ha[ks] = *(const short8*)((char*)myH + bo);
  }
  f32x4 acc2[4];
#pragma unroll
  for (int ct = 0; ct < 4; ++ct) acc2[ct] = f32x4{0.f, 0.f, 0.f, 0.f};
#pragma unroll
  for (int ct = 0; ct < 4; ++ct)
#pragma unroll
    for (int ks = 0; ks < 4; ++ks) {
      short8 b0 = *(const short8*)(ff2T + (size_t)(ct * 16 + lr) * 128 + ks * 32 + g * 8);
      acc2[ct] = __builtin_amdgcn_mfma_f32_16x16x32_bf16(ha[ks], b0, acc2[ct], 0, 0, 0);
    }
#pragma unroll
  for (int ct = 0; ct < 4; ++ct) {
    int o = ct * 16 + lr;
    float bv = b2[o];
#pragma unroll
    for (int reg = 0; reg < 4; ++reg)
      out[(size_t)(r0 + w * 16 + g * 4 + reg) * 64 + o] = acc2[ct][reg] + bv;
  }
}

// ---------------- fused LN1 -> FFN(64->8 gelu ->64) -> LN2 ----------------
__global__ __launch_bounds__(256) void k_tffn(const float* __restrict__ A, const float* __restrict__ Bz,
                                              const float* __restrict__ l1w, const float* __restrict__ l1b,
                                              const float* __restrict__ l2w, const float* __restrict__ l2b,
                                              const float* __restrict__ ln1g, const float* __restrict__ ln1b,
                                              const float* __restrict__ ln2g, const float* __restrict__ ln2b,
                                              float* __restrict__ outp) {
  int r0 = blockIdx.x * 64;
  __shared__ float sSrc[64][65];
  __shared__ float sH[64][8];
  __shared__ float sW1[64][8];
  __shared__ float sW2[8][64];
  int t = threadIdx.x;
  for (int i = t; i < 512; i += 256) { ((float*)sW1)[i] = l1w[i]; ((float*)sW2)[i] = l2w[i]; }
  int c = t & 63, rg = t >> 6;
  float g1 = ln1g[c], be1 = ln1b[c];
  for (int it = 0; it < 16; ++it) {
    int r = it * 4 + rg;
    size_t idx = (size_t)(r0 + r) * 64 + c;
    float x = A[idx] + Bz[idx];
    float s = x, ss = x * x;
#pragma unroll
    for (int off = 32; off; off >>= 1) { s += __shfl_xor(s, off); ss += __shfl_xor(ss, off); }
    float mu = s * (1.f / 64.f);
    float var = ss * (1.f / 64.f) - mu * mu;
    sSrc[r][c] = (x - mu) * rsqrtf(var + EPSV) * g1 + be1;
  }
  __syncthreads();
#pragma unroll
  for (int p = 0; p < 2; ++p) {
    int idx = t + 256 * p;
    int row = idx >> 3, j = idx & 7;
    float acc = l1b[j];
    for (int cc = 0; cc < 64; ++cc) acc += sSrc[row][cc] * sW1[cc][j];
    acc = 0.5f * acc * (1.f + erff(acc * 0.70710678118654752440f));
    sH[row][j] = acc;
  }
  __syncthreads();
  float g2 = ln2g[c], be2 = ln2b[c];
  float l2bc = l2b[c];
  for (int it = 0; it < 16; ++it) {
    int r = it * 4 + rg;
    float o = l2bc;
#pragma unroll
    for (int j = 0; j < 8; ++j) o += sH[r][j] * sW2[j][c];
    float x = sSrc[r][c] + o;
    float s = x, ss = x * x;
#pragma unroll
    for (int off = 32; off; off >>= 1) { s += __shfl_xor(s, off); ss += __shfl_xor(ss, off); }
    float mu = s * (1.f / 64.f);
    float var = ss * (1.f / 64.f) - mu * mu;
    outp[(size_t)(r0 + r) * 64 + c] = (x - mu) * rsqrtf(var + EPSV) * g2 + be2;
  }
}

// ---------------- per-head MFMA attention + fused output projection -> fp32 ----------------
template <int NKV, int KVSHIFT>
__global__ __launch_bounds__(512) void k_attnP(const unsigned short* __restrict__ Qb,
                                               const unsigned short* __restrict__ Kb,
                                               const unsigned short* __restrict__ VTb,
                                               const unsigned short* __restrict__ WT,
                                               const float* __restrict__ bias,
                                               float* __restrict__ out) {
  constexpr int NCT = NKV / 16;
  constexpr int NKS = NKV / 32;
  int blk = blockIdx.x;
  const unsigned short* Qp = Qb + (size_t)blk * 128 * 64;
  const unsigned short* Kp = Kb + (size_t)(blk >> KVSHIFT) * NKV * 64;
  const unsigned short* VTp = VTb + (size_t)(blk >> KVSHIFT) * 64 * NKV;
  int t = threadIdx.x;
  int h = t >> 6, lane = t & 63, lr = lane & 15, g = lane >> 4;
  __shared__ unsigned short sP[8][16 * NKV];
  __shared__ unsigned short sO[128 * 64];
  unsigned short* myP = sP[h];

  short8 kbf[NCT];
#pragma unroll
  for (int ct = 0; ct < NCT; ++ct)
    kbf[ct] = *(const short8*)(Kp + (size_t)(ct * 16 + lr) * 64 + h * 8);

  short8 vbf[NKS];
  if (lr < 8) {
    int vr = h * 8 + lr;
#pragma unroll
    for (int ks = 0; ks < NKS; ++ks)
      vbf[ks] = *(const short8*)(VTp + (size_t)vr * NKV + ks * 32 + g * 8);
  } else if (lr == 8) {
    const short ONE = (short)0x3F80;  // bf16 1.0
#pragma unroll
    for (int ks = 0; ks < NKS; ++ks)
      vbf[ks] = short8{ONE, ONE, ONE, ONE, ONE, ONE, ONE, ONE};
  } else {
#pragma unroll
    for (int ks = 0; ks < NKS; ++ks)
      vbf[ks] = short8{0, 0, 0, 0, 0, 0, 0, 0};
  }
  int srcl = (lane & 48) | 8;   // lane holding this row-group's col-8 (row sums)

  for (int mt = 0; mt < 8; ++mt) {
    short8 qa = short8{0, 0, 0, 0, 0, 0, 0, 0};
    if (g == 0) qa = *(const short8*)(Qp + (size_t)(mt * 16 + lr) * 64 + h * 8);

    f32x4 sacc[NCT];
#pragma unroll
    for (int ct = 0; ct < NCT; ++ct) sacc[ct] = f32x4{0.f, 0.f, 0.f, 0.f};
#pragma unroll
    for (int ct = 0; ct < NCT; ++ct)
      sacc[ct] = __builtin_amdgcn_mfma_f32_16x16x32_bf16(qa, kbf[ct], sacc[ct], 0, 0, 0);

#pragma unroll
    for (int ct = 0; ct < NCT; ++ct)
#pragma unroll
      for (int reg = 0; reg < 4; ++reg)
        sacc[ct][reg] = __expf(sacc[ct][reg] * SCL);

    // P store: slot sigma(c) = lr*NCT + ct -> contiguous NCT values per row
#pragma unroll
    for (int reg = 0; reg < 4; ++reg) {
      int row = g * 4 + reg;
#pragma unroll
      for (int c4 = 0; c4 < NCT; c4 += 4) {
        ushort4 pk;
        pk.x = f2bf(sacc[c4 + 0][reg]); pk.y = f2bf(sacc[c4 + 1][reg]);
        pk.z = f2bf(sacc[c4 + 2][reg]); pk.w = f2bf(sacc[c4 + 3][reg]);
        int bo = ((row * NKV + lr * NCT + c4) * 2) ^ ((row & 7) << 4);
        *(ushort4*)((char*)myP + bo) = pk;
      }
    }
    // no barrier: myP is wave-private

    f32x4 oacc = f32x4{0.f, 0.f, 0.f, 0.f};
#pragma unroll
    for (int ks = 0; ks < NKS; ++ks) {
      int bo = ((lr * NKV + ks * 32 + g * 8) * 2) ^ ((lr & 7) << 4);
      short8 pa = *(const short8*)((char*)myP + bo);
      oacc = __builtin_amdgcn_mfma_f32_16x16x32_bf16(pa, vbf[ks], oacc, 0, 0, 0);
    }
    float inv4[4];
#pragma unroll
    for (int reg = 0; reg < 4; ++reg)
      inv4[reg] = 1.f / __shfl(oacc[reg], srcl);
    if (lr < 8) {
#pragma unroll
      for (int reg = 0; reg < 4; ++reg) {
        int row = mt * 16 + g * 4 + reg;
        int col = h * 8 + lr;
        int bo = ((row * 64 + col) * 2) ^ ((row & 7) << 4);
        *(unsigned short*)((char*)sO + bo) = f2bf(oacc[reg] * inv4[reg]);
      }
    }
  }
  __syncthreads();

  int row = h * 16 + lr;
  int bo0 = ((row * 64 + g * 8) * 2) ^ ((row & 7) << 4);
  int bo1 = ((row * 64 + 32 + g * 8) * 2) ^ ((row & 7) << 4);
  short8 af0 = *(const short8*)((char*)sO + bo0);
  short8 af1 = *(const short8*)((char*)sO + bo1);
  f32x4 acc[4];
#pragma unroll
  for (int ct = 0; ct < 4; ++ct) acc[ct] = f32x4{0.f, 0.f, 0.f, 0.f};
#pragma unroll
  for (int ct = 0; ct < 4; ++ct) {
    short8 b0 = *(const short8*)(WT + (size_t)(ct * 16 + lr) * 64 + g * 8);
    short8 b1 = *(const short8*)(WT + (size_t)(ct * 16 + lr) * 64 + 32 + g * 8);
    acc[ct] = __builtin_amdgcn_mfma_f32_16x16x32_bf16(af0, b0, acc[ct], 0, 0, 0);
    acc[ct] = __builtin_amdgcn_mfma_f32_16x16x32_bf16(af1, b1, acc[ct], 0, 0, 0);
  }
  float* op = out + (size_t)blk * 128 * 64;
#pragma unroll
  for (int ct = 0; ct < 4; ++ct) {
    int o = ct * 16 + lr;
    float bv = bias[o];
#pragma unroll
    for (int reg = 0; reg < 4; ++reg)
      op[(size_t)(h * 16 + g * 4 + reg) * 64 + o] = acc[ct][reg] + bv;
  }
}

// ---------------- GroupNorm stats (fp32 single input) ----------------
__global__ __launch_bounds__(256) void k_gn_part(const float* __restrict__ p0,
                                                 float* __restrict__ part) {
  int bg = blockIdx.y, blk = blockIdx.x, t = threadIdx.x;
  size_t start = (size_t)bg * ((size_t)CPG * NN) + (size_t)blk * 8192;
  const float4* q0 = (const float4*)(p0 + start);
  float s = 0.f, ss = 0.f;
  for (int i = t; i < 2048; i += 256) {
    float4 x = q0[i];
    s += x.x + x.y + x.z + x.w;
    ss += x.x * x.x + x.y * x.y + x.z * x.z + x.w * x.w;
  }
  __shared__ float rs[256], rq[256];
  rs[t] = s; rq[t] = ss; __syncthreads();
  for (int off = 128; off; off >>= 1) { if (t < off) { rs[t] += rs[t + off]; rq[t] += rq[t + off]; } __syncthreads(); }
  if (t == 0) { part[(bg * 64 + blk) * 2] = rs[0]; part[(bg * 64 + blk) * 2 + 1] = rq[0]; }
}

// ---------------- GroupNorm stats (bf16 single input) ----------------
__global__ __launch_bounds__(256) void k_gn_part1B(const unsigned short* __restrict__ p0,
                                                   float* __restrict__ part) {
  int bg = blockIdx.y, blk = blockIdx.x, t = threadIdx.x;
  size_t start = (size_t)bg * ((size_t)CPG * NN) + (size_t)blk * 8192;
  const ushort4* q0 = (const ushort4*)(p0 + start);
  float s = 0.f, ss = 0.f;
  for (int i = t; i < 2048; i += 256) {
    ushort4 u = q0[i];
    float a = bf2f(u.x), b = bf2f(u.y), c = bf2f(u.z), d = bf2f(u.w);
    s += a + b + c + d;
    ss += a * a + b * b + c * c + d * d;
  }
  __shared__ float rs[256], rq[256];
  rs[t] = s; rq[t] = ss; __syncthreads();
  for (int off = 128; off; off >>= 1) { if (t < off) { rs[t] += rs[t + off]; rq[t] += rq[t + off]; } __syncthreads(); }
  if (t == 0) { part[(bg * 64 + blk) * 2] = rs[0]; part[(bg * 64 + blk) * 2 + 1] = rq[0]; }
}

// ---------------- GroupNorm stats: y(fp32) + 4 bf16 -> bf16 sum + partials ----------------
__global__ __launch_bounds__(256) void k_gn_partB(const float* __restrict__ p0,
                                                  const unsigned short* __restrict__ q1,
                                                  const unsigned short* __restrict__ q2,
                                                  const unsigned short* __restrict__ q3,
                                                  const unsigned short* __restrict__ q4,
                                                  unsigned short* __restrict__ sumOut,
                                                  float* __restrict__ part) {
  int bg = blockIdx.y, blk = blockIdx.x, t = threadIdx.x;
  size_t start = (size_t)bg * ((size_t)CPG * NN) + (size_t)blk * 8192;
  const float4* f0 = (const float4*)(p0 + start);
  const ushort4* b1 = (const ushort4*)(q1 + start);
  const ushort4* b2 = (const ushort4*)(q2 + start);
  const ushort4* b3 = (const ushort4*)(q3 + start);
  const ushort4* b4 = (const ushort4*)(q4 + start);
  ushort4* so = (ushort4*)(sumOut + start);
  float s = 0.f, ss = 0.f;
  for (int i = t; i < 2048; i += 256) {
    float4 x = f0[i];
    ushort4 u;
    u = b1[i]; x.x += bf2f(u.x); x.y += bf2f(u.y); x.z += bf2f(u.z); x.w += bf2f(u.w);
    u = b2[i]; x.x += bf2f(u.x); x.y += bf2f(u.y); x.z += bf2f(u.z); x.w += bf2f(u.w);
    u = b3[i]; x.x += bf2f(u.x); x.y += bf2f(u.y); x.z += bf2f(u.z); x.w += bf2f(u.w);
    u = b4[i]; x.x += bf2f(u.x); x.y += bf2f(u.y); x.z += bf2f(u.z); x.w += bf2f(u.w);
    ushort4 pk;
    pk.x = f2bf(x.x); pk.y = f2bf(x.y); pk.z = f2bf(x.z); pk.w = f2bf(x.w);
    so[i] = pk;
    s += x.x + x.y + x.z + x.w;
    ss += x.x * x.x + x.y * x.y + x.z * x.z + x.w * x.w;
  }
  __shared__ float rs[256], rq[256];
  rs[t] = s; rq[t] = ss; __syncthreads();
  for (int off = 128; off; off >>= 1) { if (t < off) { rs[t] += rs[t + off]; rq[t] += rq[t + off]; } __syncthreads(); }
  if (t == 0) { part[(bg * 64 + blk) * 2] = rs[0]; part[(bg * 64 + blk) * 2 + 1] = rq[0]; }
}

// out = GN(p0) — reduces 64 partials per block (final GN)
__global__ __launch_bounds__(256) void k_gn_apply(const float* __restrict__ p0,
                                                  const float* __restrict__ part, const float* __restrict__ g,
                                                  const float* __restrict__ be,
                                                  float* __restrict__ out) {
  size_t i4 = (size_t)blockIdx.x * 256 + threadIdx.x;
  size_t i = i4 * 4;
  int chan = (int)(i >> 15) & 63;
  int bg = (int)(i >> 19);
  __shared__ float smu, srr;
  int t = threadIdx.x;
  if (t < 64) {
    float s = part[(bg * 64 + t) * 2], ss = part[(bg * 64 + t) * 2 + 1];
#pragma unroll
    for (int off = 32; off; off >>= 1) { s += __shfl_xor(s, off); ss += __shfl_xor(ss, off); }
    if (t == 0) {
      float inv = 1.f / (float)((size_t)CPG * NN);
      float mu = s * inv;
      float var = ss * inv - mu * mu;
      smu = mu; srr = rsqrtf(var + EPSV);
    }
  }
  __syncthreads();
  float mu = smu, rr = srr;
  float4 x = ((const float4*)p0)[i4];
  float gc = g[chan], bc = be[chan];
  float4 v;
  v.x = (x.x - mu) * rr * gc + bc;
  v.y = (x.y - mu) * rr * gc + bc;
  v.z = (x.z - mu) * rr * gc + bc;
  v.w = (x.w - mu) * rr * gc + bc;
  ((float4*)out)[i4] = v;
}

// out = GN_l(SLb) + GN_s(SSb) + GN_t(STb); bf16 inputs; three partial sets at part+0/+2048/+4096
__global__ __launch_bounds__(256) void k_gn_apply3B(const unsigned short* __restrict__ SLb,
                                                    const unsigned short* __restrict__ SSb,
                                                    const unsigned short* __restrict__ STb,
                                                    const float* __restrict__ part,
                                                    const float* __restrict__ gl, const float* __restrict__ bl_,
                                                    const float* __restrict__ gs, const float* __restrict__ bs_,
                                                    const float* __restrict__ gt, const float* __restrict__ bt_,
                                                    float* __restrict__ out) {
  size_t i4 = (size_t)blockIdx.x * 256 + threadIdx.x;
  size_t i = i4 * 4;
  int chan = (int)(i >> 15) & 63;
  int bg = (int)(i >> 19);
  __shared__ float smu[3], srr[3];
  int t = threadIdx.x;
  if (t < 192) {
    int which = t >> 6, tt = t & 63;
    const float* pp = part + which * 2048;
    float s = pp[(bg * 64 + tt) * 2], ss = pp[(bg * 64 + tt) * 2 + 1];
#pragma unroll
    for (int off = 32; off; off >>= 1) { s += __shfl_xor(s, off); ss += __shfl_xor(ss, off); }
    if (tt == 0) {
      float inv = 1.f / (float)((size_t)CPG * NN);
      float mu = s * inv;
      float var = ss * inv - mu * mu;
      smu[which] = mu; srr[which] = rsqrtf(var + EPSV);
    }
  }
  __syncthreads();
  float gL = gl[chan] * srr[0], bL = bl_[chan] - smu[0] * gl[chan] * srr[0];
  float gS = gs[chan] * srr[1], bS = bs_[chan] - smu[1] * gs[chan] * srr[1];
  float gT = gt[chan] * srr[2], bT = bt_[chan] - smu[2] * gt[chan] * srr[2];
  ushort4 ul = ((const ushort4*)SLb)[i4];
  ushort4 us = ((const ushort4*)SSb)[i4];
  ushort4 ut = ((const ushort4*)STb)[i4];
  float4 v;
  v.x = bf2f(ul.x) * gL + bL + bf2f(us.x) * gS + bS + bf2f(ut.x) * gT + bT;
  v.y = bf2f(ul.y) * gL + bL + bf2f(us.y) * gS + bS + bf2f(ut.y) * gT + bT;
  v.z = bf2f(ul.z) * gL + bL + bf2f(us.z) * gS + bS + bf2f(ut.z) * gT + bT;
  v.w = bf2f(ul.w) * gL + bL + bf2f(us.w) * gS + bS + bf2f(ut.w) * gT + bT;
  ((float4*)out)[i4] = v;
}

extern "C" void kernel_launch(void* const* d_in, const int* in_sizes, int n_in,
                              void* d_out, int out_size, void* d_ws, size_t ws_size,
                              hipStream_t stream) {
  (void)in_sizes; (void)n_in; (void)out_size; (void)ws_size;
  const float* y     = (const float*)d_in[0];
  const float* a1    = (const float*)d_in[1];
  const float* a2    = (const float*)d_in[2];
  const float* nv1   = (const float*)d_in[3];
  const float* nv2   = (const float*)d_in[4];
  const float* gcn_w = (const float*)d_in[5];
  const float* gcn_b = (const float*)d_in[6];
  const float* s_wq  = (const float*)d_in[7];
  const float* s_wk  = (const float*)d_in[8];
  const float* s_wv  = (const float*)d_in[9];
  const float* s_pk  = (const float*)d_in[10];
  const float* s_pv  = (const float*)d_in[11];
  const float* s_wo  = (const float*)d_in[12];
  const float* s_bo  = (const float*)d_in[13];
  const float* t_wq  = (const float*)d_in[14];
  const float* t_wk  = (const float*)d_in[15];
  const float* t_wv  = (const float*)d_in[16];
  const float* t_bq  = (const float*)d_in[17];
  const float* t_bk  = (const float*)d_in[18];
  const float* t_bv  = (const float*)d_in[19];
  const float* t_wo  = (const float*)d_in[20];
  const float* t_bo  = (const float*)d_in[21];
  const float* t_l1w = (const float*)d_in[22];
  const float* t_l1b = (const float*)d_in[23];
  const float* t_l2w = (const float*)d_in[24];
  const float* t_l2b = (const float*)d_in[25];
  const float* ln1g  = (const float*)d_in[26];
  const float* ln1b  = (const float*)d_in[27];
  const float* ln2g  = (const float*)d_in[28];
  const float* ln2b  = (const float*)d_in[29];
  const float* gnlg  = (const float*)d_in[30];
  const float* gnlb  = (const float*)d_in[31];
  const float* gnsg  = (const float*)d_in[32];
  const float* gnsb  = (const float*)d_in[33];
  const float* gntg  = (const float*)d_in[34];
  const float* gntb  = (const float*)d_in[35];
  const float* ff1w  = (const float*)d_in[36];
  const float* ff1b  = (const float*)d_in[37];
  const float* ff2w  = (const float*)d_in[38];
  const float* ff2b  = (const float*)d_in[39];
  const float* gn2g  = (const float*)d_in[40];
  const float* gn2b  = (const float*)d_in[41];

  float* ws = (float*)d_ws;
  float* part  = ws + 65536;
  unsigned short* a1_bf   = (unsigned short*)(ws + 131072);
  unsigned short* a2_bf   = (unsigned short*)(ws + 163840);
  unsigned short* adp_bf  = (unsigned short*)(ws + 196608);
  unsigned short* gcnw_bf = (unsigned short*)(ws + 229376);
  unsigned short* xs_bf   = (unsigned short*)(ws + 262144);
  unsigned short* swoT = (unsigned short*)(ws + 2359296);
  unsigned short* twoT = (unsigned short*)(ws + 2361344);
  unsigned short* ff1T = (unsigned short*)(ws + 2363392);
  unsigned short* ff2T = (unsigned short*)(ws + 2367488);
  unsigned short* swqT = (unsigned short*)(ws + 2371584);
  unsigned short* swkT = (unsigned short*)(ws + 2373632);
  unsigned short* swvT = (unsigned short*)(ws + 2375680);
  unsigned short* twqT = (unsigned short*)(ws + 2377728);
  unsigned short* twkT = (unsigned short*)(ws + 2379776);
  unsigned short* twvT = (unsigned short*)(ws + 2381824);
  unsigned short* PkT  = (unsigned short*)(ws + 2383872);
  unsigned short* PvT  = (unsigned short*)(ws + 2392064);
  unsigned short* kpb  = (unsigned short*)(ws + 131072);
  unsigned short* vptb = (unsigned short*)(ws + 1179648);
  const size_t SLOT = 4194304;
  float* G0 = ws + SLOT * 1;
  float* G1 = ws + SLOT * 2;
  float* G2 = ws + SLOT * 3;
  float* G3 = ws + SLOT * 4;
  float* G4 = ws + SLOT * 5;
  float* G5 = ws + SLOT * 6;
  float* G6 = ws + SLOT * 7;
  unsigned short* U1 = (unsigned short*)G3;
  unsigned short* U2 = (unsigned short*)G3 + 4194304;
  unsigned short* U3 = (unsigned short*)G4;
  unsigned short* U4 = (unsigned short*)G4 + 4194304;
  unsigned short* U5 = (unsigned short*)G5;
  unsigned short* U6 = (unsigned short*)G5 + 4194304;
  unsigned short* s0bf = (unsigned short*)G1;
  unsigned short* Q1bf = (unsigned short*)G0;
  unsigned short* Q3bf = (unsigned short*)G0 + 4194304;
  unsigned short* Q2bf = (unsigned short*)G6;
  unsigned short* SLb  = (unsigned short*)G3;   // GCN branch sum (bf16)
  unsigned short* SSb  = (unsigned short*)G1;   // spatial branch sum
  unsigned short* STb  = (unsigned short*)G2;   // temporal branch sum
  unsigned short* qbuf = (unsigned short*)G0;
  unsigned short* xkT = (unsigned short*)G4;
  unsigned short* xvT = (unsigned short*)G5;
  unsigned short* kbuf = (unsigned short*)G4;
  unsigned short* vtbuf = (unsigned short*)G5;
  unsigned short* xt_bf = (unsigned short*)G6;
  float* out = (float*)d_out;

  const long BS = 2097152;

  // ---- merged setup: weight casts + adaptive adjacency ----
  k_setup<<<1216, 256, 0, stream>>>(a1, a2, gcn_w, s_wo, t_wo, ff1w, ff2w,
                                    s_wq, s_wk, s_wv, t_wq, t_wk, t_wv, s_pk, s_pv, nv1, nv2,
                                    a1_bf, a2_bf, gcnw_bf, swoT, twoT, ff1T, ff2T,
                                    swqT, swkT, swvT, twqT, twkT, twvT, PkT, PvT, adp_bf);

  // ---- xs bf16 (B,L,K,C) ----
  k_tr<<<dim3(512, 8), 256, 0, stream>>>(y, nullptr, nullptr, xs_bf, BS, 128, 32768, 1, BS, 64, 1, 16384, 64, 128);

  // ---- AdaptiveGCN (merged mixes + merged 2-hops) ----
  k_mixall<<<4096, 64, 0, stream>>>(xs_bf, gcnw_bf, gcn_b, s0bf, U1, U2, U3, U4, U5, U6);
  k_adj3<<<dim3(512, 3), 256, 0, stream>>>(a1_bf, a2_bf, adp_bf, U1, U2, U3, U4, U5, U6,
                                           Q1bf, Q2bf, Q3bf);
  k_gn_partB<<<dim3(64, 8), 256, 0, stream>>>(y, s0bf, Q1bf, Q2bf, Q3bf, SLb, part);

  // ---- spatial QKV + temporal pre-transpose (merged) ----
  k_qkvs_tr<<<5120, 256, 0, stream>>>(xs_bf, swqT, swkT, swvT, qbuf, xkT, xvT, y, G2, xt_bf);
  k_sprojM<<<dim3(256, 2), 256, 0, stream>>>(xkT, xvT, PkT, PvT, kpb, vptb);
  k_attnP<64, 1><<<512, 512, 0, stream>>>(qbuf, kpb, vptb, swoT, s_bo, G4);
  k_tr<<<dim3(512, 8), 256, 0, stream>>>(G4, nullptr, y, SSb, BS, 64, 16384, 1, BS, 128, 1, 32768, 128, 64);

  // ---- temporal QKV + spatial GN stats (merged) ----
  k_qkvt_gn<<<1536, 256, 0, stream>>>(xt_bf, twqT, twkT, twvT, t_bq, t_bk, t_bv,
                                      qbuf, kbuf, vtbuf, SSb, part + 2048);
  k_attnP<128, 0><<<512, 512, 0, stream>>>(qbuf, kbuf, vtbuf, twoT, t_bo, G6);
  k_tffn<<<1024, 256, 0, stream>>>(G2, G6, t_l1w, t_l1b, t_l2w, t_l2b,
                                   ln1g, ln1b, ln2g, ln2b, G0);
  k_tr<<<dim3(512, 8), 256, 0, stream>>>(G0, nullptr, y, STb, BS, 8192, 64, 1, BS, 128, 1, 32768, 128, 64);
  k_gn_part1B<<<dim3(64, 8), 256, 0, stream>>>(STb, part + 4096);

  // ---- fused triple-GN: y_in2 = GN_l + GN_s + GN_t -> G4 fp32 ----
  k_gn_apply3B<<<4096, 256, 0, stream>>>(SLb, SSb, STb, part, gnlg, gnlb, gnsg, gnsb, gntg, gntb, G4);

  // ---- fuse + channel FFN + final GroupNorm ----
  k_tr<<<dim3(512, 8), 256, 0, stream>>>(G4, nullptr, nullptr, (unsigned short*)G5,
                                         BS, 128, 32768, 1, BS, 8192, 1, 64, 64, 128);
  k_cffn<<<1024, 256, 0, stream>>>((unsigned short*)G5, ff1T, ff2T, ff1b, ff2b, G6);
  k_tr<<<dim3(512, 8), 256, 0, stream>>>(G6, out, G4, nullptr, BS, 8192, 64, 1, BS, 128, 1, 32768, 128, 64);
  k_gn_part<<<dim3(64, 8), 256, 0, stream>>>(out, part);
  k_gn_apply<<<4096, 256, 0, stream>>>(out, part, gn2g, gn2b, out);
}